// Round 1
// baseline (805.016 us; speedup 1.0000x reference)
//
#include <hip/hip_runtime.h>
#include <math.h>

#define N_NODES 50000
#define N_EDGES 800000
#define ETOT (N_EDGES + N_NODES)
#define IN_DIM 128
#define HIDC 64
#define HEADS 4
#define F1 (HEADS * HIDC) /* 256 */

// ---------------- edge-index dtype detect + decode ----------------
// int64 values are < 50000 => every odd 32-bit word is 0. For int32 input,
// odd words are edge indices (random in [0,50000)) -> not all zero over 2048.
__global__ void detect_idx_kernel(const unsigned int* __restrict__ buf, int* __restrict__ flag) {
  __shared__ int any;
  if (threadIdx.x == 0) any = 0;
  __syncthreads();
  for (int i = threadIdx.x; i < 2048; i += blockDim.x)
    if (buf[2 * i + 1] != 0u) any = 1;
  __syncthreads();
  if (threadIdx.x == 0) *flag = any; // 1 => int32, 0 => int64
}

__global__ void decode_idx_kernel(const void* __restrict__ eidx, const int* __restrict__ flag,
                                  int* __restrict__ srcO, int* __restrict__ dstO) {
  int i = blockIdx.x * blockDim.x + threadIdx.x;
  if (i >= N_EDGES) return;
  if (*flag) {
    const int* b = (const int*)eidx;
    srcO[i] = b[i];
    dstO[i] = b[N_EDGES + i];
  } else {
    const long long* b = (const long long*)eidx;
    srcO[i] = (int)b[i];
    dstO[i] = (int)b[N_EDGES + i];
  }
}

// ---------------- CSR build (by dst), self-loops appended ----------------
__global__ void hist_kernel(const int* __restrict__ dst, int* __restrict__ cnt) {
  int i = blockIdx.x * blockDim.x + threadIdx.x;
  if (i >= ETOT) return;
  int d = (i < N_EDGES) ? dst[i] : (i - N_EDGES);
  atomicAdd(&cnt[d], 1);
}

__global__ __launch_bounds__(1024) void scan_kernel(const int* __restrict__ cnt, int* __restrict__ off) {
  const int T = 1024;
  const int n = N_NODES;
  int tid = threadIdx.x;
  int chunk = (n + T - 1) / T;
  int s0 = tid * chunk;
  int s1 = min(s0 + chunk, n);
  int sum = 0;
  for (int i = s0; i < s1; ++i) sum += cnt[i];
  __shared__ int tmp[T];
  tmp[tid] = sum;
  __syncthreads();
  for (int o = 1; o < T; o <<= 1) {
    int t = (tid >= o) ? tmp[tid - o] : 0;
    __syncthreads();
    tmp[tid] += t;
    __syncthreads();
  }
  int run = tmp[tid] - sum; // exclusive prefix
  for (int i = s0; i < s1; ++i) {
    off[i] = run;
    run += cnt[i];
  }
  if (tid == T - 1) off[n] = run; // == ETOT
}

__global__ void fill_kernel(const int* __restrict__ src, const int* __restrict__ dst,
                            const int* __restrict__ csrOff, int* __restrict__ fillc,
                            int* __restrict__ csrSrc) {
  int i = blockIdx.x * blockDim.x + threadIdx.x;
  if (i >= ETOT) return;
  int s, d;
  if (i < N_EDGES) { s = src[i]; d = dst[i]; } else { s = i - N_EDGES; d = s; }
  int pos = csrOff[d] + atomicAdd(&fillc[d], 1);
  csrSrc[pos] = s;
}

// ---------------- fp32 tiled GEMM: C[M,Nout] = A[M,K] * B[K,Nout] ----------------
#define BM 64
#define BN 64
#define BK 16
__global__ __launch_bounds__(256) void gemm_f32_kernel(const float* __restrict__ A,
                                                       const float* __restrict__ B,
                                                       float* __restrict__ C,
                                                       int M, int K, int Nout) {
  __shared__ float As[BK][BM + 1];
  __shared__ float Bs[BK][BN + 1];
  int tid = threadIdx.x;
  int brow = blockIdx.x * BM;
  int bcol = blockIdx.y * BN;
  int ty = tid >> 4, tx = tid & 15;
  float acc[4][4] = {};
  for (int k0 = 0; k0 < K; k0 += BK) {
    {
      int r = tid >> 2;
      int kq = (tid & 3) * 4;
      int row = brow + r;
      float4 v = make_float4(0.f, 0.f, 0.f, 0.f);
      if (row < M) v = *reinterpret_cast<const float4*>(&A[(size_t)row * K + k0 + kq]);
      As[kq + 0][r] = v.x; As[kq + 1][r] = v.y; As[kq + 2][r] = v.z; As[kq + 3][r] = v.w;
    }
    {
      int kk = tid >> 4;
      int cq = (tid & 15) * 4;
      float4 v = *reinterpret_cast<const float4*>(&B[(size_t)(k0 + kk) * Nout + bcol + cq]);
      Bs[kk][cq + 0] = v.x; Bs[kk][cq + 1] = v.y; Bs[kk][cq + 2] = v.z; Bs[kk][cq + 3] = v.w;
    }
    __syncthreads();
#pragma unroll
    for (int k = 0; k < BK; ++k) {
      float a[4], b[4];
#pragma unroll
      for (int i = 0; i < 4; ++i) a[i] = As[k][ty * 4 + i];
#pragma unroll
      for (int j = 0; j < 4; ++j) b[j] = Bs[k][tx * 4 + j];
#pragma unroll
      for (int i = 0; i < 4; ++i)
#pragma unroll
        for (int j = 0; j < 4; ++j) acc[i][j] = fmaf(a[i], b[j], acc[i][j]);
    }
    __syncthreads();
  }
#pragma unroll
  for (int i = 0; i < 4; ++i) {
    int row = brow + ty * 4 + i;
    if (row < M) {
#pragma unroll
      for (int j = 0; j < 4; ++j) C[(size_t)row * Nout + bcol + tx * 4 + j] = acc[i][j];
    }
  }
}

// ---------------- per-node attention logits: a_s[n,h], a_d[n,h] ----------------
template <int H>
__global__ __launch_bounds__(256) void att_proj_kernel(const float* __restrict__ xl,
                                                       const float* __restrict__ atts,
                                                       const float* __restrict__ attd,
                                                       float* __restrict__ a_s,
                                                       float* __restrict__ a_d) {
  int wave = threadIdx.x >> 6;
  int lane = threadIdx.x & 63;
  int node = blockIdx.x * 4 + wave;
  if (node >= N_NODES) return;
  const float* row = xl + (size_t)node * (H * 64);
#pragma unroll
  for (int j = 0; j < H; ++j) {
    float xv = row[j * 64 + lane];
    float ps = xv * atts[j * 64 + lane];
    float pd = xv * attd[j * 64 + lane];
#pragma unroll
    for (int o = 32; o > 0; o >>= 1) {
      ps += __shfl_xor(ps, o);
      pd += __shfl_xor(pd, o);
    }
    if (lane == 0) {
      a_s[node * H + j] = ps;
      a_d[node * H + j] = pd;
    }
  }
}

// ---------------- edge softmax + aggregate (one wave per dst node) ----------------
template <int H>
__global__ __launch_bounds__(256) void gat_agg_kernel(const float* __restrict__ xl,
                                                      const float* __restrict__ a_srcv,
                                                      const float* __restrict__ a_dstv,
                                                      const int* __restrict__ csrOff,
                                                      const int* __restrict__ csrSrc,
                                                      const float* __restrict__ bias,
                                                      float* __restrict__ out) {
  int wave = threadIdx.x >> 6;
  int lane = threadIdx.x & 63;
  int d = blockIdx.x * 4 + wave;
  if (d >= N_NODES) return;
  int e0 = csrOff[d], e1 = csrOff[d + 1];
  float adv[H];
  if constexpr (H == 4) {
    float4 t = reinterpret_cast<const float4*>(a_dstv)[d];
    adv[0] = t.x; adv[1] = t.y; adv[2] = t.z; adv[3] = t.w;
  } else {
    adv[0] = a_dstv[d];
  }
  float m[H], ssum[H], acc[H];
#pragma unroll
  for (int j = 0; j < H; ++j) { m[j] = -1e30f; ssum[j] = 0.f; acc[j] = 0.f; }
  for (int cb = e0; cb < e1; cb += 64) {
    int ecount = min(64, e1 - cb);
    int sidx = (lane < ecount) ? csrSrc[cb + lane] : 0;
    float asv[H];
#pragma unroll
    for (int j = 0; j < H; ++j) asv[j] = 0.f;
    if (lane < ecount) {
      if constexpr (H == 4) {
        float4 t = reinterpret_cast<const float4*>(a_srcv)[sidx];
        asv[0] = t.x; asv[1] = t.y; asv[2] = t.z; asv[3] = t.w;
      } else {
        asv[0] = a_srcv[sidx];
      }
    }
    float p[H];
#pragma unroll
    for (int j = 0; j < H; ++j) {
      float al = -1e30f;
      if (lane < ecount) {
        float v = asv[j] + adv[j];
        al = (v > 0.f) ? v : 0.2f * v;
      }
      float cm = al;
#pragma unroll
      for (int o = 32; o > 0; o >>= 1) cm = fmaxf(cm, __shfl_xor(cm, o));
      float nm = fmaxf(m[j], cm);
      float scale = __expf(m[j] - nm); // first chunk: exp(-1e30-nm) == 0
      p[j] = (lane < ecount) ? __expf(al - nm) : 0.f;
      float ps = p[j];
#pragma unroll
      for (int o = 32; o > 0; o >>= 1) ps += __shfl_xor(ps, o);
      ssum[j] = ssum[j] * scale + ps;
      acc[j] *= scale;
      m[j] = nm;
    }
    for (int i = 0; i < ecount; ++i) {
      int s = __shfl(sidx, i);
      const float* xr = xl + (size_t)s * (H * 64);
#pragma unroll
      for (int j = 0; j < H; ++j) {
        float pj = __shfl(p[j], i);
        acc[j] = fmaf(pj, xr[j * 64 + lane], acc[j]);
      }
    }
  }
  size_t ob = (size_t)d * (H * 64);
#pragma unroll
  for (int j = 0; j < H; ++j) {
    float v = acc[j] / (ssum[j] + 1e-16f) + bias[j * 64 + lane];
    out[ob + j * 64 + lane] = (v > 0.f) ? v : (__expf(v) - 1.f); // ELU
  }
}

// layer 3 (H=1) + fused b3 + fc (64->2) + fc_b, writes final output
__global__ __launch_bounds__(256) void gat_final_kernel(const float* __restrict__ xl,
                                                        const float* __restrict__ a_srcv,
                                                        const float* __restrict__ a_dstv,
                                                        const int* __restrict__ csrOff,
                                                        const int* __restrict__ csrSrc,
                                                        const float* __restrict__ b3,
                                                        const float* __restrict__ fcw,
                                                        const float* __restrict__ fcb,
                                                        float* __restrict__ out) {
  int wave = threadIdx.x >> 6;
  int lane = threadIdx.x & 63;
  int d = blockIdx.x * 4 + wave;
  if (d >= N_NODES) return;
  int e0 = csrOff[d], e1 = csrOff[d + 1];
  float adv = a_dstv[d];
  float m = -1e30f, ssum = 0.f, acc = 0.f;
  for (int cb = e0; cb < e1; cb += 64) {
    int ecount = min(64, e1 - cb);
    int sidx = (lane < ecount) ? csrSrc[cb + lane] : 0;
    float al = -1e30f;
    if (lane < ecount) {
      float v = a_srcv[sidx] + adv;
      al = (v > 0.f) ? v : 0.2f * v;
    }
    float cm = al;
#pragma unroll
    for (int o = 32; o > 0; o >>= 1) cm = fmaxf(cm, __shfl_xor(cm, o));
    float nm = fmaxf(m, cm);
    float scale = __expf(m - nm);
    float p = (lane < ecount) ? __expf(al - nm) : 0.f;
    float ps = p;
#pragma unroll
    for (int o = 32; o > 0; o >>= 1) ps += __shfl_xor(ps, o);
    ssum = ssum * scale + ps;
    acc *= scale;
    m = nm;
    for (int i = 0; i < ecount; ++i) {
      int s = __shfl(sidx, i);
      float pj = __shfl(p, i);
      acc = fmaf(pj, xl[(size_t)s * 64 + lane], acc);
    }
  }
  float v = acc / (ssum + 1e-16f) + b3[lane];
  float l0 = v * fcw[lane * 2 + 0];
  float l1 = v * fcw[lane * 2 + 1];
#pragma unroll
  for (int o = 32; o > 0; o >>= 1) {
    l0 += __shfl_xor(l0, o);
    l1 += __shfl_xor(l1, o);
  }
  if (lane == 0) {
    out[2 * d + 0] = l0 + fcb[0];
    out[2 * d + 1] = l1 + fcb[1];
  }
}

extern "C" void kernel_launch(void* const* d_in, const int* in_sizes, int n_in,
                              void* d_out, int out_size, void* d_ws, size_t ws_size,
                              hipStream_t stream) {
  (void)in_sizes; (void)n_in; (void)out_size; (void)ws_size;
  const float* x      = (const float*)d_in[0];
  const void*  eidx   = d_in[1];
  const float* W1     = (const float*)d_in[2];
  const float* att_s1 = (const float*)d_in[3];
  const float* att_d1 = (const float*)d_in[4];
  const float* b1     = (const float*)d_in[5];
  const float* W2     = (const float*)d_in[6];
  const float* att_s2 = (const float*)d_in[7];
  const float* att_d2 = (const float*)d_in[8];
  const float* b2     = (const float*)d_in[9];
  const float* W3     = (const float*)d_in[10];
  const float* att_s3 = (const float*)d_in[11];
  const float* att_d3 = (const float*)d_in[12];
  const float* b3     = (const float*)d_in[13];
  const float* fcw    = (const float*)d_in[14];
  const float* fcb    = (const float*)d_in[15];
  float* out = (float*)d_out;

  char* ws = (char*)d_ws;
  size_t off = 0;
  auto alloc = [&](size_t bytes) -> void* {
    void* p = (void*)(ws + off);
    off += (bytes + 255) & ~(size_t)255;
    return p;
  };
  int*   srcI   = (int*)alloc((size_t)N_EDGES * 4);
  int*   dstI   = (int*)alloc((size_t)N_EDGES * 4);
  int*   cnt    = (int*)alloc((size_t)N_NODES * 4);
  int*   fillc  = (int*)alloc((size_t)N_NODES * 4);
  int*   csrOff = (int*)alloc((size_t)(N_NODES + 1) * 4);
  int*   csrSrc = (int*)alloc((size_t)ETOT * 4);
  int*   flag   = (int*)alloc(256);
  float* a_s    = (float*)alloc((size_t)N_NODES * HEADS * 4);
  float* a_d    = (float*)alloc((size_t)N_NODES * HEADS * 4);
  float* bufA   = (float*)alloc((size_t)N_NODES * F1 * 4); // xl of current layer
  float* bufB   = (float*)alloc((size_t)N_NODES * F1 * 4); // aggregated h
  // total ws use ~114 MB

  hipMemsetAsync(cnt, 0, (size_t)N_NODES * 4, stream);
  hipMemsetAsync(fillc, 0, (size_t)N_NODES * 4, stream);

  detect_idx_kernel<<<1, 256, 0, stream>>>((const unsigned int*)eidx, flag);
  decode_idx_kernel<<<(N_EDGES + 255) / 256, 256, 0, stream>>>(eidx, flag, srcI, dstI);
  hist_kernel<<<(ETOT + 255) / 256, 256, 0, stream>>>(dstI, cnt);
  scan_kernel<<<1, 1024, 0, stream>>>(cnt, csrOff);
  fill_kernel<<<(ETOT + 255) / 256, 256, 0, stream>>>(srcI, dstI, csrOff, fillc, csrSrc);

  int gx = (N_NODES + BM - 1) / BM; // 782
  int gn = (N_NODES + 3) / 4;       // 12500

  // Layer 1: x[N,128] @ W1[128,256]
  gemm_f32_kernel<<<dim3(gx, F1 / BN), 256, 0, stream>>>(x, W1, bufA, N_NODES, IN_DIM, F1);
  att_proj_kernel<4><<<gn, 256, 0, stream>>>(bufA, att_s1, att_d1, a_s, a_d);
  gat_agg_kernel<4><<<gn, 256, 0, stream>>>(bufA, a_s, a_d, csrOff, csrSrc, b1, bufB);

  // Layer 2: h1[N,256] @ W2[256,256]
  gemm_f32_kernel<<<dim3(gx, F1 / BN), 256, 0, stream>>>(bufB, W2, bufA, N_NODES, F1, F1);
  att_proj_kernel<4><<<gn, 256, 0, stream>>>(bufA, att_s2, att_d2, a_s, a_d);
  gat_agg_kernel<4><<<gn, 256, 0, stream>>>(bufA, a_s, a_d, csrOff, csrSrc, b2, bufB);

  // Layer 3: h2[N,256] @ W3[256,64], H=1, fused fc
  gemm_f32_kernel<<<dim3(gx, 1), 256, 0, stream>>>(bufB, W3, bufA, N_NODES, F1, HIDC);
  att_proj_kernel<1><<<gn, 256, 0, stream>>>(bufA, att_s3, att_d3, a_s, a_d);
  gat_final_kernel<<<gn, 256, 0, stream>>>(bufA, a_s, a_d, csrOff, csrSrc, b3, fcw, fcb, out);
}

// Round 2
// 684.389 us; speedup vs baseline: 1.1763x; 1.1763x over previous
//
#include <hip/hip_runtime.h>
#include <math.h>

#define N_NODES 50000
#define N_EDGES 800000
#define ETOT (N_EDGES + N_NODES)
#define IN_DIM 128
#define HIDC 64
#define HEADS 4
#define F1 (HEADS * HIDC) /* 256 */
#define MP 50048 /* N_NODES padded to 128 */

typedef __bf16 bf16x8 __attribute__((ext_vector_type(8)));
typedef float f32x4 __attribute__((ext_vector_type(4)));
typedef unsigned short u16x8 __attribute__((ext_vector_type(8)));

__device__ inline unsigned short f2bf(float f) {
  unsigned u = __builtin_bit_cast(unsigned, f);
  u += 0x7fff + ((u >> 16) & 1);
  return (unsigned short)(u >> 16);
}
__device__ inline float bf2f(unsigned short h) {
  unsigned u = ((unsigned)h) << 16;
  return __builtin_bit_cast(float, u);
}

__device__ inline void gload_lds16(const void* g, void* l) {
  __builtin_amdgcn_global_load_lds(
      (const __attribute__((address_space(1))) unsigned int*)g,
      (__attribute__((address_space(3))) unsigned int*)l, 16, 0, 0);
}

// ---------------- edge-index dtype detect + decode ----------------
__global__ void detect_idx_kernel(const unsigned int* __restrict__ buf, int* __restrict__ flag) {
  __shared__ int any;
  if (threadIdx.x == 0) any = 0;
  __syncthreads();
  for (int i = threadIdx.x; i < 2048; i += blockDim.x)
    if (buf[2 * i + 1] != 0u) any = 1;
  __syncthreads();
  if (threadIdx.x == 0) *flag = any; // 1 => int32, 0 => int64
}

__global__ void decode_idx_kernel(const void* __restrict__ eidx, const int* __restrict__ flag,
                                  int* __restrict__ srcO, int* __restrict__ dstO) {
  int i = blockIdx.x * blockDim.x + threadIdx.x;
  if (i >= N_EDGES) return;
  if (*flag) {
    const int* b = (const int*)eidx;
    srcO[i] = b[i];
    dstO[i] = b[N_EDGES + i];
  } else {
    const long long* b = (const long long*)eidx;
    srcO[i] = (int)b[i];
    dstO[i] = (int)b[N_EDGES + i];
  }
}

// ---------------- CSR build (by dst), self-loops appended ----------------
__global__ void hist_kernel(const int* __restrict__ dst, int* __restrict__ cnt) {
  int i = blockIdx.x * blockDim.x + threadIdx.x;
  if (i >= ETOT) return;
  int d = (i < N_EDGES) ? dst[i] : (i - N_EDGES);
  atomicAdd(&cnt[d], 1);
}

__global__ __launch_bounds__(1024) void scan_kernel(const int* __restrict__ cnt, int* __restrict__ off) {
  const int T = 1024;
  const int n = N_NODES;
  int tid = threadIdx.x;
  int chunk = (n + T - 1) / T;
  int s0 = tid * chunk;
  int s1 = min(s0 + chunk, n);
  int sum = 0;
  for (int i = s0; i < s1; ++i) sum += cnt[i];
  __shared__ int tmp[T];
  tmp[tid] = sum;
  __syncthreads();
  for (int o = 1; o < T; o <<= 1) {
    int t = (tid >= o) ? tmp[tid - o] : 0;
    __syncthreads();
    tmp[tid] += t;
    __syncthreads();
  }
  int run = tmp[tid] - sum;
  for (int i = s0; i < s1; ++i) {
    off[i] = run;
    run += cnt[i];
  }
  if (tid == T - 1) off[n] = run;
}

__global__ void fill_kernel(const int* __restrict__ src, const int* __restrict__ dst,
                            const int* __restrict__ csrOff, int* __restrict__ fillc,
                            int* __restrict__ csrSrc) {
  int i = blockIdx.x * blockDim.x + threadIdx.x;
  if (i >= ETOT) return;
  int s, d;
  if (i < N_EDGES) { s = src[i]; d = dst[i]; } else { s = i - N_EDGES; d = s; }
  int pos = csrOff[d] + atomicAdd(&fillc[d], 1);
  csrSrc[pos] = s;
}

// ---------------- fp32 -> split-bf16 (hi/lo), MFMA fragment-tiled layout ----------------
// A tiled: [MP/16][K/32][kg=4][r=16][j=8]  (each 16x32 fragment = contiguous 1KB)
template <int K>
__global__ __launch_bounds__(256) void convA_kernel(const float* __restrict__ A,
                                                    unsigned short* __restrict__ hi,
                                                    unsigned short* __restrict__ lo, int M) {
  __shared__ float ld[16][264];
  const int mblk = blockIdx.x;
  const int tid = threadIdx.x;
  const int elems = 16 * K;
#pragma unroll
  for (int e = tid * 4; e < elems; e += 1024) {
    int r = e / K, c = e % K;
    int row = mblk * 16 + r;
    float4 v = make_float4(0.f, 0.f, 0.f, 0.f);
    if (row < M) v = *reinterpret_cast<const float4*>(&A[(size_t)row * K + c]);
    ld[r][c + 0] = v.x; ld[r][c + 1] = v.y; ld[r][c + 2] = v.z; ld[r][c + 3] = v.w;
  }
  __syncthreads();
#pragma unroll
  for (int o = tid * 8; o < elems; o += 2048) {
    int r = (o >> 3) & 15;
    int kg = (o >> 7) & 3;
    int kb = o >> 9;
    int k0 = kb * 32 + kg * 8;
    u16x8 h8, l8;
#pragma unroll
    for (int j = 0; j < 8; ++j) {
      float v = ld[r][k0 + j];
      unsigned short h = f2bf(v);
      h8[j] = h;
      l8[j] = f2bf(v - bf2f(h));
    }
    size_t base = ((size_t)mblk * (K >> 5) + kb) * 512 + (size_t)(kg * 16 + r) * 8;
    *reinterpret_cast<u16x8*>(hi + base) = h8;
    *reinterpret_cast<u16x8*>(lo + base) = l8;
  }
}

// W [K,Nw] row-major -> tiled [Nw/16][K/32][kg=4][c=16][j=8]
__global__ void convW_kernel(const float* __restrict__ W, unsigned short* __restrict__ hi,
                             unsigned short* __restrict__ lo, int K, int Nw) {
  int t = blockIdx.x * blockDim.x + threadIdx.x;
  int KB = K >> 5;
  int total = (Nw >> 4) * KB * 64;
  if (t >= total) return;
  int c = t & 15;
  int kg = (t >> 4) & 3;
  int kb = (t >> 6) % KB;
  int nblk = (t >> 6) / KB;
  int n = nblk * 16 + c;
  int k0 = kb * 32 + kg * 8;
  u16x8 h8, l8;
#pragma unroll
  for (int j = 0; j < 8; ++j) {
    float v = W[(size_t)(k0 + j) * Nw + n];
    unsigned short h = f2bf(v);
    h8[j] = h;
    l8[j] = f2bf(v - bf2f(h));
  }
  *reinterpret_cast<u16x8*>(hi + (size_t)t * 8) = h8;
  *reinterpret_cast<u16x8*>(lo + (size_t)t * 8) = l8;
}

// ---------------- split-bf16 MFMA GEMM: C = Ahi*Bhi + Alo*Bhi + Ahi*Blo ----------------
// tile 128 x (NB*16); 4 waves, wave w owns rows [w*32,w*32+32), all NB col-frags
template <int KB, int NB>
__global__ __launch_bounds__(256) void gemm_mfma_kernel(
    const unsigned short* __restrict__ Ahi, const unsigned short* __restrict__ Alo,
    const unsigned short* __restrict__ Bhi, const unsigned short* __restrict__ Blo,
    float* __restrict__ C, int M, int Nout) {
  __shared__ unsigned short As[8 * 512];
  __shared__ unsigned short Bs[NB * 512];
  const int tid = threadIdx.x;
  const int w = tid >> 6, lane = tid & 63;
  const size_t machunk = ((size_t)blockIdx.x * 8 + w * 2) * KB; // in 512-elem units
  const int nblk0 = blockIdx.y * NB;
  const int laneo = lane * 8;

  f32x4 acc[2][NB];
#pragma unroll
  for (int mi = 0; mi < 2; ++mi)
#pragma unroll
    for (int nj = 0; nj < NB; ++nj) acc[mi][nj] = {0.f, 0.f, 0.f, 0.f};

  const unsigned short* Ap[3] = {Ahi, Alo, Ahi};
  const unsigned short* Bp[3] = {Bhi, Bhi, Blo};
#pragma unroll
  for (int p = 0; p < 3; ++p) {
    const unsigned short* Abase = Ap[p];
    const unsigned short* Bbase = Bp[p];
    for (int kb = 0; kb < KB; ++kb) {
      // stage A: wave w loads its 2 mblk chunks; B: wave w loads NB/4 chunks
      gload_lds16(Abase + (machunk + kb) * 512 + laneo, As + (w * 2) * 512);
      gload_lds16(Abase + (machunk + (size_t)KB + kb) * 512 + laneo, As + (w * 2 + 1) * 512);
#pragma unroll
      for (int q = 0; q < NB / 4; ++q) {
        int nbl = w * (NB / 4) + q;
        gload_lds16(Bbase + ((size_t)(nblk0 + nbl) * KB + kb) * 512 + laneo, Bs + nbl * 512);
      }
      __syncthreads(); // drains vmcnt -> loads visible to all waves
      bf16x8 a0 = *reinterpret_cast<const bf16x8*>(As + (w * 2) * 512 + laneo);
      bf16x8 a1 = *reinterpret_cast<const bf16x8*>(As + (w * 2 + 1) * 512 + laneo);
      bf16x8 b[NB];
#pragma unroll
      for (int nj = 0; nj < NB; ++nj)
        b[nj] = *reinterpret_cast<const bf16x8*>(Bs + nj * 512 + laneo);
#pragma unroll
      for (int nj = 0; nj < NB; ++nj) {
        acc[0][nj] = __builtin_amdgcn_mfma_f32_16x16x32_bf16(a0, b[nj], acc[0][nj], 0, 0, 0);
        acc[1][nj] = __builtin_amdgcn_mfma_f32_16x16x32_bf16(a1, b[nj], acc[1][nj], 0, 0, 0);
      }
      __syncthreads(); // compute done before next overwrite
    }
  }
  // epilogue: C/D frag mapping: row=(lane>>4)*4+reg, col=lane&15
  const int col0 = nblk0 * 16 + (lane & 15);
  const int row0 = blockIdx.x * 128 + w * 32 + (lane >> 4) * 4;
#pragma unroll
  for (int mi = 0; mi < 2; ++mi) {
#pragma unroll
    for (int nj = 0; nj < NB; ++nj) {
      int col = col0 + nj * 16;
#pragma unroll
      for (int r = 0; r < 4; ++r) {
        int row = row0 + mi * 16 + r;
        if (row < M) C[(size_t)row * Nout + col] = acc[mi][nj][r];
      }
    }
  }
}

// ---------------- per-node attention logits: a_s[n,h], a_d[n,h] ----------------
template <int H>
__global__ __launch_bounds__(256) void att_proj_kernel(const float* __restrict__ xl,
                                                       const float* __restrict__ atts,
                                                       const float* __restrict__ attd,
                                                       float* __restrict__ a_s,
                                                       float* __restrict__ a_d) {
  int wave = threadIdx.x >> 6;
  int lane = threadIdx.x & 63;
  int node = blockIdx.x * 4 + wave;
  if (node >= N_NODES) return;
  const float* row = xl + (size_t)node * (H * 64);
#pragma unroll
  for (int j = 0; j < H; ++j) {
    float xv = row[j * 64 + lane];
    float ps = xv * atts[j * 64 + lane];
    float pd = xv * attd[j * 64 + lane];
#pragma unroll
    for (int o = 32; o > 0; o >>= 1) {
      ps += __shfl_xor(ps, o);
      pd += __shfl_xor(pd, o);
    }
    if (lane == 0) {
      a_s[node * H + j] = ps;
      a_d[node * H + j] = pd;
    }
  }
}

// ---------------- edge softmax + aggregate (one wave per dst node) ----------------
template <int H>
__global__ __launch_bounds__(256) void gat_agg_kernel(const float* __restrict__ xl,
                                                      const float* __restrict__ a_srcv,
                                                      const float* __restrict__ a_dstv,
                                                      const int* __restrict__ csrOff,
                                                      const int* __restrict__ csrSrc,
                                                      const float* __restrict__ bias,
                                                      float* __restrict__ out) {
  int wave = threadIdx.x >> 6;
  int lane = threadIdx.x & 63;
  int d = blockIdx.x * 4 + wave;
  if (d >= N_NODES) return;
  int e0 = csrOff[d], e1 = csrOff[d + 1];
  float adv[H];
  if constexpr (H == 4) {
    float4 t = reinterpret_cast<const float4*>(a_dstv)[d];
    adv[0] = t.x; adv[1] = t.y; adv[2] = t.z; adv[3] = t.w;
  } else {
    adv[0] = a_dstv[d];
  }
  float m[H], ssum[H], acc[H];
#pragma unroll
  for (int j = 0; j < H; ++j) { m[j] = -1e30f; ssum[j] = 0.f; acc[j] = 0.f; }
  for (int cb = e0; cb < e1; cb += 64) {
    int ecount = min(64, e1 - cb);
    int sidx = (lane < ecount) ? csrSrc[cb + lane] : 0;
    float asv[H];
#pragma unroll
    for (int j = 0; j < H; ++j) asv[j] = 0.f;
    if (lane < ecount) {
      if constexpr (H == 4) {
        float4 t = reinterpret_cast<const float4*>(a_srcv)[sidx];
        asv[0] = t.x; asv[1] = t.y; asv[2] = t.z; asv[3] = t.w;
      } else {
        asv[0] = a_srcv[sidx];
      }
    }
    float p[H];
#pragma unroll
    for (int j = 0; j < H; ++j) {
      float al = -1e30f;
      if (lane < ecount) {
        float v = asv[j] + adv[j];
        al = (v > 0.f) ? v : 0.2f * v;
      }
      float cm = al;
#pragma unroll
      for (int o = 32; o > 0; o >>= 1) cm = fmaxf(cm, __shfl_xor(cm, o));
      float nm = fmaxf(m[j], cm);
      float scale = __expf(m[j] - nm);
      p[j] = (lane < ecount) ? __expf(al - nm) : 0.f;
      float ps = p[j];
#pragma unroll
      for (int o = 32; o > 0; o >>= 1) ps += __shfl_xor(ps, o);
      ssum[j] = ssum[j] * scale + ps;
      acc[j] *= scale;
      m[j] = nm;
    }
    for (int i = 0; i < ecount; ++i) {
      int s = __shfl(sidx, i);
      const float* xr = xl + (size_t)s * (H * 64);
#pragma unroll
      for (int j = 0; j < H; ++j) {
        float pj = __shfl(p[j], i);
        acc[j] = fmaf(pj, xr[j * 64 + lane], acc[j]);
      }
    }
  }
  size_t ob = (size_t)d * (H * 64);
#pragma unroll
  for (int j = 0; j < H; ++j) {
    float v = acc[j] / (ssum[j] + 1e-16f) + bias[j * 64 + lane];
    out[ob + j * 64 + lane] = (v > 0.f) ? v : (__expf(v) - 1.f); // ELU
  }
}

// layer 3 (H=1) + fused b3 + fc (64->2) + fc_b, writes final output
__global__ __launch_bounds__(256) void gat_final_kernel(const float* __restrict__ xl,
                                                        const float* __restrict__ a_srcv,
                                                        const float* __restrict__ a_dstv,
                                                        const int* __restrict__ csrOff,
                                                        const int* __restrict__ csrSrc,
                                                        const float* __restrict__ b3,
                                                        const float* __restrict__ fcw,
                                                        const float* __restrict__ fcb,
                                                        float* __restrict__ out) {
  int wave = threadIdx.x >> 6;
  int lane = threadIdx.x & 63;
  int d = blockIdx.x * 4 + wave;
  if (d >= N_NODES) return;
  int e0 = csrOff[d], e1 = csrOff[d + 1];
  float adv = a_dstv[d];
  float m = -1e30f, ssum = 0.f, acc = 0.f;
  for (int cb = e0; cb < e1; cb += 64) {
    int ecount = min(64, e1 - cb);
    int sidx = (lane < ecount) ? csrSrc[cb + lane] : 0;
    float al = -1e30f;
    if (lane < ecount) {
      float v = a_srcv[sidx] + adv;
      al = (v > 0.f) ? v : 0.2f * v;
    }
    float cm = al;
#pragma unroll
    for (int o = 32; o > 0; o >>= 1) cm = fmaxf(cm, __shfl_xor(cm, o));
    float nm = fmaxf(m, cm);
    float scale = __expf(m - nm);
    float p = (lane < ecount) ? __expf(al - nm) : 0.f;
    float ps = p;
#pragma unroll
    for (int o = 32; o > 0; o >>= 1) ps += __shfl_xor(ps, o);
    ssum = ssum * scale + ps;
    acc *= scale;
    m = nm;
    for (int i = 0; i < ecount; ++i) {
      int s = __shfl(sidx, i);
      float pj = __shfl(p, i);
      acc = fmaf(pj, xl[(size_t)s * 64 + lane], acc);
    }
  }
  float v = acc / (ssum + 1e-16f) + b3[lane];
  float l0 = v * fcw[lane * 2 + 0];
  float l1 = v * fcw[lane * 2 + 1];
#pragma unroll
  for (int o = 32; o > 0; o >>= 1) {
    l0 += __shfl_xor(l0, o);
    l1 += __shfl_xor(l1, o);
  }
  if (lane == 0) {
    out[2 * d + 0] = l0 + fcb[0];
    out[2 * d + 1] = l1 + fcb[1];
  }
}

extern "C" void kernel_launch(void* const* d_in, const int* in_sizes, int n_in,
                              void* d_out, int out_size, void* d_ws, size_t ws_size,
                              hipStream_t stream) {
  (void)in_sizes; (void)n_in; (void)out_size; (void)ws_size;
  const float* x      = (const float*)d_in[0];
  const void*  eidx   = d_in[1];
  const float* W1     = (const float*)d_in[2];
  const float* att_s1 = (const float*)d_in[3];
  const float* att_d1 = (const float*)d_in[4];
  const float* b1     = (const float*)d_in[5];
  const float* W2     = (const float*)d_in[6];
  const float* att_s2 = (const float*)d_in[7];
  const float* att_d2 = (const float*)d_in[8];
  const float* b2     = (const float*)d_in[9];
  const float* W3     = (const float*)d_in[10];
  const float* att_s3 = (const float*)d_in[11];
  const float* att_d3 = (const float*)d_in[12];
  const float* b3     = (const float*)d_in[13];
  const float* fcw    = (const float*)d_in[14];
  const float* fcb    = (const float*)d_in[15];
  float* out = (float*)d_out;

  char* ws = (char*)d_ws;
  size_t off = 0;
  auto alloc = [&](size_t bytes) -> void* {
    void* p = (void*)(ws + off);
    off += (bytes + 255) & ~(size_t)255;
    return p;
  };
  int*   srcI   = (int*)alloc((size_t)N_EDGES * 4);
  int*   dstI   = (int*)alloc((size_t)N_EDGES * 4);
  int*   cnt    = (int*)alloc((size_t)N_NODES * 4);
  int*   fillc  = (int*)alloc((size_t)N_NODES * 4);
  int*   csrOff = (int*)alloc((size_t)(N_NODES + 1) * 4);
  int*   csrSrc = (int*)alloc((size_t)ETOT * 4);
  int*   flag   = (int*)alloc(256);
  float* a_s    = (float*)alloc((size_t)N_NODES * HEADS * 4);
  float* a_d    = (float*)alloc((size_t)N_NODES * HEADS * 4);
  float* bufA   = (float*)alloc((size_t)N_NODES * F1 * 4); // xl of current layer
  float* bufB   = (float*)alloc((size_t)N_NODES * F1 * 4); // aggregated h
  unsigned short* Ahi = (unsigned short*)alloc((size_t)MP * F1 * 2);
  unsigned short* Alo = (unsigned short*)alloc((size_t)MP * F1 * 2);
  unsigned short* Whi = (unsigned short*)alloc((size_t)F1 * F1 * 2);
  unsigned short* Wlo = (unsigned short*)alloc((size_t)F1 * F1 * 2);
  // total ws use ~167 MB

  hipMemsetAsync(cnt, 0, (size_t)N_NODES * 4, stream);
  hipMemsetAsync(fillc, 0, (size_t)N_NODES * 4, stream);

  detect_idx_kernel<<<1, 256, 0, stream>>>((const unsigned int*)eidx, flag);
  decode_idx_kernel<<<(N_EDGES + 255) / 256, 256, 0, stream>>>(eidx, flag, srcI, dstI);
  hist_kernel<<<(ETOT + 255) / 256, 256, 0, stream>>>(dstI, cnt);
  scan_kernel<<<1, 1024, 0, stream>>>(cnt, csrOff);
  fill_kernel<<<(ETOT + 255) / 256, 256, 0, stream>>>(srcI, dstI, csrOff, fillc, csrSrc);

  const int gn = (N_NODES + 3) / 4;  // 12500
  const int gmb = MP / 16;           // 3128
  const int gx = MP / 128;           // 391

  // ---- Layer 1: x[N,128] @ W1[128,256] ----
  convA_kernel<IN_DIM><<<gmb, 256, 0, stream>>>(x, Ahi, Alo, N_NODES);
  convW_kernel<<<(4096 + 255) / 256, 256, 0, stream>>>(W1, Whi, Wlo, IN_DIM, F1);
  gemm_mfma_kernel<4, 8><<<dim3(gx, 2), 256, 0, stream>>>(Ahi, Alo, Whi, Wlo, bufA, N_NODES, F1);
  att_proj_kernel<4><<<gn, 256, 0, stream>>>(bufA, att_s1, att_d1, a_s, a_d);
  gat_agg_kernel<4><<<gn, 256, 0, stream>>>(bufA, a_s, a_d, csrOff, csrSrc, b1, bufB);

  // ---- Layer 2: h1[N,256] @ W2[256,256] ----
  convA_kernel<F1><<<gmb, 256, 0, stream>>>(bufB, Ahi, Alo, N_NODES);
  convW_kernel<<<(8192 + 255) / 256, 256, 0, stream>>>(W2, Whi, Wlo, F1, F1);
  gemm_mfma_kernel<8, 8><<<dim3(gx, 2), 256, 0, stream>>>(Ahi, Alo, Whi, Wlo, bufA, N_NODES, F1);
  att_proj_kernel<4><<<gn, 256, 0, stream>>>(bufA, att_s2, att_d2, a_s, a_d);
  gat_agg_kernel<4><<<gn, 256, 0, stream>>>(bufA, a_s, a_d, csrOff, csrSrc, b2, bufB);

  // ---- Layer 3: h2[N,256] @ W3[256,64], H=1, fused fc ----
  convA_kernel<F1><<<gmb, 256, 0, stream>>>(bufB, Ahi, Alo, N_NODES);
  convW_kernel<<<(2048 + 255) / 256, 256, 0, stream>>>(W3, Whi, Wlo, F1, HIDC);
  gemm_mfma_kernel<8, 4><<<dim3(gx, 1), 256, 0, stream>>>(Ahi, Alo, Whi, Wlo, bufA, N_NODES, HIDC);
  att_proj_kernel<1><<<gn, 256, 0, stream>>>(bufA, att_s3, att_d3, a_s, a_d);
  gat_final_kernel<<<gn, 256, 0, stream>>>(bufA, a_s, a_d, csrOff, csrSrc, b3, fcw, fcb, out);
}

// Round 3
// 671.396 us; speedup vs baseline: 1.1990x; 1.0194x over previous
//
#include <hip/hip_runtime.h>
#include <math.h>

#define N_NODES 50000
#define N_EDGES 800000
#define ETOT (N_EDGES + N_NODES)
#define IN_DIM 128
#define HIDC 64
#define HEADS 4
#define F1 (HEADS * HIDC) /* 256 */
#define MP 50048 /* N_NODES padded to 128 */

typedef __bf16 bf16x8 __attribute__((ext_vector_type(8)));
typedef float f32x4 __attribute__((ext_vector_type(4)));
typedef unsigned short u16x8 __attribute__((ext_vector_type(8)));

__device__ inline unsigned short f2bf(float f) {
  unsigned u = __builtin_bit_cast(unsigned, f);
  u += 0x7fff + ((u >> 16) & 1);
  return (unsigned short)(u >> 16);
}
__device__ inline float bf2f(unsigned short h) {
  unsigned u = ((unsigned)h) << 16;
  return __builtin_bit_cast(float, u);
}

__device__ inline void gload_lds16(const void* g, void* l) {
  __builtin_amdgcn_global_load_lds(
      (const __attribute__((address_space(1))) unsigned int*)g,
      (__attribute__((address_space(3))) unsigned int*)l, 16, 0, 0);
}

// ---------------- edge-index dtype detect + decode ----------------
__global__ void detect_idx_kernel(const unsigned int* __restrict__ buf, int* __restrict__ flag) {
  __shared__ int any;
  if (threadIdx.x == 0) any = 0;
  __syncthreads();
  for (int i = threadIdx.x; i < 2048; i += blockDim.x)
    if (buf[2 * i + 1] != 0u) any = 1;
  __syncthreads();
  if (threadIdx.x == 0) *flag = any; // 1 => int32, 0 => int64
}

__global__ void decode_idx_kernel(const void* __restrict__ eidx, const int* __restrict__ flag,
                                  int* __restrict__ srcO, int* __restrict__ dstO) {
  int i = blockIdx.x * blockDim.x + threadIdx.x;
  if (i >= N_EDGES) return;
  if (*flag) {
    const int* b = (const int*)eidx;
    srcO[i] = b[i];
    dstO[i] = b[N_EDGES + i];
  } else {
    const long long* b = (const long long*)eidx;
    srcO[i] = (int)b[i];
    dstO[i] = (int)b[N_EDGES + i];
  }
}

// ---------------- CSR build (by dst), self-loops appended ----------------
__global__ void hist_kernel(const int* __restrict__ dst, int* __restrict__ cnt) {
  int i = blockIdx.x * blockDim.x + threadIdx.x;
  if (i >= ETOT) return;
  int d = (i < N_EDGES) ? dst[i] : (i - N_EDGES);
  atomicAdd(&cnt[d], 1);
}

__global__ __launch_bounds__(1024) void scan_kernel(const int* __restrict__ cnt, int* __restrict__ off) {
  const int T = 1024;
  const int n = N_NODES;
  int tid = threadIdx.x;
  int chunk = (n + T - 1) / T;
  int s0 = tid * chunk;
  int s1 = min(s0 + chunk, n);
  int sum = 0;
  for (int i = s0; i < s1; ++i) sum += cnt[i];
  __shared__ int tmp[T];
  tmp[tid] = sum;
  __syncthreads();
  for (int o = 1; o < T; o <<= 1) {
    int t = (tid >= o) ? tmp[tid - o] : 0;
    __syncthreads();
    tmp[tid] += t;
    __syncthreads();
  }
  int run = tmp[tid] - sum;
  for (int i = s0; i < s1; ++i) {
    off[i] = run;
    run += cnt[i];
  }
  if (tid == T - 1) off[n] = run;
}

__global__ void fill_kernel(const int* __restrict__ src, const int* __restrict__ dst,
                            const int* __restrict__ csrOff, int* __restrict__ fillc,
                            int* __restrict__ csrSrc) {
  int i = blockIdx.x * blockDim.x + threadIdx.x;
  if (i >= ETOT) return;
  int s, d;
  if (i < N_EDGES) { s = src[i]; d = dst[i]; } else { s = i - N_EDGES; d = s; }
  int pos = csrOff[d] + atomicAdd(&fillc[d], 1);
  csrSrc[pos] = s;
}

// ---------------- fp32 -> split-bf16 (hi/lo), MFMA fragment-tiled layout ----------------
// A tiled: [MP/16][K/32][kg=4][r=16][j=8]  (each 16x32 fragment = contiguous 1KB)
template <int K>
__global__ __launch_bounds__(256) void convA_kernel(const float* __restrict__ A,
                                                    unsigned short* __restrict__ hi,
                                                    unsigned short* __restrict__ lo, int M) {
  __shared__ float ld[16][264];
  const int mblk = blockIdx.x;
  const int tid = threadIdx.x;
  const int elems = 16 * K;
#pragma unroll
  for (int e = tid * 4; e < elems; e += 1024) {
    int r = e / K, c = e % K;
    int row = mblk * 16 + r;
    float4 v = make_float4(0.f, 0.f, 0.f, 0.f);
    if (row < M) v = *reinterpret_cast<const float4*>(&A[(size_t)row * K + c]);
    ld[r][c + 0] = v.x; ld[r][c + 1] = v.y; ld[r][c + 2] = v.z; ld[r][c + 3] = v.w;
  }
  __syncthreads();
#pragma unroll
  for (int o = tid * 8; o < elems; o += 2048) {
    int r = (o >> 3) & 15;
    int kg = (o >> 7) & 3;
    int kb = o >> 9;
    int k0 = kb * 32 + kg * 8;
    u16x8 h8, l8;
#pragma unroll
    for (int j = 0; j < 8; ++j) {
      float v = ld[r][k0 + j];
      unsigned short h = f2bf(v);
      h8[j] = h;
      l8[j] = f2bf(v - bf2f(h));
    }
    size_t base = ((size_t)mblk * (K >> 5) + kb) * 512 + (size_t)(kg * 16 + r) * 8;
    *reinterpret_cast<u16x8*>(hi + base) = h8;
    *reinterpret_cast<u16x8*>(lo + base) = l8;
  }
}

// W [K,Nw] row-major -> tiled [Nw/16][K/32][kg=4][c=16][j=8]
__global__ void convW_kernel(const float* __restrict__ W, unsigned short* __restrict__ hi,
                             unsigned short* __restrict__ lo, int K, int Nw) {
  int t = blockIdx.x * blockDim.x + threadIdx.x;
  int KB = K >> 5;
  int total = (Nw >> 4) * KB * 64;
  if (t >= total) return;
  int c = t & 15;
  int kg = (t >> 4) & 3;
  int kb = (t >> 6) % KB;
  int nblk = (t >> 6) / KB;
  int n = nblk * 16 + c;
  int k0 = kb * 32 + kg * 8;
  u16x8 h8, l8;
#pragma unroll
  for (int j = 0; j < 8; ++j) {
    float v = W[(size_t)(k0 + j) * Nw + n];
    unsigned short h = f2bf(v);
    h8[j] = h;
    l8[j] = f2bf(v - bf2f(h));
  }
  *reinterpret_cast<u16x8*>(hi + (size_t)t * 8) = h8;
  *reinterpret_cast<u16x8*>(lo + (size_t)t * 8) = l8;
}

// ---------------- split-bf16 MFMA GEMM: C = Ahi*Bhi + Alo*Bhi + Ahi*Blo ----------------
template <int KB, int NB>
__global__ __launch_bounds__(256) void gemm_mfma_kernel(
    const unsigned short* __restrict__ Ahi, const unsigned short* __restrict__ Alo,
    const unsigned short* __restrict__ Bhi, const unsigned short* __restrict__ Blo,
    float* __restrict__ C, int M, int Nout) {
  __shared__ unsigned short As[8 * 512];
  __shared__ unsigned short Bs[NB * 512];
  const int tid = threadIdx.x;
  const int w = tid >> 6, lane = tid & 63;
  const size_t machunk = ((size_t)blockIdx.x * 8 + w * 2) * KB;
  const int nblk0 = blockIdx.y * NB;
  const int laneo = lane * 8;

  f32x4 acc[2][NB];
#pragma unroll
  for (int mi = 0; mi < 2; ++mi)
#pragma unroll
    for (int nj = 0; nj < NB; ++nj) acc[mi][nj] = {0.f, 0.f, 0.f, 0.f};

  const unsigned short* Ap[3] = {Ahi, Alo, Ahi};
  const unsigned short* Bp[3] = {Bhi, Bhi, Blo};
#pragma unroll
  for (int p = 0; p < 3; ++p) {
    const unsigned short* Abase = Ap[p];
    const unsigned short* Bbase = Bp[p];
    for (int kb = 0; kb < KB; ++kb) {
      gload_lds16(Abase + (machunk + kb) * 512 + laneo, As + (w * 2) * 512);
      gload_lds16(Abase + (machunk + (size_t)KB + kb) * 512 + laneo, As + (w * 2 + 1) * 512);
#pragma unroll
      for (int q = 0; q < NB / 4; ++q) {
        int nbl = w * (NB / 4) + q;
        gload_lds16(Bbase + ((size_t)(nblk0 + nbl) * KB + kb) * 512 + laneo, Bs + nbl * 512);
      }
      __syncthreads();
      bf16x8 a0 = *reinterpret_cast<const bf16x8*>(As + (w * 2) * 512 + laneo);
      bf16x8 a1 = *reinterpret_cast<const bf16x8*>(As + (w * 2 + 1) * 512 + laneo);
      bf16x8 b[NB];
#pragma unroll
      for (int nj = 0; nj < NB; ++nj)
        b[nj] = *reinterpret_cast<const bf16x8*>(Bs + nj * 512 + laneo);
#pragma unroll
      for (int nj = 0; nj < NB; ++nj) {
        acc[0][nj] = __builtin_amdgcn_mfma_f32_16x16x32_bf16(a0, b[nj], acc[0][nj], 0, 0, 0);
        acc[1][nj] = __builtin_amdgcn_mfma_f32_16x16x32_bf16(a1, b[nj], acc[1][nj], 0, 0, 0);
      }
      __syncthreads();
    }
  }
  const int col0 = nblk0 * 16 + (lane & 15);
  const int row0 = blockIdx.x * 128 + w * 32 + (lane >> 4) * 4;
#pragma unroll
  for (int mi = 0; mi < 2; ++mi) {
#pragma unroll
    for (int nj = 0; nj < NB; ++nj) {
      int col = col0 + nj * 16;
#pragma unroll
      for (int r = 0; r < 4; ++r) {
        int row = row0 + mi * 16 + r;
        if (row < M) C[(size_t)row * Nout + col] = acc[mi][nj][r];
      }
    }
  }
}

// ---------------- per-node attention logits: a_s[n,h], a_d[n,h] ----------------
template <int H>
__global__ __launch_bounds__(256) void att_proj_kernel(const float* __restrict__ xl,
                                                       const float* __restrict__ atts,
                                                       const float* __restrict__ attd,
                                                       float* __restrict__ a_s,
                                                       float* __restrict__ a_d) {
  int wave = threadIdx.x >> 6;
  int lane = threadIdx.x & 63;
  int node = blockIdx.x * 4 + wave;
  if (node >= N_NODES) return;
  const float* row = xl + (size_t)node * (H * 64);
#pragma unroll
  for (int j = 0; j < H; ++j) {
    float xv = row[j * 64 + lane];
    float ps = xv * atts[j * 64 + lane];
    float pd = xv * attd[j * 64 + lane];
#pragma unroll
    for (int o = 32; o > 0; o >>= 1) {
      ps += __shfl_xor(ps, o);
      pd += __shfl_xor(pd, o);
    }
    if (lane == 0) {
      a_s[node * H + j] = ps;
      a_d[node * H + j] = pd;
    }
  }
}

// ---------------- H=4 edge softmax + aggregate (one wave per dst node) ----------------
// lane L owns output cols 4L..4L+3 (head = L>>4 uniform per lane)
__global__ __launch_bounds__(256) void gat_agg4_kernel(const float* __restrict__ xl,
                                                       const float* __restrict__ a_srcv,
                                                       const float* __restrict__ a_dstv,
                                                       const int* __restrict__ csrOff,
                                                       const int* __restrict__ csrSrc,
                                                       const float* __restrict__ bias,
                                                       float* __restrict__ out) {
  __shared__ float4 plds[4][64];
  __shared__ int slds[4][64];
  const int w = threadIdx.x >> 6;
  const int lane = threadIdx.x & 63;
  const int d = blockIdx.x * 4 + w;
  if (d >= N_NODES) return;
  const int h = lane >> 4; // head this lane accumulates
  int e0 = csrOff[d], e1 = csrOff[d + 1];
  float4 adv = reinterpret_cast<const float4*>(a_dstv)[d];
  float m[4], ssum[4];
#pragma unroll
  for (int j = 0; j < 4; ++j) { m[j] = -1e30f; ssum[j] = 0.f; }
  float4 acc = make_float4(0.f, 0.f, 0.f, 0.f);
  const float4* xl4 = reinterpret_cast<const float4*>(xl);
  const float* pbase = reinterpret_cast<const float*>(&plds[w][0]);

  for (int cb = e0; cb < e1; cb += 64) {
    int ecount = min(64, e1 - cb);
    int sidx = (lane < ecount) ? csrSrc[cb + lane] : 0;
    slds[w][lane] = sidx;
    float4 asv = make_float4(0.f, 0.f, 0.f, 0.f);
    if (lane < ecount) asv = reinterpret_cast<const float4*>(a_srcv)[sidx];
    float p[4], scl[4];
#pragma unroll
    for (int j = 0; j < 4; ++j) {
      float av = (j == 0) ? asv.x : (j == 1) ? asv.y : (j == 2) ? asv.z : asv.w;
      float dv = (j == 0) ? adv.x : (j == 1) ? adv.y : (j == 2) ? adv.z : adv.w;
      float al = -1e30f;
      if (lane < ecount) {
        float v = av + dv;
        al = (v > 0.f) ? v : 0.2f * v;
      }
      float cm = al;
#pragma unroll
      for (int o = 32; o > 0; o >>= 1) cm = fmaxf(cm, __shfl_xor(cm, o));
      float nm = fmaxf(m[j], cm);
      float scale = __expf(m[j] - nm); // first chunk: exp(-inf)=0
      p[j] = (lane < ecount) ? __expf(al - nm) : 0.f;
      float ps = p[j];
#pragma unroll
      for (int o = 32; o > 0; o >>= 1) ps += __shfl_xor(ps, o);
      ssum[j] = ssum[j] * scale + ps;
      m[j] = nm;
      scl[j] = scale;
    }
    plds[w][lane] = make_float4(p[0], p[1], p[2], p[3]);
    float sc = (h == 0) ? scl[0] : (h == 1) ? scl[1] : (h == 2) ? scl[2] : scl[3];
    acc.x *= sc; acc.y *= sc; acc.z *= sc; acc.w *= sc;
    for (int i = 0; i < ecount; ++i) {
      int s = slds[w][i];                       // broadcast ds_read
      float pv = pbase[i * 4 + h];              // broadcast-within-16 ds_read
      float4 xv = xl4[(size_t)s * 64 + lane];   // 1KB coalesced row gather
      acc.x = fmaf(pv, xv.x, acc.x);
      acc.y = fmaf(pv, xv.y, acc.y);
      acc.z = fmaf(pv, xv.z, acc.z);
      acc.w = fmaf(pv, xv.w, acc.w);
    }
  }
  float sm = (h == 0) ? ssum[0] : (h == 1) ? ssum[1] : (h == 2) ? ssum[2] : ssum[3];
  float inv = 1.f / (sm + 1e-16f);
  float4 bv = reinterpret_cast<const float4*>(bias)[lane];
  float4 r;
  r.x = acc.x * inv + bv.x;
  r.y = acc.y * inv + bv.y;
  r.z = acc.z * inv + bv.z;
  r.w = acc.w * inv + bv.w;
  r.x = (r.x > 0.f) ? r.x : (__expf(r.x) - 1.f);
  r.y = (r.y > 0.f) ? r.y : (__expf(r.y) - 1.f);
  r.z = (r.z > 0.f) ? r.z : (__expf(r.z) - 1.f);
  r.w = (r.w > 0.f) ? r.w : (__expf(r.w) - 1.f);
  reinterpret_cast<float4*>(out)[(size_t)d * 64 + lane] = r;
}

// layer 3 (H=1) + fused b3 + fc (64->2) + fc_b; 4 edges per iteration
__global__ __launch_bounds__(256) void gat_final_kernel(const float* __restrict__ xl,
                                                        const float* __restrict__ a_srcv,
                                                        const float* __restrict__ a_dstv,
                                                        const int* __restrict__ csrOff,
                                                        const int* __restrict__ csrSrc,
                                                        const float* __restrict__ b3,
                                                        const float* __restrict__ fcw,
                                                        const float* __restrict__ fcb,
                                                        float* __restrict__ out) {
  __shared__ float plds[4][64];
  __shared__ int slds[4][64];
  const int w = threadIdx.x >> 6;
  const int lane = threadIdx.x & 63;
  const int d = blockIdx.x * 4 + w;
  if (d >= N_NODES) return;
  const int g = lane >> 4;   // edge subgroup
  const int c4 = lane & 15;  // float4 col index
  int e0 = csrOff[d], e1 = csrOff[d + 1];
  float adv = a_dstv[d];
  float m = -1e30f, ssum = 0.f;
  float4 acc = make_float4(0.f, 0.f, 0.f, 0.f);
  const float4* xl4 = reinterpret_cast<const float4*>(xl); // row stride 16

  for (int cb = e0; cb < e1; cb += 64) {
    int ecount = min(64, e1 - cb);
    int sidx = (lane < ecount) ? csrSrc[cb + lane] : 0;
    slds[w][lane] = sidx;
    float al = -1e30f;
    if (lane < ecount) {
      float v = a_srcv[sidx] + adv;
      al = (v > 0.f) ? v : 0.2f * v;
    }
    float cm = al;
#pragma unroll
    for (int o = 32; o > 0; o >>= 1) cm = fmaxf(cm, __shfl_xor(cm, o));
    float nm = fmaxf(m, cm);
    float scale = __expf(m - nm);
    float p = (lane < ecount) ? __expf(al - nm) : 0.f;
    float ps = p;
#pragma unroll
    for (int o = 32; o > 0; o >>= 1) ps += __shfl_xor(ps, o);
    ssum = ssum * scale + ps;
    m = nm;
    plds[w][lane] = p;
    acc.x *= scale; acc.y *= scale; acc.z *= scale; acc.w *= scale;
    for (int i = 0; i < ecount; i += 4) {
      int e = i + g; // <= 63 always; p==0 for e>=ecount
      int s = slds[w][e];
      float pv = plds[w][e];
      float4 xv = xl4[(size_t)s * 16 + c4];
      acc.x = fmaf(pv, xv.x, acc.x);
      acc.y = fmaf(pv, xv.y, acc.y);
      acc.z = fmaf(pv, xv.z, acc.z);
      acc.w = fmaf(pv, xv.w, acc.w);
    }
  }
  // sum the 4 edge-subgroups (lanes differing in bits 4,5)
#pragma unroll
  for (int o = 16; o <= 32; o <<= 1) {
    acc.x += __shfl_xor(acc.x, o);
    acc.y += __shfl_xor(acc.y, o);
    acc.z += __shfl_xor(acc.z, o);
    acc.w += __shfl_xor(acc.w, o);
  }
  float inv = 1.f / (ssum + 1e-16f);
  float4 bv = reinterpret_cast<const float4*>(b3)[c4];
  float4 v;
  v.x = acc.x * inv + bv.x;
  v.y = acc.y * inv + bv.y;
  v.z = acc.z * inv + bv.z;
  v.w = acc.w * inv + bv.w;
  const float2* fcw2 = reinterpret_cast<const float2*>(fcw);
  float2 w0 = fcw2[c4 * 4 + 0], w1 = fcw2[c4 * 4 + 1], w2 = fcw2[c4 * 4 + 2], w3 = fcw2[c4 * 4 + 3];
  float l0 = v.x * w0.x + v.y * w1.x + v.z * w2.x + v.w * w3.x;
  float l1 = v.x * w0.y + v.y * w1.y + v.z * w2.y + v.w * w3.y;
#pragma unroll
  for (int o = 1; o <= 8; o <<= 1) {
    l0 += __shfl_xor(l0, o);
    l1 += __shfl_xor(l1, o);
  }
  if (lane == 0) {
    out[2 * d + 0] = l0 + fcb[0];
    out[2 * d + 1] = l1 + fcb[1];
  }
}

extern "C" void kernel_launch(void* const* d_in, const int* in_sizes, int n_in,
                              void* d_out, int out_size, void* d_ws, size_t ws_size,
                              hipStream_t stream) {
  (void)in_sizes; (void)n_in; (void)out_size; (void)ws_size;
  const float* x      = (const float*)d_in[0];
  const void*  eidx   = d_in[1];
  const float* W1     = (const float*)d_in[2];
  const float* att_s1 = (const float*)d_in[3];
  const float* att_d1 = (const float*)d_in[4];
  const float* b1     = (const float*)d_in[5];
  const float* W2     = (const float*)d_in[6];
  const float* att_s2 = (const float*)d_in[7];
  const float* att_d2 = (const float*)d_in[8];
  const float* b2     = (const float*)d_in[9];
  const float* W3     = (const float*)d_in[10];
  const float* att_s3 = (const float*)d_in[11];
  const float* att_d3 = (const float*)d_in[12];
  const float* b3     = (const float*)d_in[13];
  const float* fcw    = (const float*)d_in[14];
  const float* fcb    = (const float*)d_in[15];
  float* out = (float*)d_out;

  char* ws = (char*)d_ws;
  size_t off = 0;
  auto alloc = [&](size_t bytes) -> void* {
    void* p = (void*)(ws + off);
    off += (bytes + 255) & ~(size_t)255;
    return p;
  };
  int*   srcI   = (int*)alloc((size_t)N_EDGES * 4);
  int*   dstI   = (int*)alloc((size_t)N_EDGES * 4);
  int*   cnt    = (int*)alloc((size_t)N_NODES * 4);
  int*   fillc  = (int*)alloc((size_t)N_NODES * 4);
  int*   csrOff = (int*)alloc((size_t)(N_NODES + 1) * 4);
  int*   csrSrc = (int*)alloc((size_t)ETOT * 4);
  int*   flag   = (int*)alloc(256);
  float* a_s    = (float*)alloc((size_t)N_NODES * HEADS * 4);
  float* a_d    = (float*)alloc((size_t)N_NODES * HEADS * 4);
  float* bufA   = (float*)alloc((size_t)N_NODES * F1 * 4);
  float* bufB   = (float*)alloc((size_t)N_NODES * F1 * 4);
  unsigned short* Ahi = (unsigned short*)alloc((size_t)MP * F1 * 2);
  unsigned short* Alo = (unsigned short*)alloc((size_t)MP * F1 * 2);
  unsigned short* Whi = (unsigned short*)alloc((size_t)F1 * F1 * 2);
  unsigned short* Wlo = (unsigned short*)alloc((size_t)F1 * F1 * 2);

  hipMemsetAsync(cnt, 0, (size_t)N_NODES * 4, stream);
  hipMemsetAsync(fillc, 0, (size_t)N_NODES * 4, stream);

  detect_idx_kernel<<<1, 256, 0, stream>>>((const unsigned int*)eidx, flag);
  decode_idx_kernel<<<(N_EDGES + 255) / 256, 256, 0, stream>>>(eidx, flag, srcI, dstI);
  hist_kernel<<<(ETOT + 255) / 256, 256, 0, stream>>>(dstI, cnt);
  scan_kernel<<<1, 1024, 0, stream>>>(cnt, csrOff);
  fill_kernel<<<(ETOT + 255) / 256, 256, 0, stream>>>(srcI, dstI, csrOff, fillc, csrSrc);

  const int gn = (N_NODES + 3) / 4;  // 12500
  const int gmb = MP / 16;           // 3128
  const int gx = MP / 128;           // 391

  // ---- Layer 1: x[N,128] @ W1[128,256] ----
  convA_kernel<IN_DIM><<<gmb, 256, 0, stream>>>(x, Ahi, Alo, N_NODES);
  convW_kernel<<<(4096 + 255) / 256, 256, 0, stream>>>(W1, Whi, Wlo, IN_DIM, F1);
  gemm_mfma_kernel<4, 8><<<dim3(gx, 2), 256, 0, stream>>>(Ahi, Alo, Whi, Wlo, bufA, N_NODES, F1);
  att_proj_kernel<4><<<gn, 256, 0, stream>>>(bufA, att_s1, att_d1, a_s, a_d);
  gat_agg4_kernel<<<gn, 256, 0, stream>>>(bufA, a_s, a_d, csrOff, csrSrc, b1, bufB);

  // ---- Layer 2: h1[N,256] @ W2[256,256] ----
  convA_kernel<F1><<<gmb, 256, 0, stream>>>(bufB, Ahi, Alo, N_NODES);
  convW_kernel<<<(8192 + 255) / 256, 256, 0, stream>>>(W2, Whi, Wlo, F1, F1);
  gemm_mfma_kernel<8, 8><<<dim3(gx, 2), 256, 0, stream>>>(Ahi, Alo, Whi, Wlo, bufA, N_NODES, F1);
  att_proj_kernel<4><<<gn, 256, 0, stream>>>(bufA, att_s2, att_d2, a_s, a_d);
  gat_agg4_kernel<<<gn, 256, 0, stream>>>(bufA, a_s, a_d, csrOff, csrSrc, b2, bufB);

  // ---- Layer 3: h2[N,256] @ W3[256,64], H=1, fused fc ----
  convA_kernel<F1><<<gmb, 256, 0, stream>>>(bufB, Ahi, Alo, N_NODES);
  convW_kernel<<<(2048 + 255) / 256, 256, 0, stream>>>(W3, Whi, Wlo, F1, HIDC);
  gemm_mfma_kernel<8, 4><<<dim3(gx, 1), 256, 0, stream>>>(Ahi, Alo, Whi, Wlo, bufA, N_NODES, HIDC);
  att_proj_kernel<1><<<gn, 256, 0, stream>>>(bufA, att_s3, att_d3, a_s, a_d);
  gat_final_kernel<<<gn, 256, 0, stream>>>(bufA, a_s, a_d, csrOff, csrSrc, b3, fcw, fcb, out);
}

// Round 4
// 526.433 us; speedup vs baseline: 1.5292x; 1.2754x over previous
//
#include <hip/hip_runtime.h>
#include <hip/hip_fp16.h>
#include <math.h>

#define N_NODES 50000
#define N_EDGES 800000
#define ETOT (N_EDGES + N_NODES)
#define IN_DIM 128
#define HIDC 64
#define HEADS 4
#define F1 (HEADS * HIDC) /* 256 */
#define MP 50048 /* N_NODES padded to 128 */

typedef __bf16 bf16x8 __attribute__((ext_vector_type(8)));
typedef float f32x4 __attribute__((ext_vector_type(4)));
typedef unsigned short u16x8 __attribute__((ext_vector_type(8)));

__device__ inline unsigned short f2bf(float f) {
  unsigned u = __builtin_bit_cast(unsigned, f);
  u += 0x7fff + ((u >> 16) & 1);
  return (unsigned short)(u >> 16);
}
__device__ inline float bf2f(unsigned short h) {
  unsigned u = ((unsigned)h) << 16;
  return __builtin_bit_cast(float, u);
}

__device__ inline void gload_lds16(const void* g, void* l) {
  __builtin_amdgcn_global_load_lds(
      (const __attribute__((address_space(1))) unsigned int*)g,
      (__attribute__((address_space(3))) unsigned int*)l, 16, 0, 0);
}

// ---------------- edge-index dtype detect + decode ----------------
__global__ void detect_idx_kernel(const unsigned int* __restrict__ buf, int* __restrict__ flag) {
  __shared__ int any;
  if (threadIdx.x == 0) any = 0;
  __syncthreads();
  for (int i = threadIdx.x; i < 2048; i += blockDim.x)
    if (buf[2 * i + 1] != 0u) any = 1;
  __syncthreads();
  if (threadIdx.x == 0) *flag = any; // 1 => int32, 0 => int64
}

__global__ void decode_idx_kernel(const void* __restrict__ eidx, const int* __restrict__ flag,
                                  int* __restrict__ srcO, int* __restrict__ dstO) {
  int i = blockIdx.x * blockDim.x + threadIdx.x;
  if (i >= N_EDGES) return;
  if (*flag) {
    const int* b = (const int*)eidx;
    srcO[i] = b[i];
    dstO[i] = b[N_EDGES + i];
  } else {
    const long long* b = (const long long*)eidx;
    srcO[i] = (int)b[i];
    dstO[i] = (int)b[N_EDGES + i];
  }
}

// ---------------- CSR build (by dst), self-loops appended ----------------
__global__ void hist_kernel(const int* __restrict__ dst, int* __restrict__ cnt) {
  int i = blockIdx.x * blockDim.x + threadIdx.x;
  if (i >= ETOT) return;
  int d = (i < N_EDGES) ? dst[i] : (i - N_EDGES);
  atomicAdd(&cnt[d], 1);
}

__global__ __launch_bounds__(1024) void scan_kernel(const int* __restrict__ cnt, int* __restrict__ off) {
  const int T = 1024;
  const int n = N_NODES;
  int tid = threadIdx.x;
  int chunk = (n + T - 1) / T;
  int s0 = tid * chunk;
  int s1 = min(s0 + chunk, n);
  int sum = 0;
  for (int i = s0; i < s1; ++i) sum += cnt[i];
  __shared__ int tmp[T];
  tmp[tid] = sum;
  __syncthreads();
  for (int o = 1; o < T; o <<= 1) {
    int t = (tid >= o) ? tmp[tid - o] : 0;
    __syncthreads();
    tmp[tid] += t;
    __syncthreads();
  }
  int run = tmp[tid] - sum;
  for (int i = s0; i < s1; ++i) {
    off[i] = run;
    run += cnt[i];
  }
  if (tid == T - 1) off[n] = run;
}

__global__ void fill_kernel(const int* __restrict__ src, const int* __restrict__ dst,
                            const int* __restrict__ csrOff, int* __restrict__ fillc,
                            int* __restrict__ csrSrc) {
  int i = blockIdx.x * blockDim.x + threadIdx.x;
  if (i >= ETOT) return;
  int s, d;
  if (i < N_EDGES) { s = src[i]; d = dst[i]; } else { s = i - N_EDGES; d = s; }
  int pos = csrOff[d] + atomicAdd(&fillc[d], 1);
  csrSrc[pos] = s;
}

// ---------------- fp32 -> split-bf16 (hi/lo), MFMA fragment-tiled layout ----------------
// tiled: [MP/16][K/32][kg=4][r=16][j=8]  (each 16x32 fragment = contiguous 1KB)
template <int K>
__global__ __launch_bounds__(256) void convA_kernel(const float* __restrict__ A,
                                                    unsigned short* __restrict__ hi,
                                                    unsigned short* __restrict__ lo, int M) {
  __shared__ float ld[16][264];
  const int mblk = blockIdx.x;
  const int tid = threadIdx.x;
  const int elems = 16 * K;
#pragma unroll
  for (int e = tid * 4; e < elems; e += 1024) {
    int r = e / K, c = e % K;
    int row = mblk * 16 + r;
    float4 v = make_float4(0.f, 0.f, 0.f, 0.f);
    if (row < M) v = *reinterpret_cast<const float4*>(&A[(size_t)row * K + c]);
    ld[r][c + 0] = v.x; ld[r][c + 1] = v.y; ld[r][c + 2] = v.z; ld[r][c + 3] = v.w;
  }
  __syncthreads();
#pragma unroll
  for (int o = tid * 8; o < elems; o += 2048) {
    int r = (o >> 3) & 15;
    int kg = (o >> 7) & 3;
    int kb = o >> 9;
    int k0 = kb * 32 + kg * 8;
    u16x8 h8, l8;
#pragma unroll
    for (int j = 0; j < 8; ++j) {
      float v = ld[r][k0 + j];
      unsigned short h = f2bf(v);
      h8[j] = h;
      l8[j] = f2bf(v - bf2f(h));
    }
    size_t base = ((size_t)mblk * (K >> 5) + kb) * 512 + (size_t)(kg * 16 + r) * 8;
    *reinterpret_cast<u16x8*>(hi + base) = h8;
    *reinterpret_cast<u16x8*>(lo + base) = l8;
  }
}

// W [K,Nw] row-major -> tiled [Nw/16][K/32][kg=4][c=16][j=8]
__global__ void convW_kernel(const float* __restrict__ W, unsigned short* __restrict__ hi,
                             unsigned short* __restrict__ lo, int K, int Nw) {
  int t = blockIdx.x * blockDim.x + threadIdx.x;
  int KB = K >> 5;
  int total = (Nw >> 4) * KB * 64;
  if (t >= total) return;
  int c = t & 15;
  int kg = (t >> 4) & 3;
  int kb = (t >> 6) % KB;
  int nblk = (t >> 6) / KB;
  int n = nblk * 16 + c;
  int k0 = kb * 32 + kg * 8;
  u16x8 h8, l8;
#pragma unroll
  for (int j = 0; j < 8; ++j) {
    float v = W[(size_t)(k0 + j) * Nw + n];
    unsigned short h = f2bf(v);
    h8[j] = h;
    l8[j] = f2bf(v - bf2f(h));
  }
  *reinterpret_cast<u16x8*>(hi + (size_t)t * 8) = h8;
  *reinterpret_cast<u16x8*>(lo + (size_t)t * 8) = l8;
}

// ---------------- split-bf16 MFMA GEMM: C = Ahi*Bhi + Alo*Bhi + Ahi*Blo -> fp16 out ----------------
template <int KB, int NB>
__global__ __launch_bounds__(256) void gemm_mfma_kernel(
    const unsigned short* __restrict__ Ahi, const unsigned short* __restrict__ Alo,
    const unsigned short* __restrict__ Bhi, const unsigned short* __restrict__ Blo,
    __half* __restrict__ Ch, int M, int Nout) {
  __shared__ unsigned short As[8 * 512];
  __shared__ unsigned short Bs[NB * 512];
  const int tid = threadIdx.x;
  const int w = tid >> 6, lane = tid & 63;
  const size_t machunk = ((size_t)blockIdx.x * 8 + w * 2) * KB;
  const int nblk0 = blockIdx.y * NB;
  const int laneo = lane * 8;

  f32x4 acc[2][NB];
#pragma unroll
  for (int mi = 0; mi < 2; ++mi)
#pragma unroll
    for (int nj = 0; nj < NB; ++nj) acc[mi][nj] = {0.f, 0.f, 0.f, 0.f};

  const unsigned short* Ap[3] = {Ahi, Alo, Ahi};
  const unsigned short* Bp[3] = {Bhi, Bhi, Blo};
#pragma unroll
  for (int p = 0; p < 3; ++p) {
    const unsigned short* Abase = Ap[p];
    const unsigned short* Bbase = Bp[p];
    for (int kb = 0; kb < KB; ++kb) {
      gload_lds16(Abase + (machunk + kb) * 512 + laneo, As + (w * 2) * 512);
      gload_lds16(Abase + (machunk + (size_t)KB + kb) * 512 + laneo, As + (w * 2 + 1) * 512);
#pragma unroll
      for (int q = 0; q < NB / 4; ++q) {
        int nbl = w * (NB / 4) + q;
        gload_lds16(Bbase + ((size_t)(nblk0 + nbl) * KB + kb) * 512 + laneo, Bs + nbl * 512);
      }
      __syncthreads();
      bf16x8 a0 = *reinterpret_cast<const bf16x8*>(As + (w * 2) * 512 + laneo);
      bf16x8 a1 = *reinterpret_cast<const bf16x8*>(As + (w * 2 + 1) * 512 + laneo);
      bf16x8 b[NB];
#pragma unroll
      for (int nj = 0; nj < NB; ++nj)
        b[nj] = *reinterpret_cast<const bf16x8*>(Bs + nj * 512 + laneo);
#pragma unroll
      for (int nj = 0; nj < NB; ++nj) {
        acc[0][nj] = __builtin_amdgcn_mfma_f32_16x16x32_bf16(a0, b[nj], acc[0][nj], 0, 0, 0);
        acc[1][nj] = __builtin_amdgcn_mfma_f32_16x16x32_bf16(a1, b[nj], acc[1][nj], 0, 0, 0);
      }
      __syncthreads();
    }
  }
  const int col0 = nblk0 * 16 + (lane & 15);
  const int row0 = blockIdx.x * 128 + w * 32 + (lane >> 4) * 4;
#pragma unroll
  for (int mi = 0; mi < 2; ++mi) {
#pragma unroll
    for (int nj = 0; nj < NB; ++nj) {
      int col = col0 + nj * 16;
#pragma unroll
      for (int r = 0; r < 4; ++r) {
        int row = row0 + mi * 16 + r;
        if (row < M) Ch[(size_t)row * Nout + col] = __float2half(acc[mi][nj][r]);
      }
    }
  }
}

// ---------------- per-node attention logits from fp16 xl ----------------
template <int H>
__global__ __launch_bounds__(256) void att_proj_kernel(const __half* __restrict__ xl,
                                                       const float* __restrict__ atts,
                                                       const float* __restrict__ attd,
                                                       float* __restrict__ a_s,
                                                       float* __restrict__ a_d) {
  int wave = threadIdx.x >> 6;
  int lane = threadIdx.x & 63;
  int node = blockIdx.x * 4 + wave;
  if (node >= N_NODES) return;
  const __half* row = xl + (size_t)node * (H * 64);
#pragma unroll
  for (int j = 0; j < H; ++j) {
    float xv = __half2float(row[j * 64 + lane]);
    float ps = xv * atts[j * 64 + lane];
    float pd = xv * attd[j * 64 + lane];
#pragma unroll
    for (int o = 32; o > 0; o >>= 1) {
      ps += __shfl_xor(ps, o);
      pd += __shfl_xor(pd, o);
    }
    if (lane == 0) {
      a_s[node * H + j] = ps;
      a_d[node * H + j] = pd;
    }
  }
}

// ---------------- H=4 edge softmax + aggregate; fp16 gather; writes split-bf16 tiled + ELU ----------------
// lane L owns output cols 4L..4L+3 (head = L>>4 uniform per lane). Output layout == convA (K=256, KB=8).
__global__ __launch_bounds__(256) void gat_agg4_kernel(const __half* __restrict__ xlh,
                                                       const float* __restrict__ a_srcv,
                                                       const float* __restrict__ a_dstv,
                                                       const int* __restrict__ csrOff,
                                                       const int* __restrict__ csrSrc,
                                                       const float* __restrict__ bias,
                                                       unsigned short* __restrict__ outHi,
                                                       unsigned short* __restrict__ outLo) {
  __shared__ float4 plds[4][64];
  __shared__ int slds[4][64];
  const int w = threadIdx.x >> 6;
  const int lane = threadIdx.x & 63;
  const int d = blockIdx.x * 4 + w;
  if (d >= N_NODES) return;
  const int h = lane >> 4; // head this lane accumulates
  int e0 = csrOff[d], e1 = csrOff[d + 1];
  float4 adv = reinterpret_cast<const float4*>(a_dstv)[d];
  float m[4], ssum[4];
#pragma unroll
  for (int j = 0; j < 4; ++j) { m[j] = -1e30f; ssum[j] = 0.f; }
  float4 acc = make_float4(0.f, 0.f, 0.f, 0.f);
  const float* pbase = reinterpret_cast<const float*>(&plds[w][0]);

  for (int cb = e0; cb < e1; cb += 64) {
    int ecount = min(64, e1 - cb);
    int sidx = (lane < ecount) ? csrSrc[cb + lane] : 0;
    slds[w][lane] = sidx;
    float4 asv = make_float4(0.f, 0.f, 0.f, 0.f);
    if (lane < ecount) asv = reinterpret_cast<const float4*>(a_srcv)[sidx];
    float p[4], scl[4];
#pragma unroll
    for (int j = 0; j < 4; ++j) {
      float av = (j == 0) ? asv.x : (j == 1) ? asv.y : (j == 2) ? asv.z : asv.w;
      float dv = (j == 0) ? adv.x : (j == 1) ? adv.y : (j == 2) ? adv.z : adv.w;
      float al = -1e30f;
      if (lane < ecount) {
        float v = av + dv;
        al = (v > 0.f) ? v : 0.2f * v;
      }
      float cm = al;
#pragma unroll
      for (int o = 32; o > 0; o >>= 1) cm = fmaxf(cm, __shfl_xor(cm, o));
      float nm = fmaxf(m[j], cm);
      float scale = __expf(m[j] - nm); // first chunk: exp(-inf)=0
      p[j] = (lane < ecount) ? __expf(al - nm) : 0.f;
      float ps = p[j];
#pragma unroll
      for (int o = 32; o > 0; o >>= 1) ps += __shfl_xor(ps, o);
      ssum[j] = ssum[j] * scale + ps;
      m[j] = nm;
      scl[j] = scale;
    }
    plds[w][lane] = make_float4(p[0], p[1], p[2], p[3]);
    float sc = (h == 0) ? scl[0] : (h == 1) ? scl[1] : (h == 2) ? scl[2] : scl[3];
    acc.x *= sc; acc.y *= sc; acc.z *= sc; acc.w *= sc;
    for (int i = 0; i < ecount; ++i) {
      int s = slds[w][i];          // broadcast ds_read
      float pv = pbase[i * 4 + h]; // broadcast-within-16 ds_read
      uint2 raw = *reinterpret_cast<const uint2*>(xlh + (size_t)s * 256 + lane * 4); // 512B/row coalesced
      float2 f0 = __half22float2(__builtin_bit_cast(__half2, raw.x));
      float2 f1 = __half22float2(__builtin_bit_cast(__half2, raw.y));
      acc.x = fmaf(pv, f0.x, acc.x);
      acc.y = fmaf(pv, f0.y, acc.y);
      acc.z = fmaf(pv, f1.x, acc.z);
      acc.w = fmaf(pv, f1.y, acc.w);
    }
  }
  float sm = (h == 0) ? ssum[0] : (h == 1) ? ssum[1] : (h == 2) ? ssum[2] : ssum[3];
  float inv = 1.f / (sm + 1e-16f);
  float4 bv = reinterpret_cast<const float4*>(bias)[lane];
  float4 r;
  r.x = acc.x * inv + bv.x;
  r.y = acc.y * inv + bv.y;
  r.z = acc.z * inv + bv.z;
  r.w = acc.w * inv + bv.w;
  r.x = (r.x > 0.f) ? r.x : (__expf(r.x) - 1.f);
  r.y = (r.y > 0.f) ? r.y : (__expf(r.y) - 1.f);
  r.z = (r.z > 0.f) ? r.z : (__expf(r.z) - 1.f);
  r.w = (r.w > 0.f) ? r.w : (__expf(r.w) - 1.f);
  // split-bf16 write in MFMA-tiled layout (col c=4L+i: kb=L>>3, kg=(L>>1)&3, j=(L&1)*4+i)
  ushort4 hh, ll;
  hh.x = f2bf(r.x); ll.x = f2bf(r.x - bf2f(hh.x));
  hh.y = f2bf(r.y); ll.y = f2bf(r.y - bf2f(hh.y));
  hh.z = f2bf(r.z); ll.z = f2bf(r.z - bf2f(hh.z));
  hh.w = f2bf(r.w); ll.w = f2bf(r.w - bf2f(hh.w));
  const int mblk = d >> 4, rr = d & 15;
  const int kb = lane >> 3, kg = (lane >> 1) & 3, jj = (lane & 1) * 4;
  size_t base = ((size_t)mblk * 8 + kb) * 512 + (size_t)(kg * 16 + rr) * 8 + jj;
  *reinterpret_cast<ushort4*>(outHi + base) = hh;
  *reinterpret_cast<ushort4*>(outLo + base) = ll;
}

// layer 3 (H=1) + fused b3 + fc (64->2) + fc_b; fp16 gather; 4 edges per iteration
__global__ __launch_bounds__(256) void gat_final_kernel(const __half* __restrict__ xlh,
                                                        const float* __restrict__ a_srcv,
                                                        const float* __restrict__ a_dstv,
                                                        const int* __restrict__ csrOff,
                                                        const int* __restrict__ csrSrc,
                                                        const float* __restrict__ b3,
                                                        const float* __restrict__ fcw,
                                                        const float* __restrict__ fcb,
                                                        float* __restrict__ out) {
  __shared__ float plds[4][64];
  __shared__ int slds[4][64];
  const int w = threadIdx.x >> 6;
  const int lane = threadIdx.x & 63;
  const int d = blockIdx.x * 4 + w;
  if (d >= N_NODES) return;
  const int g = lane >> 4;   // edge subgroup
  const int c4 = lane & 15;  // 4-col group index
  int e0 = csrOff[d], e1 = csrOff[d + 1];
  float adv = a_dstv[d];
  float m = -1e30f, ssum = 0.f;
  float4 acc = make_float4(0.f, 0.f, 0.f, 0.f);

  for (int cb = e0; cb < e1; cb += 64) {
    int ecount = min(64, e1 - cb);
    int sidx = (lane < ecount) ? csrSrc[cb + lane] : 0;
    slds[w][lane] = sidx;
    float al = -1e30f;
    if (lane < ecount) {
      float v = a_srcv[sidx] + adv;
      al = (v > 0.f) ? v : 0.2f * v;
    }
    float cm = al;
#pragma unroll
    for (int o = 32; o > 0; o >>= 1) cm = fmaxf(cm, __shfl_xor(cm, o));
    float nm = fmaxf(m, cm);
    float scale = __expf(m - nm);
    float p = (lane < ecount) ? __expf(al - nm) : 0.f;
    float ps = p;
#pragma unroll
    for (int o = 32; o > 0; o >>= 1) ps += __shfl_xor(ps, o);
    ssum = ssum * scale + ps;
    m = nm;
    plds[w][lane] = p;
    acc.x *= scale; acc.y *= scale; acc.z *= scale; acc.w *= scale;
    for (int i = 0; i < ecount; i += 4) {
      int e = i + g; // <= 63 always; p==0 for e>=ecount
      int s = slds[w][e];
      float pv = plds[w][e];
      uint2 raw = *reinterpret_cast<const uint2*>(xlh + (size_t)s * 64 + c4 * 4); // 128B/row
      float2 f0 = __half22float2(__builtin_bit_cast(__half2, raw.x));
      float2 f1 = __half22float2(__builtin_bit_cast(__half2, raw.y));
      acc.x = fmaf(pv, f0.x, acc.x);
      acc.y = fmaf(pv, f0.y, acc.y);
      acc.z = fmaf(pv, f1.x, acc.z);
      acc.w = fmaf(pv, f1.y, acc.w);
    }
  }
  // sum the 4 edge-subgroups (lanes differing in bits 4,5)
#pragma unroll
  for (int o = 16; o <= 32; o <<= 1) {
    acc.x += __shfl_xor(acc.x, o);
    acc.y += __shfl_xor(acc.y, o);
    acc.z += __shfl_xor(acc.z, o);
    acc.w += __shfl_xor(acc.w, o);
  }
  float inv = 1.f / (ssum + 1e-16f);
  float4 bv = reinterpret_cast<const float4*>(b3)[c4];
  float4 v;
  v.x = acc.x * inv + bv.x;
  v.y = acc.y * inv + bv.y;
  v.z = acc.z * inv + bv.z;
  v.w = acc.w * inv + bv.w;
  const float2* fcw2 = reinterpret_cast<const float2*>(fcw);
  float2 w0 = fcw2[c4 * 4 + 0], w1 = fcw2[c4 * 4 + 1], w2 = fcw2[c4 * 4 + 2], w3 = fcw2[c4 * 4 + 3];
  float l0 = v.x * w0.x + v.y * w1.x + v.z * w2.x + v.w * w3.x;
  float l1 = v.x * w0.y + v.y * w1.y + v.z * w2.y + v.w * w3.y;
#pragma unroll
  for (int o = 1; o <= 8; o <<= 1) {
    l0 += __shfl_xor(l0, o);
    l1 += __shfl_xor(l1, o);
  }
  if (lane == 0) {
    out[2 * d + 0] = l0 + fcb[0];
    out[2 * d + 1] = l1 + fcb[1];
  }
}

extern "C" void kernel_launch(void* const* d_in, const int* in_sizes, int n_in,
                              void* d_out, int out_size, void* d_ws, size_t ws_size,
                              hipStream_t stream) {
  (void)in_sizes; (void)n_in; (void)out_size; (void)ws_size;
  const float* x      = (const float*)d_in[0];
  const void*  eidx   = d_in[1];
  const float* W1     = (const float*)d_in[2];
  const float* att_s1 = (const float*)d_in[3];
  const float* att_d1 = (const float*)d_in[4];
  const float* b1     = (const float*)d_in[5];
  const float* W2     = (const float*)d_in[6];
  const float* att_s2 = (const float*)d_in[7];
  const float* att_d2 = (const float*)d_in[8];
  const float* b2     = (const float*)d_in[9];
  const float* W3     = (const float*)d_in[10];
  const float* att_s3 = (const float*)d_in[11];
  const float* att_d3 = (const float*)d_in[12];
  const float* b3     = (const float*)d_in[13];
  const float* fcw    = (const float*)d_in[14];
  const float* fcb    = (const float*)d_in[15];
  float* out = (float*)d_out;

  char* ws = (char*)d_ws;
  size_t off = 0;
  auto alloc = [&](size_t bytes) -> void* {
    void* p = (void*)(ws + off);
    off += (bytes + 255) & ~(size_t)255;
    return p;
  };
  int*   srcI   = (int*)alloc((size_t)N_EDGES * 4);
  int*   dstI   = (int*)alloc((size_t)N_EDGES * 4);
  int*   cnt    = (int*)alloc((size_t)N_NODES * 4);
  int*   fillc  = (int*)alloc((size_t)N_NODES * 4);
  int*   csrOff = (int*)alloc((size_t)(N_NODES + 1) * 4);
  int*   csrSrc = (int*)alloc((size_t)ETOT * 4);
  int*   flag   = (int*)alloc(256);
  float* a_s    = (float*)alloc((size_t)N_NODES * HEADS * 4);
  float* a_d    = (float*)alloc((size_t)N_NODES * HEADS * 4);
  unsigned short* Ahi = (unsigned short*)alloc((size_t)MP * F1 * 2);
  unsigned short* Alo = (unsigned short*)alloc((size_t)MP * F1 * 2);
  unsigned short* Whi = (unsigned short*)alloc((size_t)F1 * F1 * 2);
  unsigned short* Wlo = (unsigned short*)alloc((size_t)F1 * F1 * 2);
  __half* xlh  = (__half*)alloc((size_t)MP * F1 * 2);  // fp16 xl (layers 1,2)
  __half* xlh3 = (__half*)alloc((size_t)MP * HIDC * 2); // fp16 xl (layer 3)

  hipMemsetAsync(cnt, 0, (size_t)N_NODES * 4, stream);
  hipMemsetAsync(fillc, 0, (size_t)N_NODES * 4, stream);

  detect_idx_kernel<<<1, 256, 0, stream>>>((const unsigned int*)eidx, flag);
  decode_idx_kernel<<<(N_EDGES + 255) / 256, 256, 0, stream>>>(eidx, flag, srcI, dstI);
  hist_kernel<<<(ETOT + 255) / 256, 256, 0, stream>>>(dstI, cnt);
  scan_kernel<<<1, 1024, 0, stream>>>(cnt, csrOff);
  fill_kernel<<<(ETOT + 255) / 256, 256, 0, stream>>>(srcI, dstI, csrOff, fillc, csrSrc);

  const int gn = (N_NODES + 3) / 4;  // 12500
  const int gmb = MP / 16;           // 3128
  const int gx = MP / 128;           // 391

  // ---- Layer 1: x[N,128] @ W1[128,256] ----
  convA_kernel<IN_DIM><<<gmb, 256, 0, stream>>>(x, Ahi, Alo, N_NODES);
  convW_kernel<<<(4096 + 255) / 256, 256, 0, stream>>>(W1, Whi, Wlo, IN_DIM, F1);
  gemm_mfma_kernel<4, 8><<<dim3(gx, 2), 256, 0, stream>>>(Ahi, Alo, Whi, Wlo, xlh, N_NODES, F1);
  att_proj_kernel<4><<<gn, 256, 0, stream>>>(xlh, att_s1, att_d1, a_s, a_d);
  gat_agg4_kernel<<<gn, 256, 0, stream>>>(xlh, a_s, a_d, csrOff, csrSrc, b1, Ahi, Alo);

  // ---- Layer 2: h1[N,256] @ W2[256,256] (A from agg epilogue, tiled) ----
  convW_kernel<<<(8192 + 255) / 256, 256, 0, stream>>>(W2, Whi, Wlo, F1, F1);
  gemm_mfma_kernel<8, 8><<<dim3(gx, 2), 256, 0, stream>>>(Ahi, Alo, Whi, Wlo, xlh, N_NODES, F1);
  att_proj_kernel<4><<<gn, 256, 0, stream>>>(xlh, att_s2, att_d2, a_s, a_d);
  gat_agg4_kernel<<<gn, 256, 0, stream>>>(xlh, a_s, a_d, csrOff, csrSrc, b2, Ahi, Alo);

  // ---- Layer 3: h2[N,256] @ W3[256,64], H=1, fused fc ----
  convW_kernel<<<(2048 + 255) / 256, 256, 0, stream>>>(W3, Whi, Wlo, F1, HIDC);
  gemm_mfma_kernel<8, 4><<<dim3(gx, 1), 256, 0, stream>>>(Ahi, Alo, Whi, Wlo, xlh3, N_NODES, HIDC);
  att_proj_kernel<1><<<gn, 256, 0, stream>>>(xlh3, att_s3, att_d3, a_s, a_d);
  gat_final_kernel<<<gn, 256, 0, stream>>>(xlh3, a_s, a_d, csrOff, csrSrc, b3, fcw, fcb, out);
}

// Round 5
// 473.106 us; speedup vs baseline: 1.7016x; 1.1127x over previous
//
#include <hip/hip_runtime.h>
#include <hip/hip_fp16.h>
#include <math.h>

#define N_NODES 50000
#define N_EDGES 800000
#define ETOT (N_EDGES + N_NODES)
#define IN_DIM 128
#define HIDC 64
#define HEADS 4
#define F1 (HEADS * HIDC) /* 256 */
#define MP 50048 /* N_NODES padded to 128 */

typedef __bf16 bf16x8 __attribute__((ext_vector_type(8)));
typedef float f32x4 __attribute__((ext_vector_type(4)));
typedef unsigned short u16x8 __attribute__((ext_vector_type(8)));

__device__ inline unsigned short f2bf(float f) {
  unsigned u = __builtin_bit_cast(unsigned, f);
  u += 0x7fff + ((u >> 16) & 1);
  return (unsigned short)(u >> 16);
}
__device__ inline float bf2f(unsigned short h) {
  unsigned u = ((unsigned)h) << 16;
  return __builtin_bit_cast(float, u);
}

__device__ inline void gload_lds16(const void* g, void* l) {
  __builtin_amdgcn_global_load_lds(
      (const __attribute__((address_space(1))) unsigned int*)g,
      (__attribute__((address_space(3))) unsigned int*)l, 16, 0, 0);
}

// ---------------- edge-index dtype detect ----------------
__global__ void detect_idx_kernel(const unsigned int* __restrict__ buf, int* __restrict__ flag) {
  __shared__ int any;
  if (threadIdx.x == 0) any = 0;
  __syncthreads();
  for (int i = threadIdx.x; i < 2048; i += blockDim.x)
    if (buf[2 * i + 1] != 0u) any = 1;
  __syncthreads();
  if (threadIdx.x == 0) *flag = any; // 1 => int32, 0 => int64
}

__global__ void init_cnt_kernel(int* __restrict__ cnt, int* __restrict__ fillc) {
  int i = blockIdx.x * blockDim.x + threadIdx.x;
  if (i < N_NODES) { cnt[i] = 1; fillc[i] = 0; } // self-loop pre-counted
}

// decode + histogram in one pass
__global__ void decode_hist_kernel(const void* __restrict__ eidx, const int* __restrict__ flag,
                                   int* __restrict__ srcO, int* __restrict__ dstO,
                                   int* __restrict__ cnt) {
  int i = blockIdx.x * blockDim.x + threadIdx.x;
  if (i >= N_EDGES) return;
  int s, d;
  if (*flag) {
    const int* b = (const int*)eidx;
    s = b[i]; d = b[N_EDGES + i];
  } else {
    const long long* b = (const long long*)eidx;
    s = (int)b[i]; d = (int)b[N_EDGES + i];
  }
  srcO[i] = s;
  dstO[i] = d;
  atomicAdd(&cnt[d], 1);
}

__global__ __launch_bounds__(1024) void scan_kernel(const int* __restrict__ cnt, int* __restrict__ off) {
  const int T = 1024;
  const int n = N_NODES;
  int tid = threadIdx.x;
  int chunk = (n + T - 1) / T;
  int s0 = tid * chunk;
  int s1 = min(s0 + chunk, n);
  int sum = 0;
  for (int i = s0; i < s1; ++i) sum += cnt[i];
  __shared__ int tmp[T];
  tmp[tid] = sum;
  __syncthreads();
  for (int o = 1; o < T; o <<= 1) {
    int t = (tid >= o) ? tmp[tid - o] : 0;
    __syncthreads();
    tmp[tid] += t;
    __syncthreads();
  }
  int run = tmp[tid] - sum;
  for (int i = s0; i < s1; ++i) {
    off[i] = run;
    run += cnt[i];
  }
  if (tid == T - 1) off[n] = run;
}

__global__ void fill_kernel(const int* __restrict__ src, const int* __restrict__ dst,
                            const int* __restrict__ csrOff, int* __restrict__ fillc,
                            int* __restrict__ csrSrc) {
  int i = blockIdx.x * blockDim.x + threadIdx.x;
  if (i >= ETOT) return;
  int s, d;
  if (i < N_EDGES) { s = src[i]; d = dst[i]; } else { s = i - N_EDGES; d = s; }
  int pos = csrOff[d] + atomicAdd(&fillc[d], 1);
  csrSrc[pos] = s;
}

// ---------------- fp32 -> split-bf16 (hi/lo), MFMA fragment-tiled layout ----------------
// tiled: [MP/16][K/32][kg=4][r=16][j=8]  (each 16x32 fragment = contiguous 1KB)
template <int K>
__global__ __launch_bounds__(256) void convA_kernel(const float* __restrict__ A,
                                                    unsigned short* __restrict__ hi,
                                                    unsigned short* __restrict__ lo, int M) {
  __shared__ float ld[16][264];
  const int mblk = blockIdx.x;
  const int tid = threadIdx.x;
  const int elems = 16 * K;
#pragma unroll
  for (int e = tid * 4; e < elems; e += 1024) {
    int r = e / K, c = e % K;
    int row = mblk * 16 + r;
    float4 v = make_float4(0.f, 0.f, 0.f, 0.f);
    if (row < M) v = *reinterpret_cast<const float4*>(&A[(size_t)row * K + c]);
    ld[r][c + 0] = v.x; ld[r][c + 1] = v.y; ld[r][c + 2] = v.z; ld[r][c + 3] = v.w;
  }
  __syncthreads();
#pragma unroll
  for (int o = tid * 8; o < elems; o += 2048) {
    int r = (o >> 3) & 15;
    int kg = (o >> 7) & 3;
    int kb = o >> 9;
    int k0 = kb * 32 + kg * 8;
    u16x8 h8, l8;
#pragma unroll
    for (int j = 0; j < 8; ++j) {
      float v = ld[r][k0 + j];
      unsigned short h = f2bf(v);
      h8[j] = h;
      l8[j] = f2bf(v - bf2f(h));
    }
    size_t base = ((size_t)mblk * (K >> 5) + kb) * 512 + (size_t)(kg * 16 + r) * 8;
    *reinterpret_cast<u16x8*>(hi + base) = h8;
    *reinterpret_cast<u16x8*>(lo + base) = l8;
  }
}

// W [K,Nw] row-major -> tiled [Nw/16][K/32][kg=4][c=16][j=8]
__global__ void convW_kernel(const float* __restrict__ W, unsigned short* __restrict__ hi,
                             unsigned short* __restrict__ lo, int K, int Nw) {
  int t = blockIdx.x * blockDim.x + threadIdx.x;
  int KB = K >> 5;
  int total = (Nw >> 4) * KB * 64;
  if (t >= total) return;
  int c = t & 15;
  int kg = (t >> 4) & 3;
  int kb = (t >> 6) % KB;
  int nblk = (t >> 6) / KB;
  int n = nblk * 16 + c;
  int k0 = kb * 32 + kg * 8;
  u16x8 h8, l8;
#pragma unroll
  for (int j = 0; j < 8; ++j) {
    float v = W[(size_t)(k0 + j) * Nw + n];
    unsigned short h = f2bf(v);
    h8[j] = h;
    l8[j] = f2bf(v - bf2f(h));
  }
  *reinterpret_cast<u16x8*>(hi + (size_t)t * 8) = h8;
  *reinterpret_cast<u16x8*>(lo + (size_t)t * 8) = l8;
}

// ---------------- single-pass split-bf16 MFMA GEMM + fused att-proj epilogue ----------------
// C = Ahi*Bhi + Alo*Bhi + Ahi*Blo -> fp16; a_s/a_d[node][H] = xl . att  (block covers whole heads)
template <int KB, int NB, int H>
__global__ __launch_bounds__(256) void gemm_fused_kernel(
    const unsigned short* __restrict__ Ahi, const unsigned short* __restrict__ Alo,
    const unsigned short* __restrict__ Bhi, const unsigned short* __restrict__ Blo,
    const float* __restrict__ atts, const float* __restrict__ attd,
    __half* __restrict__ Ch, float* __restrict__ a_s, float* __restrict__ a_d,
    int M, int Nout) {
  __shared__ unsigned short AsH[8 * 512], AsL[8 * 512];
  __shared__ unsigned short BsH[NB * 512], BsL[NB * 512];
  const int tid = threadIdx.x;
  const int w = tid >> 6, lane = tid & 63;
  const size_t machunk = ((size_t)blockIdx.x * 8 + w * 2) * KB;
  const int nblk0 = blockIdx.y * NB;
  const int laneo = lane * 8;

  f32x4 acc[2][NB];
#pragma unroll
  for (int mi = 0; mi < 2; ++mi)
#pragma unroll
    for (int nj = 0; nj < NB; ++nj) acc[mi][nj] = {0.f, 0.f, 0.f, 0.f};

  for (int kb = 0; kb < KB; ++kb) {
    gload_lds16(Ahi + (machunk + kb) * 512 + laneo, AsH + (w * 2) * 512);
    gload_lds16(Ahi + (machunk + (size_t)KB + kb) * 512 + laneo, AsH + (w * 2 + 1) * 512);
    gload_lds16(Alo + (machunk + kb) * 512 + laneo, AsL + (w * 2) * 512);
    gload_lds16(Alo + (machunk + (size_t)KB + kb) * 512 + laneo, AsL + (w * 2 + 1) * 512);
#pragma unroll
    for (int q = 0; q < NB / 4; ++q) {
      int nbl = w * (NB / 4) + q;
      size_t bo = ((size_t)(nblk0 + nbl) * KB + kb) * 512 + laneo;
      gload_lds16(Bhi + bo, BsH + nbl * 512);
      gload_lds16(Blo + bo, BsL + nbl * 512);
    }
    __syncthreads();
    bf16x8 a0h = *reinterpret_cast<const bf16x8*>(AsH + (w * 2) * 512 + laneo);
    bf16x8 a1h = *reinterpret_cast<const bf16x8*>(AsH + (w * 2 + 1) * 512 + laneo);
    bf16x8 a0l = *reinterpret_cast<const bf16x8*>(AsL + (w * 2) * 512 + laneo);
    bf16x8 a1l = *reinterpret_cast<const bf16x8*>(AsL + (w * 2 + 1) * 512 + laneo);
#pragma unroll
    for (int nj = 0; nj < NB; ++nj) {
      bf16x8 bh = *reinterpret_cast<const bf16x8*>(BsH + nj * 512 + laneo);
      bf16x8 bl = *reinterpret_cast<const bf16x8*>(BsL + nj * 512 + laneo);
      acc[0][nj] = __builtin_amdgcn_mfma_f32_16x16x32_bf16(a0h, bh, acc[0][nj], 0, 0, 0);
      acc[1][nj] = __builtin_amdgcn_mfma_f32_16x16x32_bf16(a1h, bh, acc[1][nj], 0, 0, 0);
      acc[0][nj] = __builtin_amdgcn_mfma_f32_16x16x32_bf16(a0l, bh, acc[0][nj], 0, 0, 0);
      acc[1][nj] = __builtin_amdgcn_mfma_f32_16x16x32_bf16(a1l, bh, acc[1][nj], 0, 0, 0);
      acc[0][nj] = __builtin_amdgcn_mfma_f32_16x16x32_bf16(a0h, bl, acc[0][nj], 0, 0, 0);
      acc[1][nj] = __builtin_amdgcn_mfma_f32_16x16x32_bf16(a1h, bl, acc[1][nj], 0, 0, 0);
    }
    __syncthreads();
  }
  // ---- epilogue: fp16 store + fused att dot products ----
  const int col0 = nblk0 * 16 + (lane & 15);
  const int row0 = blockIdx.x * 128 + w * 32 + (lane >> 4) * 4;
  float attsv[NB], attdv[NB];
#pragma unroll
  for (int nj = 0; nj < NB; ++nj) {
    int gcol = nblk0 + nj;
    int hh = gcol >> 2;
    int coff = (gcol & 3) * 16 + (lane & 15);
    attsv[nj] = atts[hh * 64 + coff];
    attdv[nj] = attd[hh * 64 + coff];
  }
#pragma unroll
  for (int mi = 0; mi < 2; ++mi) {
#pragma unroll
    for (int nj = 0; nj < NB; ++nj) {
      int col = col0 + nj * 16;
#pragma unroll
      for (int r = 0; r < 4; ++r) {
        int row = row0 + mi * 16 + r;
        if (row < M) Ch[(size_t)row * Nout + col] = __float2half(acc[mi][nj][r]);
      }
    }
#pragma unroll
    for (int r = 0; r < 4; ++r) {
      int row = row0 + mi * 16 + r;
#pragma unroll
      for (int g = 0; g < NB / 4; ++g) {
        float ps = 0.f, pd = 0.f;
#pragma unroll
        for (int q = 0; q < 4; ++q) {
          float v = acc[mi][g * 4 + q][r];
          ps = fmaf(v, attsv[g * 4 + q], ps);
          pd = fmaf(v, attdv[g * 4 + q], pd);
        }
#pragma unroll
        for (int o = 1; o <= 8; o <<= 1) {
          ps += __shfl_xor(ps, o);
          pd += __shfl_xor(pd, o);
        }
        if ((lane & 15) == 0 && row < M) {
          int hh = (nblk0 + g * 4) >> 2;
          a_s[(size_t)row * H + hh] = ps;
          a_d[(size_t)row * H + hh] = pd;
        }
      }
    }
  }
}

// ---------------- H=4 edge softmax + aggregate; fp16 gather; writes split-bf16 tiled + ELU ----------------
__global__ __launch_bounds__(256) void gat_agg4_kernel(const __half* __restrict__ xlh,
                                                       const float* __restrict__ a_srcv,
                                                       const float* __restrict__ a_dstv,
                                                       const int* __restrict__ csrOff,
                                                       const int* __restrict__ csrSrc,
                                                       const float* __restrict__ bias,
                                                       unsigned short* __restrict__ outHi,
                                                       unsigned short* __restrict__ outLo) {
  __shared__ float4 plds[4][64];
  __shared__ int slds[4][64];
  const int w = threadIdx.x >> 6;
  const int lane = threadIdx.x & 63;
  const int d = blockIdx.x * 4 + w;
  if (d >= N_NODES) return;
  const int h = lane >> 4;
  int e0 = csrOff[d], e1 = csrOff[d + 1];
  float4 adv = reinterpret_cast<const float4*>(a_dstv)[d];
  float m[4], ssum[4];
#pragma unroll
  for (int j = 0; j < 4; ++j) { m[j] = -1e30f; ssum[j] = 0.f; }
  float4 acc = make_float4(0.f, 0.f, 0.f, 0.f);
  const float* pbase = reinterpret_cast<const float*>(&plds[w][0]);
  const __half* xl_lane = xlh + lane * 4;

  for (int cb = e0; cb < e1; cb += 64) {
    int ecount = min(64, e1 - cb);
    int sidx = (lane < ecount) ? csrSrc[cb + lane] : 0;
    slds[w][lane] = sidx << 8; // precomputed element offset (row stride 256)
    float4 asv = make_float4(0.f, 0.f, 0.f, 0.f);
    if (lane < ecount) asv = reinterpret_cast<const float4*>(a_srcv)[sidx];
    float p[4], scl[4];
#pragma unroll
    for (int j = 0; j < 4; ++j) {
      float av = (j == 0) ? asv.x : (j == 1) ? asv.y : (j == 2) ? asv.z : asv.w;
      float dv = (j == 0) ? adv.x : (j == 1) ? adv.y : (j == 2) ? adv.z : adv.w;
      float al = -1e30f;
      if (lane < ecount) {
        float v = av + dv;
        al = (v > 0.f) ? v : 0.2f * v;
      }
      float cm = al;
#pragma unroll
      for (int o = 32; o > 0; o >>= 1) cm = fmaxf(cm, __shfl_xor(cm, o));
      float nm = fmaxf(m[j], cm);
      float scale = __expf(m[j] - nm); // first chunk: exp(-inf)=0
      p[j] = (lane < ecount) ? __expf(al - nm) : 0.f;
      float ps = p[j];
#pragma unroll
      for (int o = 32; o > 0; o >>= 1) ps += __shfl_xor(ps, o);
      ssum[j] = ssum[j] * scale + ps;
      m[j] = nm;
      scl[j] = scale;
    }
    plds[w][lane] = make_float4(p[0], p[1], p[2], p[3]);
    float sc = (h == 0) ? scl[0] : (h == 1) ? scl[1] : (h == 2) ? scl[2] : scl[3];
    acc.x *= sc; acc.y *= sc; acc.z *= sc; acc.w *= sc;
    for (int i = 0; i < ecount; ++i) {
      int so = slds[w][i];         // broadcast ds_read (pre-multiplied)
      float pv = pbase[i * 4 + h]; // broadcast-within-16 ds_read
      uint2 raw = *reinterpret_cast<const uint2*>(xl_lane + so); // 512B/row coalesced
      float2 f0 = __half22float2(__builtin_bit_cast(__half2, raw.x));
      float2 f1 = __half22float2(__builtin_bit_cast(__half2, raw.y));
      acc.x = fmaf(pv, f0.x, acc.x);
      acc.y = fmaf(pv, f0.y, acc.y);
      acc.z = fmaf(pv, f1.x, acc.z);
      acc.w = fmaf(pv, f1.y, acc.w);
    }
  }
  float sm = (h == 0) ? ssum[0] : (h == 1) ? ssum[1] : (h == 2) ? ssum[2] : ssum[3];
  float inv = 1.f / (sm + 1e-16f);
  float4 bv = reinterpret_cast<const float4*>(bias)[lane];
  float4 r;
  r.x = acc.x * inv + bv.x;
  r.y = acc.y * inv + bv.y;
  r.z = acc.z * inv + bv.z;
  r.w = acc.w * inv + bv.w;
  r.x = (r.x > 0.f) ? r.x : (__expf(r.x) - 1.f);
  r.y = (r.y > 0.f) ? r.y : (__expf(r.y) - 1.f);
  r.z = (r.z > 0.f) ? r.z : (__expf(r.z) - 1.f);
  r.w = (r.w > 0.f) ? r.w : (__expf(r.w) - 1.f);
  // split-bf16 write in MFMA-tiled layout (col c=4L+i: kb=L>>3, kg=(L>>1)&3, j=(L&1)*4+i)
  ushort4 hh, ll;
  hh.x = f2bf(r.x); ll.x = f2bf(r.x - bf2f(hh.x));
  hh.y = f2bf(r.y); ll.y = f2bf(r.y - bf2f(hh.y));
  hh.z = f2bf(r.z); ll.z = f2bf(r.z - bf2f(hh.z));
  hh.w = f2bf(r.w); ll.w = f2bf(r.w - bf2f(hh.w));
  const int mblk = d >> 4, rr = d & 15;
  const int kb = lane >> 3, kg = (lane >> 1) & 3, jj = (lane & 1) * 4;
  size_t base = ((size_t)mblk * 8 + kb) * 512 + (size_t)(kg * 16 + rr) * 8 + jj;
  *reinterpret_cast<ushort4*>(outHi + base) = hh;
  *reinterpret_cast<ushort4*>(outLo + base) = ll;
}

// layer 3 (H=1) + fused b3 + fc (64->2) + fc_b; fp16 gather; 4 edges per iteration
__global__ __launch_bounds__(256) void gat_final_kernel(const __half* __restrict__ xlh,
                                                        const float* __restrict__ a_srcv,
                                                        const float* __restrict__ a_dstv,
                                                        const int* __restrict__ csrOff,
                                                        const int* __restrict__ csrSrc,
                                                        const float* __restrict__ b3,
                                                        const float* __restrict__ fcw,
                                                        const float* __restrict__ fcb,
                                                        float* __restrict__ out) {
  __shared__ float plds[4][64];
  __shared__ int slds[4][64];
  const int w = threadIdx.x >> 6;
  const int lane = threadIdx.x & 63;
  const int d = blockIdx.x * 4 + w;
  if (d >= N_NODES) return;
  const int g = lane >> 4;   // edge subgroup
  const int c4 = lane & 15;  // 4-col group index
  int e0 = csrOff[d], e1 = csrOff[d + 1];
  float adv = a_dstv[d];
  float m = -1e30f, ssum = 0.f;
  float4 acc = make_float4(0.f, 0.f, 0.f, 0.f);
  const __half* xl_lane = xlh + c4 * 4;

  for (int cb = e0; cb < e1; cb += 64) {
    int ecount = min(64, e1 - cb);
    int sidx = (lane < ecount) ? csrSrc[cb + lane] : 0;
    slds[w][lane] = sidx << 6; // element offset (row stride 64)
    float al = -1e30f;
    if (lane < ecount) {
      float v = a_srcv[sidx] + adv;
      al = (v > 0.f) ? v : 0.2f * v;
    }
    float cm = al;
#pragma unroll
    for (int o = 32; o > 0; o >>= 1) cm = fmaxf(cm, __shfl_xor(cm, o));
    float nm = fmaxf(m, cm);
    float scale = __expf(m - nm);
    float p = (lane < ecount) ? __expf(al - nm) : 0.f;
    float ps = p;
#pragma unroll
    for (int o = 32; o > 0; o >>= 1) ps += __shfl_xor(ps, o);
    ssum = ssum * scale + ps;
    m = nm;
    plds[w][lane] = p;
    acc.x *= scale; acc.y *= scale; acc.z *= scale; acc.w *= scale;
    for (int i = 0; i < ecount; i += 4) {
      int e = i + g; // <= 63 always; p==0 for e>=ecount
      int so = slds[w][e];
      float pv = plds[w][e];
      uint2 raw = *reinterpret_cast<const uint2*>(xl_lane + so); // 128B/row
      float2 f0 = __half22float2(__builtin_bit_cast(__half2, raw.x));
      float2 f1 = __half22float2(__builtin_bit_cast(__half2, raw.y));
      acc.x = fmaf(pv, f0.x, acc.x);
      acc.y = fmaf(pv, f0.y, acc.y);
      acc.z = fmaf(pv, f1.x, acc.z);
      acc.w = fmaf(pv, f1.y, acc.w);
    }
  }
#pragma unroll
  for (int o = 16; o <= 32; o <<= 1) {
    acc.x += __shfl_xor(acc.x, o);
    acc.y += __shfl_xor(acc.y, o);
    acc.z += __shfl_xor(acc.z, o);
    acc.w += __shfl_xor(acc.w, o);
  }
  float inv = 1.f / (ssum + 1e-16f);
  float4 bv = reinterpret_cast<const float4*>(b3)[c4];
  float4 v;
  v.x = acc.x * inv + bv.x;
  v.y = acc.y * inv + bv.y;
  v.z = acc.z * inv + bv.z;
  v.w = acc.w * inv + bv.w;
  const float2* fcw2 = reinterpret_cast<const float2*>(fcw);
  float2 w0 = fcw2[c4 * 4 + 0], w1 = fcw2[c4 * 4 + 1], w2 = fcw2[c4 * 4 + 2], w3 = fcw2[c4 * 4 + 3];
  float l0 = v.x * w0.x + v.y * w1.x + v.z * w2.x + v.w * w3.x;
  float l1 = v.x * w0.y + v.y * w1.y + v.z * w2.y + v.w * w3.y;
#pragma unroll
  for (int o = 1; o <= 8; o <<= 1) {
    l0 += __shfl_xor(l0, o);
    l1 += __shfl_xor(l1, o);
  }
  if (lane == 0) {
    out[2 * d + 0] = l0 + fcb[0];
    out[2 * d + 1] = l1 + fcb[1];
  }
}

extern "C" void kernel_launch(void* const* d_in, const int* in_sizes, int n_in,
                              void* d_out, int out_size, void* d_ws, size_t ws_size,
                              hipStream_t stream) {
  (void)in_sizes; (void)n_in; (void)out_size; (void)ws_size;
  const float* x      = (const float*)d_in[0];
  const void*  eidx   = d_in[1];
  const float* W1     = (const float*)d_in[2];
  const float* att_s1 = (const float*)d_in[3];
  const float* att_d1 = (const float*)d_in[4];
  const float* b1     = (const float*)d_in[5];
  const float* W2     = (const float*)d_in[6];
  const float* att_s2 = (const float*)d_in[7];
  const float* att_d2 = (const float*)d_in[8];
  const float* b2     = (const float*)d_in[9];
  const float* W3     = (const float*)d_in[10];
  const float* att_s3 = (const float*)d_in[11];
  const float* att_d3 = (const float*)d_in[12];
  const float* b3     = (const float*)d_in[13];
  const float* fcw    = (const float*)d_in[14];
  const float* fcb    = (const float*)d_in[15];
  float* out = (float*)d_out;

  char* ws = (char*)d_ws;
  size_t off = 0;
  auto alloc = [&](size_t bytes) -> void* {
    void* p = (void*)(ws + off);
    off += (bytes + 255) & ~(size_t)255;
    return p;
  };
  int*   srcI   = (int*)alloc((size_t)N_EDGES * 4);
  int*   dstI   = (int*)alloc((size_t)N_EDGES * 4);
  int*   cnt    = (int*)alloc((size_t)N_NODES * 4);
  int*   fillc  = (int*)alloc((size_t)N_NODES * 4);
  int*   csrOff = (int*)alloc((size_t)(N_NODES + 1) * 4);
  int*   csrSrc = (int*)alloc((size_t)ETOT * 4);
  int*   flag   = (int*)alloc(256);
  float* a_s    = (float*)alloc((size_t)N_NODES * HEADS * 4);
  float* a_d    = (float*)alloc((size_t)N_NODES * HEADS * 4);
  unsigned short* Ahi = (unsigned short*)alloc((size_t)MP * F1 * 2);
  unsigned short* Alo = (unsigned short*)alloc((size_t)MP * F1 * 2);
  unsigned short* Whi = (unsigned short*)alloc((size_t)F1 * F1 * 2);
  unsigned short* Wlo = (unsigned short*)alloc((size_t)F1 * F1 * 2);
  __half* xlh  = (__half*)alloc((size_t)MP * F1 * 2);   // fp16 xl (layers 1,2)
  __half* xlh3 = (__half*)alloc((size_t)MP * HIDC * 2); // fp16 xl (layer 3)

  detect_idx_kernel<<<1, 256, 0, stream>>>((const unsigned int*)eidx, flag);
  init_cnt_kernel<<<(N_NODES + 255) / 256, 256, 0, stream>>>(cnt, fillc);
  decode_hist_kernel<<<(N_EDGES + 255) / 256, 256, 0, stream>>>(eidx, flag, srcI, dstI, cnt);
  scan_kernel<<<1, 1024, 0, stream>>>(cnt, csrOff);
  fill_kernel<<<(ETOT + 255) / 256, 256, 0, stream>>>(srcI, dstI, csrOff, fillc, csrSrc);

  const int gn = (N_NODES + 3) / 4;  // 12500
  const int gmb = MP / 16;           // 3128
  const int gx = MP / 128;           // 391

  // ---- Layer 1: x[N,128] @ W1[128,256] ----
  convA_kernel<IN_DIM><<<gmb, 256, 0, stream>>>(x, Ahi, Alo, N_NODES);
  convW_kernel<<<(4096 + 255) / 256, 256, 0, stream>>>(W1, Whi, Wlo, IN_DIM, F1);
  gemm_fused_kernel<4, 8, 4><<<dim3(gx, 2), 256, 0, stream>>>(Ahi, Alo, Whi, Wlo, att_s1, att_d1,
                                                              xlh, a_s, a_d, N_NODES, F1);
  gat_agg4_kernel<<<gn, 256, 0, stream>>>(xlh, a_s, a_d, csrOff, csrSrc, b1, Ahi, Alo);

  // ---- Layer 2: h1[N,256] @ W2[256,256] (A from agg epilogue, tiled) ----
  convW_kernel<<<(8192 + 255) / 256, 256, 0, stream>>>(W2, Whi, Wlo, F1, F1);
  gemm_fused_kernel<8, 8, 4><<<dim3(gx, 2), 256, 0, stream>>>(Ahi, Alo, Whi, Wlo, att_s2, att_d2,
                                                              xlh, a_s, a_d, N_NODES, F1);
  gat_agg4_kernel<<<gn, 256, 0, stream>>>(xlh, a_s, a_d, csrOff, csrSrc, b2, Ahi, Alo);

  // ---- Layer 3: h2[N,256] @ W3[256,64], H=1, fused fc ----
  convW_kernel<<<(2048 + 255) / 256, 256, 0, stream>>>(W3, Whi, Wlo, F1, HIDC);
  gemm_fused_kernel<8, 4, 1><<<dim3(gx, 1), 256, 0, stream>>>(Ahi, Alo, Whi, Wlo, att_s3, att_d3,
                                                              xlh3, a_s, a_d, N_NODES, HIDC);
  gat_final_kernel<<<gn, 256, 0, stream>>>(xlh3, a_s, a_d, csrOff, csrSrc, b3, fcw, fcb, out);
}

// Round 6
// 446.337 us; speedup vs baseline: 1.8036x; 1.0600x over previous
//
#include <hip/hip_runtime.h>
#include <hip/hip_fp16.h>
#include <math.h>

#define N_NODES 50000
#define N_EDGES 800000
#define ETOT (N_EDGES + N_NODES)
#define IN_DIM 128
#define HIDC 64
#define HEADS 4
#define F1 (HEADS * HIDC) /* 256 */
#define MP 50048 /* N_NODES padded to 128 */

// tiled W buffer element offsets (within Whi/Wlo)
#define WOFF1 0
#define WOFF2 32768  /* 128*256 */
#define WOFF3 98304  /* + 256*256 */
#define WTOT_ITEMS 14336 /* 4096 + 8192 + 2048 work items (8 elems each) */

typedef __bf16 bf16x8 __attribute__((ext_vector_type(8)));
typedef float f32x4 __attribute__((ext_vector_type(4)));
typedef unsigned short u16x8 __attribute__((ext_vector_type(8)));

__device__ inline unsigned short f2bf(float f) {
  unsigned u = __builtin_bit_cast(unsigned, f);
  u += 0x7fff + ((u >> 16) & 1);
  return (unsigned short)(u >> 16);
}
__device__ inline float bf2f(unsigned short h) {
  unsigned u = ((unsigned)h) << 16;
  return __builtin_bit_cast(float, u);
}

__device__ inline void gload_lds16(const void* g, void* l) {
  __builtin_amdgcn_global_load_lds(
      (const __attribute__((address_space(1))) unsigned int*)g,
      (__attribute__((address_space(3))) unsigned int*)l, 16, 0, 0);
}

// ---------------- dtype detect + cnt/fillc init (merged) ----------------
__global__ void detect_init_kernel(const unsigned int* __restrict__ buf, int* __restrict__ flag,
                                   int* __restrict__ cnt, int* __restrict__ fillc) {
  int i = blockIdx.x * blockDim.x + threadIdx.x;
  if (i < N_NODES) { cnt[i] = 1; fillc[i] = 0; } // self-loop pre-counted
  if (blockIdx.x == 0) {
    __shared__ int any;
    if (threadIdx.x == 0) any = 0;
    __syncthreads();
    for (int k = threadIdx.x; k < 2048; k += blockDim.x)
      if (buf[2 * k + 1] != 0u) any = 1;
    __syncthreads();
    if (threadIdx.x == 0) *flag = any; // 1 => int32, 0 => int64
  }
}

// decode + histogram in one pass
__global__ void decode_hist_kernel(const void* __restrict__ eidx, const int* __restrict__ flag,
                                   int* __restrict__ srcO, int* __restrict__ dstO,
                                   int* __restrict__ cnt) {
  int i = blockIdx.x * blockDim.x + threadIdx.x;
  if (i >= N_EDGES) return;
  int s, d;
  if (*flag) {
    const int* b = (const int*)eidx;
    s = b[i]; d = b[N_EDGES + i];
  } else {
    const long long* b = (const long long*)eidx;
    s = (int)b[i]; d = (int)b[N_EDGES + i];
  }
  srcO[i] = s;
  dstO[i] = d;
  atomicAdd(&cnt[d], 1);
}

__global__ __launch_bounds__(1024) void scan_kernel(const int* __restrict__ cnt, int* __restrict__ off) {
  const int T = 1024;
  const int n = N_NODES;
  int tid = threadIdx.x;
  int chunk = (n + T - 1) / T;
  int s0 = tid * chunk;
  int s1 = min(s0 + chunk, n);
  int sum = 0;
  for (int i = s0; i < s1; ++i) sum += cnt[i];
  __shared__ int tmp[T];
  tmp[tid] = sum;
  __syncthreads();
  for (int o = 1; o < T; o <<= 1) {
    int t = (tid >= o) ? tmp[tid - o] : 0;
    __syncthreads();
    tmp[tid] += t;
    __syncthreads();
  }
  int run = tmp[tid] - sum;
  for (int i = s0; i < s1; ++i) {
    off[i] = run;
    run += cnt[i];
  }
  if (tid == T - 1) off[n] = run;
}

__global__ void fill_kernel(const int* __restrict__ src, const int* __restrict__ dst,
                            const int* __restrict__ csrOff, int* __restrict__ fillc,
                            int* __restrict__ csrSrc) {
  int i = blockIdx.x * blockDim.x + threadIdx.x;
  if (i >= ETOT) return;
  int s, d;
  if (i < N_EDGES) { s = src[i]; d = dst[i]; } else { s = i - N_EDGES; d = s; }
  int pos = csrOff[d] + atomicAdd(&fillc[d], 1);
  csrSrc[pos] = s;
}

// ---------------- fp32 -> split-bf16 (hi/lo), MFMA fragment-tiled layout ----------------
// tiled: [MP/16][K/32][kg=4][r=16][j=8]  (each 16x32 fragment = contiguous 1KB)
template <int K>
__global__ __launch_bounds__(256) void convA_kernel(const float* __restrict__ A,
                                                    unsigned short* __restrict__ hi,
                                                    unsigned short* __restrict__ lo, int M) {
  __shared__ float ld[16][264];
  const int mblk = blockIdx.x;
  const int tid = threadIdx.x;
  const int elems = 16 * K;
#pragma unroll
  for (int e = tid * 4; e < elems; e += 1024) {
    int r = e / K, c = e % K;
    int row = mblk * 16 + r;
    float4 v = make_float4(0.f, 0.f, 0.f, 0.f);
    if (row < M) v = *reinterpret_cast<const float4*>(&A[(size_t)row * K + c]);
    ld[r][c + 0] = v.x; ld[r][c + 1] = v.y; ld[r][c + 2] = v.z; ld[r][c + 3] = v.w;
  }
  __syncthreads();
#pragma unroll
  for (int o = tid * 8; o < elems; o += 2048) {
    int r = (o >> 3) & 15;
    int kg = (o >> 7) & 3;
    int kb = o >> 9;
    int k0 = kb * 32 + kg * 8;
    u16x8 h8, l8;
#pragma unroll
    for (int j = 0; j < 8; ++j) {
      float v = ld[r][k0 + j];
      unsigned short h = f2bf(v);
      h8[j] = h;
      l8[j] = f2bf(v - bf2f(h));
    }
    size_t base = ((size_t)mblk * (K >> 5) + kb) * 512 + (size_t)(kg * 16 + r) * 8;
    *reinterpret_cast<u16x8*>(hi + base) = h8;
    *reinterpret_cast<u16x8*>(lo + base) = l8;
  }
}

// all three W matrices -> tiled [Nw/16][K/32][kg=4][c=16][j=8], one launch
__device__ inline void convW_item(const float* __restrict__ W, int K, int Nw, int t,
                                  unsigned short* __restrict__ hi, unsigned short* __restrict__ lo) {
  int KB = K >> 5;
  int c = t & 15;
  int kg = (t >> 4) & 3;
  int kb = (t >> 6) % KB;
  int nblk = (t >> 6) / KB;
  int n = nblk * 16 + c;
  int k0 = kb * 32 + kg * 8;
  u16x8 h8, l8;
#pragma unroll
  for (int j = 0; j < 8; ++j) {
    float v = W[(size_t)(k0 + j) * Nw + n];
    unsigned short h = f2bf(v);
    h8[j] = h;
    l8[j] = f2bf(v - bf2f(h));
  }
  *reinterpret_cast<u16x8*>(hi + (size_t)t * 8) = h8;
  *reinterpret_cast<u16x8*>(lo + (size_t)t * 8) = l8;
}

__global__ void convW_all_kernel(const float* __restrict__ W1, const float* __restrict__ W2,
                                 const float* __restrict__ W3,
                                 unsigned short* __restrict__ hi, unsigned short* __restrict__ lo) {
  int t = blockIdx.x * blockDim.x + threadIdx.x;
  if (t >= WTOT_ITEMS) return;
  if (t < 4096) {
    convW_item(W1, IN_DIM, F1, t, hi + WOFF1, lo + WOFF1);
  } else if (t < 4096 + 8192) {
    convW_item(W2, F1, F1, t - 4096, hi + WOFF2, lo + WOFF2);
  } else {
    convW_item(W3, F1, HIDC, t - (4096 + 8192), hi + WOFF3, lo + WOFF3);
  }
}

// ---------------- single-pass split-bf16 MFMA GEMM + fused att-proj epilogue ----------------
// C = Ahi*Bhi + Alo*Bhi + Ahi*Blo -> fp16; a_s/a_d[node][H] = xl . att  (block covers whole heads)
template <int KB, int NB, int H>
__global__ __launch_bounds__(256) void gemm_fused_kernel(
    const unsigned short* __restrict__ Ahi, const unsigned short* __restrict__ Alo,
    const unsigned short* __restrict__ Bhi, const unsigned short* __restrict__ Blo,
    const float* __restrict__ atts, const float* __restrict__ attd,
    __half* __restrict__ Ch, float* __restrict__ a_s, float* __restrict__ a_d,
    int M, int Nout) {
  __shared__ unsigned short AsH[8 * 512], AsL[8 * 512];
  __shared__ unsigned short BsH[NB * 512], BsL[NB * 512];
  const int tid = threadIdx.x;
  const int w = tid >> 6, lane = tid & 63;
  const size_t machunk = ((size_t)blockIdx.x * 8 + w * 2) * KB;
  const int nblk0 = blockIdx.y * NB;
  const int laneo = lane * 8;

  f32x4 acc[2][NB];
#pragma unroll
  for (int mi = 0; mi < 2; ++mi)
#pragma unroll
    for (int nj = 0; nj < NB; ++nj) acc[mi][nj] = {0.f, 0.f, 0.f, 0.f};

  for (int kb = 0; kb < KB; ++kb) {
    gload_lds16(Ahi + (machunk + kb) * 512 + laneo, AsH + (w * 2) * 512);
    gload_lds16(Ahi + (machunk + (size_t)KB + kb) * 512 + laneo, AsH + (w * 2 + 1) * 512);
    gload_lds16(Alo + (machunk + kb) * 512 + laneo, AsL + (w * 2) * 512);
    gload_lds16(Alo + (machunk + (size_t)KB + kb) * 512 + laneo, AsL + (w * 2 + 1) * 512);
#pragma unroll
    for (int q = 0; q < NB / 4; ++q) {
      int nbl = w * (NB / 4) + q;
      size_t bo = ((size_t)(nblk0 + nbl) * KB + kb) * 512 + laneo;
      gload_lds16(Bhi + bo, BsH + nbl * 512);
      gload_lds16(Blo + bo, BsL + nbl * 512);
    }
    __syncthreads();
    bf16x8 a0h = *reinterpret_cast<const bf16x8*>(AsH + (w * 2) * 512 + laneo);
    bf16x8 a1h = *reinterpret_cast<const bf16x8*>(AsH + (w * 2 + 1) * 512 + laneo);
    bf16x8 a0l = *reinterpret_cast<const bf16x8*>(AsL + (w * 2) * 512 + laneo);
    bf16x8 a1l = *reinterpret_cast<const bf16x8*>(AsL + (w * 2 + 1) * 512 + laneo);
#pragma unroll
    for (int nj = 0; nj < NB; ++nj) {
      bf16x8 bh = *reinterpret_cast<const bf16x8*>(BsH + nj * 512 + laneo);
      bf16x8 bl = *reinterpret_cast<const bf16x8*>(BsL + nj * 512 + laneo);
      acc[0][nj] = __builtin_amdgcn_mfma_f32_16x16x32_bf16(a0h, bh, acc[0][nj], 0, 0, 0);
      acc[1][nj] = __builtin_amdgcn_mfma_f32_16x16x32_bf16(a1h, bh, acc[1][nj], 0, 0, 0);
      acc[0][nj] = __builtin_amdgcn_mfma_f32_16x16x32_bf16(a0l, bh, acc[0][nj], 0, 0, 0);
      acc[1][nj] = __builtin_amdgcn_mfma_f32_16x16x32_bf16(a1l, bh, acc[1][nj], 0, 0, 0);
      acc[0][nj] = __builtin_amdgcn_mfma_f32_16x16x32_bf16(a0h, bl, acc[0][nj], 0, 0, 0);
      acc[1][nj] = __builtin_amdgcn_mfma_f32_16x16x32_bf16(a1h, bl, acc[1][nj], 0, 0, 0);
    }
    __syncthreads();
  }
  // ---- epilogue: fp16 store + fused att dot products ----
  const int col0 = nblk0 * 16 + (lane & 15);
  const int row0 = blockIdx.x * 128 + w * 32 + (lane >> 4) * 4;
  float attsv[NB], attdv[NB];
#pragma unroll
  for (int nj = 0; nj < NB; ++nj) {
    int gcol = nblk0 + nj;
    int hh = gcol >> 2;
    int coff = (gcol & 3) * 16 + (lane & 15);
    attsv[nj] = atts[hh * 64 + coff];
    attdv[nj] = attd[hh * 64 + coff];
  }
#pragma unroll
  for (int mi = 0; mi < 2; ++mi) {
#pragma unroll
    for (int nj = 0; nj < NB; ++nj) {
      int col = col0 + nj * 16;
#pragma unroll
      for (int r = 0; r < 4; ++r) {
        int row = row0 + mi * 16 + r;
        if (row < M) Ch[(size_t)row * Nout + col] = __float2half(acc[mi][nj][r]);
      }
    }
#pragma unroll
    for (int r = 0; r < 4; ++r) {
      int row = row0 + mi * 16 + r;
#pragma unroll
      for (int g = 0; g < NB / 4; ++g) {
        float ps = 0.f, pd = 0.f;
#pragma unroll
        for (int q = 0; q < 4; ++q) {
          float v = acc[mi][g * 4 + q][r];
          ps = fmaf(v, attsv[g * 4 + q], ps);
          pd = fmaf(v, attdv[g * 4 + q], pd);
        }
#pragma unroll
        for (int o = 1; o <= 8; o <<= 1) {
          ps += __shfl_xor(ps, o);
          pd += __shfl_xor(pd, o);
        }
        if ((lane & 15) == 0 && row < M) {
          int hh = (nblk0 + g * 4) >> 2;
          a_s[(size_t)row * H + hh] = ps;
          a_d[(size_t)row * H + hh] = pd;
        }
      }
    }
  }
}

// ---------------- H=4 edge softmax + aggregate; fp16 gather; writes split-bf16 tiled + ELU ----------------
// (round-4 exact inner-loop addressing: 40 VGPR / 79us / 55% occ measured)
__global__ __launch_bounds__(256) void gat_agg4_kernel(const __half* __restrict__ xlh,
                                                       const float* __restrict__ a_srcv,
                                                       const float* __restrict__ a_dstv,
                                                       const int* __restrict__ csrOff,
                                                       const int* __restrict__ csrSrc,
                                                       const float* __restrict__ bias,
                                                       unsigned short* __restrict__ outHi,
                                                       unsigned short* __restrict__ outLo) {
  __shared__ float4 plds[4][64];
  __shared__ int slds[4][64];
  const int w = threadIdx.x >> 6;
  const int lane = threadIdx.x & 63;
  const int d = blockIdx.x * 4 + w;
  if (d >= N_NODES) return;
  const int h = lane >> 4;
  int e0 = csrOff[d], e1 = csrOff[d + 1];
  float4 adv = reinterpret_cast<const float4*>(a_dstv)[d];
  float m[4], ssum[4];
#pragma unroll
  for (int j = 0; j < 4; ++j) { m[j] = -1e30f; ssum[j] = 0.f; }
  float4 acc = make_float4(0.f, 0.f, 0.f, 0.f);
  const float* pbase = reinterpret_cast<const float*>(&plds[w][0]);

  for (int cb = e0; cb < e1; cb += 64) {
    int ecount = min(64, e1 - cb);
    int sidx = (lane < ecount) ? csrSrc[cb + lane] : 0;
    slds[w][lane] = sidx;
    float4 asv = make_float4(0.f, 0.f, 0.f, 0.f);
    if (lane < ecount) asv = reinterpret_cast<const float4*>(a_srcv)[sidx];
    float p[4], scl[4];
#pragma unroll
    for (int j = 0; j < 4; ++j) {
      float av = (j == 0) ? asv.x : (j == 1) ? asv.y : (j == 2) ? asv.z : asv.w;
      float dv = (j == 0) ? adv.x : (j == 1) ? adv.y : (j == 2) ? adv.z : adv.w;
      float al = -1e30f;
      if (lane < ecount) {
        float v = av + dv;
        al = (v > 0.f) ? v : 0.2f * v;
      }
      float cm = al;
#pragma unroll
      for (int o = 32; o > 0; o >>= 1) cm = fmaxf(cm, __shfl_xor(cm, o));
      float nm = fmaxf(m[j], cm);
      float scale = __expf(m[j] - nm); // first chunk: exp(-inf)=0
      p[j] = (lane < ecount) ? __expf(al - nm) : 0.f;
      float ps = p[j];
#pragma unroll
      for (int o = 32; o > 0; o >>= 1) ps += __shfl_xor(ps, o);
      ssum[j] = ssum[j] * scale + ps;
      m[j] = nm;
      scl[j] = scale;
    }
    plds[w][lane] = make_float4(p[0], p[1], p[2], p[3]);
    float sc = (h == 0) ? scl[0] : (h == 1) ? scl[1] : (h == 2) ? scl[2] : scl[3];
    acc.x *= sc; acc.y *= sc; acc.z *= sc; acc.w *= sc;
    for (int i = 0; i < ecount; ++i) {
      int s = slds[w][i];          // broadcast ds_read
      float pv = pbase[i * 4 + h]; // broadcast-within-16 ds_read
      uint2 raw = *reinterpret_cast<const uint2*>(xlh + (size_t)s * 256 + lane * 4); // 512B/row
      float2 f0 = __half22float2(__builtin_bit_cast(__half2, raw.x));
      float2 f1 = __half22float2(__builtin_bit_cast(__half2, raw.y));
      acc.x = fmaf(pv, f0.x, acc.x);
      acc.y = fmaf(pv, f0.y, acc.y);
      acc.z = fmaf(pv, f1.x, acc.z);
      acc.w = fmaf(pv, f1.y, acc.w);
    }
  }
  float sm = (h == 0) ? ssum[0] : (h == 1) ? ssum[1] : (h == 2) ? ssum[2] : ssum[3];
  float inv = 1.f / (sm + 1e-16f);
  float4 bv = reinterpret_cast<const float4*>(bias)[lane];
  float4 r;
  r.x = acc.x * inv + bv.x;
  r.y = acc.y * inv + bv.y;
  r.z = acc.z * inv + bv.z;
  r.w = acc.w * inv + bv.w;
  r.x = (r.x > 0.f) ? r.x : (__expf(r.x) - 1.f);
  r.y = (r.y > 0.f) ? r.y : (__expf(r.y) - 1.f);
  r.z = (r.z > 0.f) ? r.z : (__expf(r.z) - 1.f);
  r.w = (r.w > 0.f) ? r.w : (__expf(r.w) - 1.f);
  // split-bf16 write in MFMA-tiled layout (col c=4L+i: kb=L>>3, kg=(L>>1)&3, j=(L&1)*4+i)
  ushort4 hh, ll;
  hh.x = f2bf(r.x); ll.x = f2bf(r.x - bf2f(hh.x));
  hh.y = f2bf(r.y); ll.y = f2bf(r.y - bf2f(hh.y));
  hh.z = f2bf(r.z); ll.z = f2bf(r.z - bf2f(hh.z));
  hh.w = f2bf(r.w); ll.w = f2bf(r.w - bf2f(hh.w));
  const int mblk = d >> 4, rr = d & 15;
  const int kb = lane >> 3, kg = (lane >> 1) & 3, jj = (lane & 1) * 4;
  size_t base = ((size_t)mblk * 8 + kb) * 512 + (size_t)(kg * 16 + rr) * 8 + jj;
  *reinterpret_cast<ushort4*>(outHi + base) = hh;
  *reinterpret_cast<ushort4*>(outLo + base) = ll;
}

// layer 3 (H=1) + fused b3 + fc (64->2) + fc_b; fp16 gather; 4 edges per iteration
// (round-4 exact inner-loop addressing)
__global__ __launch_bounds__(256) void gat_final_kernel(const __half* __restrict__ xlh,
                                                        const float* __restrict__ a_srcv,
                                                        const float* __restrict__ a_dstv,
                                                        const int* __restrict__ csrOff,
                                                        const int* __restrict__ csrSrc,
                                                        const float* __restrict__ b3,
                                                        const float* __restrict__ fcw,
                                                        const float* __restrict__ fcb,
                                                        float* __restrict__ out) {
  __shared__ float plds[4][64];
  __shared__ int slds[4][64];
  const int w = threadIdx.x >> 6;
  const int lane = threadIdx.x & 63;
  const int d = blockIdx.x * 4 + w;
  if (d >= N_NODES) return;
  const int g = lane >> 4;   // edge subgroup
  const int c4 = lane & 15;  // 4-col group index
  int e0 = csrOff[d], e1 = csrOff[d + 1];
  float adv = a_dstv[d];
  float m = -1e30f, ssum = 0.f;
  float4 acc = make_float4(0.f, 0.f, 0.f, 0.f);

  for (int cb = e0; cb < e1; cb += 64) {
    int ecount = min(64, e1 - cb);
    int sidx = (lane < ecount) ? csrSrc[cb + lane] : 0;
    slds[w][lane] = sidx;
    float al = -1e30f;
    if (lane < ecount) {
      float v = a_srcv[sidx] + adv;
      al = (v > 0.f) ? v : 0.2f * v;
    }
    float cm = al;
#pragma unroll
    for (int o = 32; o > 0; o >>= 1) cm = fmaxf(cm, __shfl_xor(cm, o));
    float nm = fmaxf(m, cm);
    float scale = __expf(m - nm);
    float p = (lane < ecount) ? __expf(al - nm) : 0.f;
    float ps = p;
#pragma unroll
    for (int o = 32; o > 0; o >>= 1) ps += __shfl_xor(ps, o);
    ssum = ssum * scale + ps;
    m = nm;
    plds[w][lane] = p;
    acc.x *= scale; acc.y *= scale; acc.z *= scale; acc.w *= scale;
    for (int i = 0; i < ecount; i += 4) {
      int e = i + g; // <= 63 always; p==0 for e>=ecount
      int s = slds[w][e];
      float pv = plds[w][e];
      uint2 raw = *reinterpret_cast<const uint2*>(xlh + (size_t)s * 64 + c4 * 4); // 128B/row
      float2 f0 = __half22float2(__builtin_bit_cast(__half2, raw.x));
      float2 f1 = __half22float2(__builtin_bit_cast(__half2, raw.y));
      acc.x = fmaf(pv, f0.x, acc.x);
      acc.y = fmaf(pv, f0.y, acc.y);
      acc.z = fmaf(pv, f1.x, acc.z);
      acc.w = fmaf(pv, f1.y, acc.w);
    }
  }
#pragma unroll
  for (int o = 16; o <= 32; o <<= 1) {
    acc.x += __shfl_xor(acc.x, o);
    acc.y += __shfl_xor(acc.y, o);
    acc.z += __shfl_xor(acc.z, o);
    acc.w += __shfl_xor(acc.w, o);
  }
  float inv = 1.f / (ssum + 1e-16f);
  float4 bv = reinterpret_cast<const float4*>(b3)[c4];
  float4 v;
  v.x = acc.x * inv + bv.x;
  v.y = acc.y * inv + bv.y;
  v.z = acc.z * inv + bv.z;
  v.w = acc.w * inv + bv.w;
  const float2* fcw2 = reinterpret_cast<const float2*>(fcw);
  float2 w0 = fcw2[c4 * 4 + 0], w1 = fcw2[c4 * 4 + 1], w2 = fcw2[c4 * 4 + 2], w3 = fcw2[c4 * 4 + 3];
  float l0 = v.x * w0.x + v.y * w1.x + v.z * w2.x + v.w * w3.x;
  float l1 = v.x * w0.y + v.y * w1.y + v.z * w2.y + v.w * w3.y;
#pragma unroll
  for (int o = 1; o <= 8; o <<= 1) {
    l0 += __shfl_xor(l0, o);
    l1 += __shfl_xor(l1, o);
  }
  if (lane == 0) {
    out[2 * d + 0] = l0 + fcb[0];
    out[2 * d + 1] = l1 + fcb[1];
  }
}

extern "C" void kernel_launch(void* const* d_in, const int* in_sizes, int n_in,
                              void* d_out, int out_size, void* d_ws, size_t ws_size,
                              hipStream_t stream) {
  (void)in_sizes; (void)n_in; (void)out_size; (void)ws_size;
  const float* x      = (const float*)d_in[0];
  const void*  eidx   = d_in[1];
  const float* W1     = (const float*)d_in[2];
  const float* att_s1 = (const float*)d_in[3];
  const float* att_d1 = (const float*)d_in[4];
  const float* b1     = (const float*)d_in[5];
  const float* W2     = (const float*)d_in[6];
  const float* att_s2 = (const float*)d_in[7];
  const float* att_d2 = (const float*)d_in[8];
  const float* b2     = (const float*)d_in[9];
  const float* W3     = (const float*)d_in[10];
  const float* att_s3 = (const float*)d_in[11];
  const float* att_d3 = (const float*)d_in[12];
  const float* b3     = (const float*)d_in[13];
  const float* fcw    = (const float*)d_in[14];
  const float* fcb    = (const float*)d_in[15];
  float* out = (float*)d_out;

  char* ws = (char*)d_ws;
  size_t off = 0;
  auto alloc = [&](size_t bytes) -> void* {
    void* p = (void*)(ws + off);
    off += (bytes + 255) & ~(size_t)255;
    return p;
  };
  int*   srcI   = (int*)alloc((size_t)N_EDGES * 4);
  int*   dstI   = (int*)alloc((size_t)N_EDGES * 4);
  int*   cnt    = (int*)alloc((size_t)N_NODES * 4);
  int*   fillc  = (int*)alloc((size_t)N_NODES * 4);
  int*   csrOff = (int*)alloc((size_t)(N_NODES + 1) * 4);
  int*   csrSrc = (int*)alloc((size_t)ETOT * 4);
  int*   flag   = (int*)alloc(256);
  float* a_s    = (float*)alloc((size_t)N_NODES * HEADS * 4);
  float* a_d    = (float*)alloc((size_t)N_NODES * HEADS * 4);
  unsigned short* Ahi = (unsigned short*)alloc((size_t)MP * F1 * 2);
  unsigned short* Alo = (unsigned short*)alloc((size_t)MP * F1 * 2);
  unsigned short* Whi = (unsigned short*)alloc((size_t)(WOFF3 + 16384) * 2);
  unsigned short* Wlo = (unsigned short*)alloc((size_t)(WOFF3 + 16384) * 2);
  __half* xlh  = (__half*)alloc((size_t)MP * F1 * 2);   // fp16 xl (layers 1,2)
  __half* xlh3 = (__half*)alloc((size_t)MP * HIDC * 2); // fp16 xl (layer 3)

  // ---- graph build + all weight conversions up front ----
  detect_init_kernel<<<(N_NODES + 255) / 256, 256, 0, stream>>>((const unsigned int*)eidx, flag, cnt, fillc);
  decode_hist_kernel<<<(N_EDGES + 255) / 256, 256, 0, stream>>>(eidx, flag, srcI, dstI, cnt);
  scan_kernel<<<1, 1024, 0, stream>>>(cnt, csrOff);
  fill_kernel<<<(ETOT + 255) / 256, 256, 0, stream>>>(srcI, dstI, csrOff, fillc, csrSrc);
  convW_all_kernel<<<(WTOT_ITEMS + 255) / 256, 256, 0, stream>>>(W1, W2, W3, Whi, Wlo);

  const int gn = (N_NODES + 3) / 4;  // 12500
  const int gmb = MP / 16;           // 3128
  const int gx = MP / 128;           // 391

  // ---- Layer 1: x[N,128] @ W1[128,256] ----
  convA_kernel<IN_DIM><<<gmb, 256, 0, stream>>>(x, Ahi, Alo, N_NODES);
  gemm_fused_kernel<4, 8, 4><<<dim3(gx, 2), 256, 0, stream>>>(Ahi, Alo, Whi + WOFF1, Wlo + WOFF1,
                                                              att_s1, att_d1, xlh, a_s, a_d, N_NODES, F1);
  gat_agg4_kernel<<<gn, 256, 0, stream>>>(xlh, a_s, a_d, csrOff, csrSrc, b1, Ahi, Alo);

  // ---- Layer 2: h1[N,256] @ W2[256,256] (A from agg epilogue, tiled) ----
  gemm_fused_kernel<8, 8, 4><<<dim3(gx, 2), 256, 0, stream>>>(Ahi, Alo, Whi + WOFF2, Wlo + WOFF2,
                                                              att_s2, att_d2, xlh, a_s, a_d, N_NODES, F1);
  gat_agg4_kernel<<<gn, 256, 0, stream>>>(xlh, a_s, a_d, csrOff, csrSrc, b2, Ahi, Alo);

  // ---- Layer 3: h2[N,256] @ W3[256,64], H=1, fused fc ----
  gemm_fused_kernel<8, 4, 1><<<dim3(gx, 1), 256, 0, stream>>>(Ahi, Alo, Whi + WOFF3, Wlo + WOFF3,
                                                              att_s3, att_d3, xlh3, a_s, a_d, N_NODES, HIDC);
  gat_final_kernel<<<gn, 256, 0, stream>>>(xlh3, a_s, a_d, csrOff, csrSrc, b3, fcw, fcb, out);
}

// Round 7
// 419.588 us; speedup vs baseline: 1.9186x; 1.0638x over previous
//
#include <hip/hip_runtime.h>
#include <hip/hip_fp16.h>
#include <math.h>

#define N_NODES 50000
#define N_EDGES 800000
#define ETOT (N_EDGES + N_NODES)
#define IN_DIM 128
#define HIDC 64
#define HEADS 4
#define F1 (HEADS * HIDC) /* 256 */
#define MP 50048 /* N_NODES padded to 128 */

// tiled W buffer element offsets (within Whi/Wlo)
#define WOFF1 0
#define WOFF2 32768  /* 128*256 */
#define WOFF3 98304  /* + 256*256 */
#define WTOT_ITEMS 14336 /* 4096 + 8192 + 2048 work items (8 elems each) */

typedef _Float16 f16x8 __attribute__((ext_vector_type(8)));
typedef float f32x4 __attribute__((ext_vector_type(4)));
typedef unsigned short u16x8 __attribute__((ext_vector_type(8)));

__device__ inline unsigned short f2h_bits(float f) {
  _Float16 h = (_Float16)f;
  return __builtin_bit_cast(unsigned short, h);
}
__device__ inline float h_bits2f(unsigned short b) {
  return (float)__builtin_bit_cast(_Float16, b);
}

__device__ inline void gload_lds16(const void* g, void* l) {
  __builtin_amdgcn_global_load_lds(
      (const __attribute__((address_space(1))) unsigned int*)g,
      (__attribute__((address_space(3))) unsigned int*)l, 16, 0, 0);
}

// ---------------- dtype detect + cnt/fillc init (merged) ----------------
__global__ void detect_init_kernel(const unsigned int* __restrict__ buf, int* __restrict__ flag,
                                   int* __restrict__ cnt, int* __restrict__ fillc) {
  int i = blockIdx.x * blockDim.x + threadIdx.x;
  if (i < N_NODES) { cnt[i] = 1; fillc[i] = 0; } // self-loop pre-counted
  if (blockIdx.x == 0) {
    __shared__ int any;
    if (threadIdx.x == 0) any = 0;
    __syncthreads();
    for (int k = threadIdx.x; k < 2048; k += blockDim.x)
      if (buf[2 * k + 1] != 0u) any = 1;
    __syncthreads();
    if (threadIdx.x == 0) *flag = any; // 1 => int32, 0 => int64
  }
}

// decode + histogram in one pass
__global__ void decode_hist_kernel(const void* __restrict__ eidx, const int* __restrict__ flag,
                                   int* __restrict__ srcO, int* __restrict__ dstO,
                                   int* __restrict__ cnt) {
  int i = blockIdx.x * blockDim.x + threadIdx.x;
  if (i >= N_EDGES) return;
  int s, d;
  if (*flag) {
    const int* b = (const int*)eidx;
    s = b[i]; d = b[N_EDGES + i];
  } else {
    const long long* b = (const long long*)eidx;
    s = (int)b[i]; d = (int)b[N_EDGES + i];
  }
  srcO[i] = s;
  dstO[i] = d;
  atomicAdd(&cnt[d], 1);
}

__global__ __launch_bounds__(1024) void scan_kernel(const int* __restrict__ cnt, int* __restrict__ off) {
  const int T = 1024;
  const int n = N_NODES;
  int tid = threadIdx.x;
  int chunk = (n + T - 1) / T;
  int s0 = tid * chunk;
  int s1 = min(s0 + chunk, n);
  int sum = 0;
  for (int i = s0; i < s1; ++i) sum += cnt[i];
  __shared__ int tmp[T];
  tmp[tid] = sum;
  __syncthreads();
  for (int o = 1; o < T; o <<= 1) {
    int t = (tid >= o) ? tmp[tid - o] : 0;
    __syncthreads();
    tmp[tid] += t;
    __syncthreads();
  }
  int run = tmp[tid] - sum;
  for (int i = s0; i < s1; ++i) {
    off[i] = run;
    run += cnt[i];
  }
  if (tid == T - 1) off[n] = run;
}

__global__ void fill_kernel(const int* __restrict__ src, const int* __restrict__ dst,
                            const int* __restrict__ csrOff, int* __restrict__ fillc,
                            int* __restrict__ csrSrc) {
  int i = blockIdx.x * blockDim.x + threadIdx.x;
  if (i >= ETOT) return;
  int s, d;
  if (i < N_EDGES) { s = src[i]; d = dst[i]; } else { s = i - N_EDGES; d = s; }
  int pos = csrOff[d] + atomicAdd(&fillc[d], 1);
  csrSrc[pos] = s;
}

// ---------------- fp32 -> fp16, MFMA fragment-tiled layout ----------------
// tiled: [MP/16][K/32][kg=4][r=16][j=8]  (each 16x32 fragment = contiguous 1KB... 512 u16)
template <int K>
__global__ __launch_bounds__(256) void convA_kernel(const float* __restrict__ A,
                                                    unsigned short* __restrict__ At, int M) {
  __shared__ float ld[16][264];
  const int mblk = blockIdx.x;
  const int tid = threadIdx.x;
  const int elems = 16 * K;
#pragma unroll
  for (int e = tid * 4; e < elems; e += 1024) {
    int r = e / K, c = e % K;
    int row = mblk * 16 + r;
    float4 v = make_float4(0.f, 0.f, 0.f, 0.f);
    if (row < M) v = *reinterpret_cast<const float4*>(&A[(size_t)row * K + c]);
    ld[r][c + 0] = v.x; ld[r][c + 1] = v.y; ld[r][c + 2] = v.z; ld[r][c + 3] = v.w;
  }
  __syncthreads();
#pragma unroll
  for (int o = tid * 8; o < elems; o += 2048) {
    int r = (o >> 3) & 15;
    int kg = (o >> 7) & 3;
    int kb = o >> 9;
    int k0 = kb * 32 + kg * 8;
    u16x8 h8;
#pragma unroll
    for (int j = 0; j < 8; ++j) h8[j] = f2h_bits(ld[r][k0 + j]);
    size_t base = ((size_t)mblk * (K >> 5) + kb) * 512 + (size_t)(kg * 16 + r) * 8;
    *reinterpret_cast<u16x8*>(At + base) = h8;
  }
}

// all three W matrices -> tiled fp16 hi/lo [Nw/16][K/32][kg=4][c=16][j=8], one launch
__device__ inline void convW_item(const float* __restrict__ W, int K, int Nw, int t,
                                  unsigned short* __restrict__ hi, unsigned short* __restrict__ lo) {
  int KB = K >> 5;
  int c = t & 15;
  int kg = (t >> 4) & 3;
  int kb = (t >> 6) % KB;
  int nblk = (t >> 6) / KB;
  int n = nblk * 16 + c;
  int k0 = kb * 32 + kg * 8;
  u16x8 h8, l8;
#pragma unroll
  for (int j = 0; j < 8; ++j) {
    float v = W[(size_t)(k0 + j) * Nw + n];
    unsigned short h = f2h_bits(v);
    h8[j] = h;
    l8[j] = f2h_bits(v - h_bits2f(h));
  }
  *reinterpret_cast<u16x8*>(hi + (size_t)t * 8) = h8;
  *reinterpret_cast<u16x8*>(lo + (size_t)t * 8) = l8;
}

__global__ void convW_all_kernel(const float* __restrict__ W1, const float* __restrict__ W2,
                                 const float* __restrict__ W3,
                                 unsigned short* __restrict__ hi, unsigned short* __restrict__ lo) {
  int t = blockIdx.x * blockDim.x + threadIdx.x;
  if (t >= WTOT_ITEMS) return;
  if (t < 4096) {
    convW_item(W1, IN_DIM, F1, t, hi + WOFF1, lo + WOFF1);
  } else if (t < 4096 + 8192) {
    convW_item(W2, F1, F1, t - 4096, hi + WOFF2, lo + WOFF2);
  } else {
    convW_item(W3, F1, HIDC, t - (4096 + 8192), hi + WOFF3, lo + WOFF3);
  }
}

// ---------------- fp16 MFMA GEMM (2-product: A*Whi + A*Wlo) + fused att-proj epilogue ----------------
template <int KB, int NB, int H>
__global__ __launch_bounds__(256) void gemm_f16_kernel(
    const unsigned short* __restrict__ At,
    const unsigned short* __restrict__ Bhi, const unsigned short* __restrict__ Blo,
    const float* __restrict__ atts, const float* __restrict__ attd,
    __half* __restrict__ Ch, float* __restrict__ a_s, float* __restrict__ a_d,
    int M, int Nout) {
  __shared__ unsigned short As[8 * 512];
  __shared__ unsigned short BsH[NB * 512], BsL[NB * 512];
  const int tid = threadIdx.x;
  const int w = tid >> 6, lane = tid & 63;
  const size_t machunk = ((size_t)blockIdx.x * 8 + w * 2) * KB;
  const int nblk0 = blockIdx.y * NB;
  const int laneo = lane * 8;

  f32x4 acc[2][NB];
#pragma unroll
  for (int mi = 0; mi < 2; ++mi)
#pragma unroll
    for (int nj = 0; nj < NB; ++nj) acc[mi][nj] = {0.f, 0.f, 0.f, 0.f};

  for (int kb = 0; kb < KB; ++kb) {
    gload_lds16(At + (machunk + kb) * 512 + laneo, As + (w * 2) * 512);
    gload_lds16(At + (machunk + (size_t)KB + kb) * 512 + laneo, As + (w * 2 + 1) * 512);
#pragma unroll
    for (int q = 0; q < NB / 4; ++q) {
      int nbl = w * (NB / 4) + q;
      size_t bo = ((size_t)(nblk0 + nbl) * KB + kb) * 512 + laneo;
      gload_lds16(Bhi + bo, BsH + nbl * 512);
      gload_lds16(Blo + bo, BsL + nbl * 512);
    }
    __syncthreads();
    f16x8 a0 = *reinterpret_cast<const f16x8*>(As + (w * 2) * 512 + laneo);
    f16x8 a1 = *reinterpret_cast<const f16x8*>(As + (w * 2 + 1) * 512 + laneo);
#pragma unroll
    for (int nj = 0; nj < NB; ++nj) {
      f16x8 bh = *reinterpret_cast<const f16x8*>(BsH + nj * 512 + laneo);
      f16x8 bl = *reinterpret_cast<const f16x8*>(BsL + nj * 512 + laneo);
      acc[0][nj] = __builtin_amdgcn_mfma_f32_16x16x32_f16(a0, bh, acc[0][nj], 0, 0, 0);
      acc[1][nj] = __builtin_amdgcn_mfma_f32_16x16x32_f16(a1, bh, acc[1][nj], 0, 0, 0);
      acc[0][nj] = __builtin_amdgcn_mfma_f32_16x16x32_f16(a0, bl, acc[0][nj], 0, 0, 0);
      acc[1][nj] = __builtin_amdgcn_mfma_f32_16x16x32_f16(a1, bl, acc[1][nj], 0, 0, 0);
    }
    __syncthreads();
  }
  // ---- epilogue: fp16 store + fused att dot products ----
  const int col0 = nblk0 * 16 + (lane & 15);
  const int row0 = blockIdx.x * 128 + w * 32 + (lane >> 4) * 4;
  float attsv[NB], attdv[NB];
#pragma unroll
  for (int nj = 0; nj < NB; ++nj) {
    int gcol = nblk0 + nj;
    int hh = gcol >> 2;
    int coff = (gcol & 3) * 16 + (lane & 15);
    attsv[nj] = atts[hh * 64 + coff];
    attdv[nj] = attd[hh * 64 + coff];
  }
#pragma unroll
  for (int mi = 0; mi < 2; ++mi) {
#pragma unroll
    for (int nj = 0; nj < NB; ++nj) {
      int col = col0 + nj * 16;
#pragma unroll
      for (int r = 0; r < 4; ++r) {
        int row = row0 + mi * 16 + r;
        if (row < M) Ch[(size_t)row * Nout + col] = __float2half(acc[mi][nj][r]);
      }
    }
#pragma unroll
    for (int r = 0; r < 4; ++r) {
      int row = row0 + mi * 16 + r;
#pragma unroll
      for (int g = 0; g < NB / 4; ++g) {
        float ps = 0.f, pd = 0.f;
#pragma unroll
        for (int q = 0; q < 4; ++q) {
          float v = acc[mi][g * 4 + q][r];
          ps = fmaf(v, attsv[g * 4 + q], ps);
          pd = fmaf(v, attdv[g * 4 + q], pd);
        }
#pragma unroll
        for (int o = 1; o <= 8; o <<= 1) {
          ps += __shfl_xor(ps, o);
          pd += __shfl_xor(pd, o);
        }
        if ((lane & 15) == 0 && row < M) {
          int hh = (nblk0 + g * 4) >> 2;
          a_s[(size_t)row * H + hh] = ps;
          a_d[(size_t)row * H + hh] = pd;
        }
      }
    }
  }
}

// ---------------- H=4 edge softmax + aggregate; fp16 gather; writes fp16 tiled + ELU ----------------
// (round-4 exact inner-loop addressing: 40 VGPR / 79us / 55% occ measured)
__global__ __launch_bounds__(256) void gat_agg4_kernel(const __half* __restrict__ xlh,
                                                       const float* __restrict__ a_srcv,
                                                       const float* __restrict__ a_dstv,
                                                       const int* __restrict__ csrOff,
                                                       const int* __restrict__ csrSrc,
                                                       const float* __restrict__ bias,
                                                       unsigned short* __restrict__ outT) {
  __shared__ float4 plds[4][64];
  __shared__ int slds[4][64];
  const int w = threadIdx.x >> 6;
  const int lane = threadIdx.x & 63;
  const int d = blockIdx.x * 4 + w;
  if (d >= N_NODES) return;
  const int h = lane >> 4;
  int e0 = csrOff[d], e1 = csrOff[d + 1];
  float4 adv = reinterpret_cast<const float4*>(a_dstv)[d];
  float m[4], ssum[4];
#pragma unroll
  for (int j = 0; j < 4; ++j) { m[j] = -1e30f; ssum[j] = 0.f; }
  float4 acc = make_float4(0.f, 0.f, 0.f, 0.f);
  const float* pbase = reinterpret_cast<const float*>(&plds[w][0]);

  for (int cb = e0; cb < e1; cb += 64) {
    int ecount = min(64, e1 - cb);
    int sidx = (lane < ecount) ? csrSrc[cb + lane] : 0;
    slds[w][lane] = sidx;
    float4 asv = make_float4(0.f, 0.f, 0.f, 0.f);
    if (lane < ecount) asv = reinterpret_cast<const float4*>(a_srcv)[sidx];
    float p[4], scl[4];
#pragma unroll
    for (int j = 0; j < 4; ++j) {
      float av = (j == 0) ? asv.x : (j == 1) ? asv.y : (j == 2) ? asv.z : asv.w;
      float dv = (j == 0) ? adv.x : (j == 1) ? adv.y : (j == 2) ? adv.z : adv.w;
      float al = -1e30f;
      if (lane < ecount) {
        float v = av + dv;
        al = (v > 0.f) ? v : 0.2f * v;
      }
      float cm = al;
#pragma unroll
      for (int o = 32; o > 0; o >>= 1) cm = fmaxf(cm, __shfl_xor(cm, o));
      float nm = fmaxf(m[j], cm);
      float scale = __expf(m[j] - nm); // first chunk: exp(-inf)=0
      p[j] = (lane < ecount) ? __expf(al - nm) : 0.f;
      float ps = p[j];
#pragma unroll
      for (int o = 32; o > 0; o >>= 1) ps += __shfl_xor(ps, o);
      ssum[j] = ssum[j] * scale + ps;
      m[j] = nm;
      scl[j] = scale;
    }
    plds[w][lane] = make_float4(p[0], p[1], p[2], p[3]);
    float sc = (h == 0) ? scl[0] : (h == 1) ? scl[1] : (h == 2) ? scl[2] : scl[3];
    acc.x *= sc; acc.y *= sc; acc.z *= sc; acc.w *= sc;
    for (int i = 0; i < ecount; ++i) {
      int s = slds[w][i];          // broadcast ds_read
      float pv = pbase[i * 4 + h]; // broadcast-within-16 ds_read
      uint2 raw = *reinterpret_cast<const uint2*>(xlh + (size_t)s * 256 + lane * 4); // 512B/row
      float2 f0 = __half22float2(__builtin_bit_cast(__half2, raw.x));
      float2 f1 = __half22float2(__builtin_bit_cast(__half2, raw.y));
      acc.x = fmaf(pv, f0.x, acc.x);
      acc.y = fmaf(pv, f0.y, acc.y);
      acc.z = fmaf(pv, f1.x, acc.z);
      acc.w = fmaf(pv, f1.y, acc.w);
    }
  }
  float sm = (h == 0) ? ssum[0] : (h == 1) ? ssum[1] : (h == 2) ? ssum[2] : ssum[3];
  float inv = 1.f / (sm + 1e-16f);
  float4 bv = reinterpret_cast<const float4*>(bias)[lane];
  float4 r;
  r.x = acc.x * inv + bv.x;
  r.y = acc.y * inv + bv.y;
  r.z = acc.z * inv + bv.z;
  r.w = acc.w * inv + bv.w;
  r.x = (r.x > 0.f) ? r.x : (__expf(r.x) - 1.f);
  r.y = (r.y > 0.f) ? r.y : (__expf(r.y) - 1.f);
  r.z = (r.z > 0.f) ? r.z : (__expf(r.z) - 1.f);
  r.w = (r.w > 0.f) ? r.w : (__expf(r.w) - 1.f);
  // fp16 write in MFMA-tiled layout (col c=4L+i: kb=L>>3, kg=(L>>1)&3, j=(L&1)*4+i)
  ushort4 hh;
  hh.x = f2h_bits(r.x);
  hh.y = f2h_bits(r.y);
  hh.z = f2h_bits(r.z);
  hh.w = f2h_bits(r.w);
  const int mblk = d >> 4, rr = d & 15;
  const int kb = lane >> 3, kg = (lane >> 1) & 3, jj = (lane & 1) * 4;
  size_t base = ((size_t)mblk * 8 + kb) * 512 + (size_t)(kg * 16 + rr) * 8 + jj;
  *reinterpret_cast<ushort4*>(outT + base) = hh;
}

// layer 3 (H=1) + fused b3 + fc (64->2) + fc_b; fp16 gather; 4 edges per iteration
__global__ __launch_bounds__(256) void gat_final_kernel(const __half* __restrict__ xlh,
                                                        const float* __restrict__ a_srcv,
                                                        const float* __restrict__ a_dstv,
                                                        const int* __restrict__ csrOff,
                                                        const int* __restrict__ csrSrc,
                                                        const float* __restrict__ b3,
                                                        const float* __restrict__ fcw,
                                                        const float* __restrict__ fcb,
                                                        float* __restrict__ out) {
  __shared__ float plds[4][64];
  __shared__ int slds[4][64];
  const int w = threadIdx.x >> 6;
  const int lane = threadIdx.x & 63;
  const int d = blockIdx.x * 4 + w;
  if (d >= N_NODES) return;
  const int g = lane >> 4;   // edge subgroup
  const int c4 = lane & 15;  // 4-col group index
  int e0 = csrOff[d], e1 = csrOff[d + 1];
  float adv = a_dstv[d];
  float m = -1e30f, ssum = 0.f;
  float4 acc = make_float4(0.f, 0.f, 0.f, 0.f);

  for (int cb = e0; cb < e1; cb += 64) {
    int ecount = min(64, e1 - cb);
    int sidx = (lane < ecount) ? csrSrc[cb + lane] : 0;
    slds[w][lane] = sidx;
    float al = -1e30f;
    if (lane < ecount) {
      float v = a_srcv[sidx] + adv;
      al = (v > 0.f) ? v : 0.2f * v;
    }
    float cm = al;
#pragma unroll
    for (int o = 32; o > 0; o >>= 1) cm = fmaxf(cm, __shfl_xor(cm, o));
    float nm = fmaxf(m, cm);
    float scale = __expf(m - nm);
    float p = (lane < ecount) ? __expf(al - nm) : 0.f;
    float ps = p;
#pragma unroll
    for (int o = 32; o > 0; o >>= 1) ps += __shfl_xor(ps, o);
    ssum = ssum * scale + ps;
    m = nm;
    plds[w][lane] = p;
    acc.x *= scale; acc.y *= scale; acc.z *= scale; acc.w *= scale;
    for (int i = 0; i < ecount; i += 4) {
      int e = i + g; // <= 63 always; p==0 for e>=ecount
      int s = slds[w][e];
      float pv = plds[w][e];
      uint2 raw = *reinterpret_cast<const uint2*>(xlh + (size_t)s * 64 + c4 * 4); // 128B/row
      float2 f0 = __half22float2(__builtin_bit_cast(__half2, raw.x));
      float2 f1 = __half22float2(__builtin_bit_cast(__half2, raw.y));
      acc.x = fmaf(pv, f0.x, acc.x);
      acc.y = fmaf(pv, f0.y, acc.y);
      acc.z = fmaf(pv, f1.x, acc.z);
      acc.w = fmaf(pv, f1.y, acc.w);
    }
  }
#pragma unroll
  for (int o = 16; o <= 32; o <<= 1) {
    acc.x += __shfl_xor(acc.x, o);
    acc.y += __shfl_xor(acc.y, o);
    acc.z += __shfl_xor(acc.z, o);
    acc.w += __shfl_xor(acc.w, o);
  }
  float inv = 1.f / (ssum + 1e-16f);
  float4 bv = reinterpret_cast<const float4*>(b3)[c4];
  float4 v;
  v.x = acc.x * inv + bv.x;
  v.y = acc.y * inv + bv.y;
  v.z = acc.z * inv + bv.z;
  v.w = acc.w * inv + bv.w;
  const float2* fcw2 = reinterpret_cast<const float2*>(fcw);
  float2 w0 = fcw2[c4 * 4 + 0], w1 = fcw2[c4 * 4 + 1], w2 = fcw2[c4 * 4 + 2], w3 = fcw2[c4 * 4 + 3];
  float l0 = v.x * w0.x + v.y * w1.x + v.z * w2.x + v.w * w3.x;
  float l1 = v.x * w0.y + v.y * w1.y + v.z * w2.y + v.w * w3.y;
#pragma unroll
  for (int o = 1; o <= 8; o <<= 1) {
    l0 += __shfl_xor(l0, o);
    l1 += __shfl_xor(l1, o);
  }
  if (lane == 0) {
    out[2 * d + 0] = l0 + fcb[0];
    out[2 * d + 1] = l1 + fcb[1];
  }
}

extern "C" void kernel_launch(void* const* d_in, const int* in_sizes, int n_in,
                              void* d_out, int out_size, void* d_ws, size_t ws_size,
                              hipStream_t stream) {
  (void)in_sizes; (void)n_in; (void)out_size; (void)ws_size;
  const float* x      = (const float*)d_in[0];
  const void*  eidx   = d_in[1];
  const float* W1     = (const float*)d_in[2];
  const float* att_s1 = (const float*)d_in[3];
  const float* att_d1 = (const float*)d_in[4];
  const float* b1     = (const float*)d_in[5];
  const float* W2     = (const float*)d_in[6];
  const float* att_s2 = (const float*)d_in[7];
  const float* att_d2 = (const float*)d_in[8];
  const float* b2     = (const float*)d_in[9];
  const float* W3     = (const float*)d_in[10];
  const float* att_s3 = (const float*)d_in[11];
  const float* att_d3 = (const float*)d_in[12];
  const float* b3     = (const float*)d_in[13];
  const float* fcw    = (const float*)d_in[14];
  const float* fcb    = (const float*)d_in[15];
  float* out = (float*)d_out;

  char* ws = (char*)d_ws;
  size_t off = 0;
  auto alloc = [&](size_t bytes) -> void* {
    void* p = (void*)(ws + off);
    off += (bytes + 255) & ~(size_t)255;
    return p;
  };
  int*   srcI   = (int*)alloc((size_t)N_EDGES * 4);
  int*   dstI   = (int*)alloc((size_t)N_EDGES * 4);
  int*   cnt    = (int*)alloc((size_t)N_NODES * 4);
  int*   fillc  = (int*)alloc((size_t)N_NODES * 4);
  int*   csrOff = (int*)alloc((size_t)(N_NODES + 1) * 4);
  int*   csrSrc = (int*)alloc((size_t)ETOT * 4);
  int*   flag   = (int*)alloc(256);
  float* a_s    = (float*)alloc((size_t)N_NODES * HEADS * 4);
  float* a_d    = (float*)alloc((size_t)N_NODES * HEADS * 4);
  unsigned short* At  = (unsigned short*)alloc((size_t)MP * F1 * 2); // tiled fp16 A
  unsigned short* Whi = (unsigned short*)alloc((size_t)(WOFF3 + 16384) * 2);
  unsigned short* Wlo = (unsigned short*)alloc((size_t)(WOFF3 + 16384) * 2);
  __half* xlh  = (__half*)alloc((size_t)MP * F1 * 2);   // fp16 xl (layers 1,2)
  __half* xlh3 = (__half*)alloc((size_t)MP * HIDC * 2); // fp16 xl (layer 3)

  // ---- graph build + all weight conversions up front ----
  detect_init_kernel<<<(N_NODES + 255) / 256, 256, 0, stream>>>((const unsigned int*)eidx, flag, cnt, fillc);
  decode_hist_kernel<<<(N_EDGES + 255) / 256, 256, 0, stream>>>(eidx, flag, srcI, dstI, cnt);
  scan_kernel<<<1, 1024, 0, stream>>>(cnt, csrOff);
  fill_kernel<<<(ETOT + 255) / 256, 256, 0, stream>>>(srcI, dstI, csrOff, fillc, csrSrc);
  convW_all_kernel<<<(WTOT_ITEMS + 255) / 256, 256, 0, stream>>>(W1, W2, W3, Whi, Wlo);

  const int gn = (N_NODES + 3) / 4;  // 12500
  const int gmb = MP / 16;           // 3128
  const int gx = MP / 128;           // 391

  // ---- Layer 1: x[N,128] @ W1[128,256] ----
  convA_kernel<IN_DIM><<<gmb, 256, 0, stream>>>(x, At, N_NODES);
  gemm_f16_kernel<4, 8, 4><<<dim3(gx, 2), 256, 0, stream>>>(At, Whi + WOFF1, Wlo + WOFF1,
                                                            att_s1, att_d1, xlh, a_s, a_d, N_NODES, F1);
  gat_agg4_kernel<<<gn, 256, 0, stream>>>(xlh, a_s, a_d, csrOff, csrSrc, b1, At);

  // ---- Layer 2: h1[N,256] @ W2[256,256] (A from agg epilogue, tiled fp16) ----
  gemm_f16_kernel<8, 8, 4><<<dim3(gx, 2), 256, 0, stream>>>(At, Whi + WOFF2, Wlo + WOFF2,
                                                            att_s2, att_d2, xlh, a_s, a_d, N_NODES, F1);
  gat_agg4_kernel<<<gn, 256, 0, stream>>>(xlh, a_s, a_d, csrOff, csrSrc, b2, At);

  // ---- Layer 3: h2[N,256] @ W3[256,64], H=1, fused fc ----
  gemm_f16_kernel<8, 4, 1><<<dim3(gx, 1), 256, 0, stream>>>(At, Whi + WOFF3, Wlo + WOFF3,
                                                            att_s3, att_d3, xlh3, a_s, a_d, N_NODES, HIDC);
  gat_final_kernel<<<gn, 256, 0, stream>>>(xlh3, a_s, a_d, csrOff, csrSrc, b3, fcw, fcb, out);
}

// Round 8
// 354.675 us; speedup vs baseline: 2.2697x; 1.1830x over previous
//
#include <hip/hip_runtime.h>
#include <hip/hip_fp16.h>
#include <math.h>

#define N_NODES 50000
#define N_EDGES 800000
#define ETOT (N_EDGES + N_NODES)
#define IN_DIM 128
#define HIDC 64
#define HEADS 4
#define F1 (HEADS * HIDC) /* 256 */
#define MP 50048 /* N_NODES padded to 128 */
#define SCAN_BLOCKS 196 /* ceil(N_NODES/256) */

// tiled W buffer element offsets (within Whi/Wlo)
#define WOFF1 0
#define WOFF2 32768  /* 128*256 */
#define WOFF3 98304  /* + 256*256 */
#define WTOT_ITEMS 14336 /* 4096 + 8192 + 2048 work items (8 elems each) */

typedef _Float16 f16x8 __attribute__((ext_vector_type(8)));
typedef float f32x4 __attribute__((ext_vector_type(4)));
typedef unsigned short u16x8 __attribute__((ext_vector_type(8)));

__device__ inline unsigned short f2h_bits(float f) {
  _Float16 h = (_Float16)f;
  return __builtin_bit_cast(unsigned short, h);
}
__device__ inline float h_bits2f(unsigned short b) {
  return (float)__builtin_bit_cast(_Float16, b);
}

__device__ inline void gload_lds16(const void* g, void* l) {
  __builtin_amdgcn_global_load_lds(
      (const __attribute__((address_space(1))) unsigned int*)g,
      (__attribute__((address_space(3))) unsigned int*)l, 16, 0, 0);
}

// ---------------- dtype detect + cnt/fillc init (merged) ----------------
__global__ void detect_init_kernel(const unsigned int* __restrict__ buf, int* __restrict__ flag,
                                   int* __restrict__ cnt, int* __restrict__ fillc) {
  int i = blockIdx.x * blockDim.x + threadIdx.x;
  if (i < N_NODES) { cnt[i] = 1; fillc[i] = 0; } // self-loop pre-counted
  if (blockIdx.x == 0) {
    __shared__ int any;
    if (threadIdx.x == 0) any = 0;
    __syncthreads();
    for (int k = threadIdx.x; k < 2048; k += blockDim.x)
      if (buf[2 * k + 1] != 0u) any = 1;
    __syncthreads();
    if (threadIdx.x == 0) *flag = any; // 1 => int32, 0 => int64
  }
}

// decode + histogram in one pass
__global__ void decode_hist_kernel(const void* __restrict__ eidx, const int* __restrict__ flag,
                                   int* __restrict__ srcO, int* __restrict__ dstO,
                                   int* __restrict__ cnt) {
  int i = blockIdx.x * blockDim.x + threadIdx.x;
  if (i >= N_EDGES) return;
  int s, d;
  if (*flag) {
    const int* b = (const int*)eidx;
    s = b[i]; d = b[N_EDGES + i];
  } else {
    const long long* b = (const long long*)eidx;
    s = (int)b[i]; d = (int)b[N_EDGES + i];
  }
  srcO[i] = s;
  dstO[i] = d;
  atomicAdd(&cnt[d], 1);
}

// ---------------- 3-phase multi-block exclusive scan ----------------
__global__ __launch_bounds__(256) void scan1_kernel(const int* __restrict__ cnt,
                                                    int* __restrict__ escan,
                                                    int* __restrict__ bsum) {
  __shared__ int tmp[256];
  const int t = threadIdx.x;
  const int i = blockIdx.x * 256 + t;
  int v = (i < N_NODES) ? cnt[i] : 0;
  tmp[t] = v;
  __syncthreads();
#pragma unroll
  for (int o = 1; o < 256; o <<= 1) {
    int u = (t >= o) ? tmp[t - o] : 0;
    __syncthreads();
    tmp[t] += u;
    __syncthreads();
  }
  if (i < N_NODES) escan[i] = tmp[t] - v; // exclusive within block
  if (t == 255) bsum[blockIdx.x] = tmp[255];
}

__global__ __launch_bounds__(256) void scan2_kernel(const int* __restrict__ bsum,
                                                    int* __restrict__ boff) {
  __shared__ int tmp[256];
  const int t = threadIdx.x;
  int v = (t < SCAN_BLOCKS) ? bsum[t] : 0;
  tmp[t] = v;
  __syncthreads();
#pragma unroll
  for (int o = 1; o < 256; o <<= 1) {
    int u = (t >= o) ? tmp[t - o] : 0;
    __syncthreads();
    tmp[t] += u;
    __syncthreads();
  }
  if (t < SCAN_BLOCKS) boff[t] = tmp[t] - v;
}

__global__ __launch_bounds__(256) void scan3_kernel(const int* __restrict__ escan,
                                                    const int* __restrict__ boff,
                                                    int* __restrict__ off) {
  const int i = blockIdx.x * 256 + threadIdx.x;
  if (i < N_NODES) off[i] = escan[i] + boff[blockIdx.x];
  if (i == 0) off[N_NODES] = ETOT; // total is a structural constant
}

__global__ void fill_kernel(const int* __restrict__ src, const int* __restrict__ dst,
                            const int* __restrict__ csrOff, int* __restrict__ fillc,
                            int* __restrict__ csrSrc) {
  int i = blockIdx.x * blockDim.x + threadIdx.x;
  if (i >= ETOT) return;
  int s, d;
  if (i < N_EDGES) { s = src[i]; d = dst[i]; } else { s = i - N_EDGES; d = s; }
  int pos = csrOff[d] + atomicAdd(&fillc[d], 1);
  csrSrc[pos] = s;
}

// ---------------- fp32 -> fp16, MFMA fragment-tiled layout ----------------
// tiled: [MP/16][K/32][kg=4][r=16][j=8]  (each 16x32 fragment = contiguous 512 u16)
template <int K>
__global__ __launch_bounds__(256) void convA_kernel(const float* __restrict__ A,
                                                    unsigned short* __restrict__ At, int M) {
  __shared__ float ld[16][264];
  const int mblk = blockIdx.x;
  const int tid = threadIdx.x;
  const int elems = 16 * K;
#pragma unroll
  for (int e = tid * 4; e < elems; e += 1024) {
    int r = e / K, c = e % K;
    int row = mblk * 16 + r;
    float4 v = make_float4(0.f, 0.f, 0.f, 0.f);
    if (row < M) v = *reinterpret_cast<const float4*>(&A[(size_t)row * K + c]);
    ld[r][c + 0] = v.x; ld[r][c + 1] = v.y; ld[r][c + 2] = v.z; ld[r][c + 3] = v.w;
  }
  __syncthreads();
#pragma unroll
  for (int o = tid * 8; o < elems; o += 2048) {
    int r = (o >> 3) & 15;
    int kg = (o >> 7) & 3;
    int kb = o >> 9;
    int k0 = kb * 32 + kg * 8;
    u16x8 h8;
#pragma unroll
    for (int j = 0; j < 8; ++j) h8[j] = f2h_bits(ld[r][k0 + j]);
    size_t base = ((size_t)mblk * (K >> 5) + kb) * 512 + (size_t)(kg * 16 + r) * 8;
    *reinterpret_cast<u16x8*>(At + base) = h8;
  }
}

// all three W matrices -> tiled fp16 hi/lo [Nw/16][K/32][kg=4][c=16][j=8], one launch
__device__ inline void convW_item(const float* __restrict__ W, int K, int Nw, int t,
                                  unsigned short* __restrict__ hi, unsigned short* __restrict__ lo) {
  int KB = K >> 5;
  int c = t & 15;
  int kg = (t >> 4) & 3;
  int kb = (t >> 6) % KB;
  int nblk = (t >> 6) / KB;
  int n = nblk * 16 + c;
  int k0 = kb * 32 + kg * 8;
  u16x8 h8, l8;
#pragma unroll
  for (int j = 0; j < 8; ++j) {
    float v = W[(size_t)(k0 + j) * Nw + n];
    unsigned short h = f2h_bits(v);
    h8[j] = h;
    l8[j] = f2h_bits(v - h_bits2f(h));
  }
  *reinterpret_cast<u16x8*>(hi + (size_t)t * 8) = h8;
  *reinterpret_cast<u16x8*>(lo + (size_t)t * 8) = l8;
}

__global__ void convW_all_kernel(const float* __restrict__ W1, const float* __restrict__ W2,
                                 const float* __restrict__ W3,
                                 unsigned short* __restrict__ hi, unsigned short* __restrict__ lo) {
  int t = blockIdx.x * blockDim.x + threadIdx.x;
  if (t >= WTOT_ITEMS) return;
  if (t < 4096) {
    convW_item(W1, IN_DIM, F1, t, hi + WOFF1, lo + WOFF1);
  } else if (t < 4096 + 8192) {
    convW_item(W2, F1, F1, t - 4096, hi + WOFF2, lo + WOFF2);
  } else {
    convW_item(W3, F1, HIDC, t - (4096 + 8192), hi + WOFF3, lo + WOFF3);
  }
}

// ---------------- fp16 MFMA GEMM (2-product: A*Whi + A*Wlo) + fused att-proj epilogue ----------------
template <int KB, int NB, int H>
__global__ __launch_bounds__(256) void gemm_f16_kernel(
    const unsigned short* __restrict__ At,
    const unsigned short* __restrict__ Bhi, const unsigned short* __restrict__ Blo,
    const float* __restrict__ atts, const float* __restrict__ attd,
    __half* __restrict__ Ch, float* __restrict__ a_s, float* __restrict__ a_d,
    int M, int Nout) {
  __shared__ unsigned short As[8 * 512];
  __shared__ unsigned short BsH[NB * 512], BsL[NB * 512];
  const int tid = threadIdx.x;
  const int w = tid >> 6, lane = tid & 63;
  const size_t machunk = ((size_t)blockIdx.x * 8 + w * 2) * KB;
  const int nblk0 = blockIdx.y * NB;
  const int laneo = lane * 8;

  f32x4 acc[2][NB];
#pragma unroll
  for (int mi = 0; mi < 2; ++mi)
#pragma unroll
    for (int nj = 0; nj < NB; ++nj) acc[mi][nj] = {0.f, 0.f, 0.f, 0.f};

  for (int kb = 0; kb < KB; ++kb) {
    gload_lds16(At + (machunk + kb) * 512 + laneo, As + (w * 2) * 512);
    gload_lds16(At + (machunk + (size_t)KB + kb) * 512 + laneo, As + (w * 2 + 1) * 512);
#pragma unroll
    for (int q = 0; q < NB / 4; ++q) {
      int nbl = w * (NB / 4) + q;
      size_t bo = ((size_t)(nblk0 + nbl) * KB + kb) * 512 + laneo;
      gload_lds16(Bhi + bo, BsH + nbl * 512);
      gload_lds16(Blo + bo, BsL + nbl * 512);
    }
    __syncthreads();
    f16x8 a0 = *reinterpret_cast<const f16x8*>(As + (w * 2) * 512 + laneo);
    f16x8 a1 = *reinterpret_cast<const f16x8*>(As + (w * 2 + 1) * 512 + laneo);
#pragma unroll
    for (int nj = 0; nj < NB; ++nj) {
      f16x8 bh = *reinterpret_cast<const f16x8*>(BsH + nj * 512 + laneo);
      f16x8 bl = *reinterpret_cast<const f16x8*>(BsL + nj * 512 + laneo);
      acc[0][nj] = __builtin_amdgcn_mfma_f32_16x16x32_f16(a0, bh, acc[0][nj], 0, 0, 0);
      acc[1][nj] = __builtin_amdgcn_mfma_f32_16x16x32_f16(a1, bh, acc[1][nj], 0, 0, 0);
      acc[0][nj] = __builtin_amdgcn_mfma_f32_16x16x32_f16(a0, bl, acc[0][nj], 0, 0, 0);
      acc[1][nj] = __builtin_amdgcn_mfma_f32_16x16x32_f16(a1, bl, acc[1][nj], 0, 0, 0);
    }
    __syncthreads();
  }
  // ---- epilogue: fp16 store + fused att dot products ----
  const int col0 = nblk0 * 16 + (lane & 15);
  const int row0 = blockIdx.x * 128 + w * 32 + (lane >> 4) * 4;
  float attsv[NB], attdv[NB];
#pragma unroll
  for (int nj = 0; nj < NB; ++nj) {
    int gcol = nblk0 + nj;
    int hh = gcol >> 2;
    int coff = (gcol & 3) * 16 + (lane & 15);
    attsv[nj] = atts[hh * 64 + coff];
    attdv[nj] = attd[hh * 64 + coff];
  }
#pragma unroll
  for (int mi = 0; mi < 2; ++mi) {
#pragma unroll
    for (int nj = 0; nj < NB; ++nj) {
      int col = col0 + nj * 16;
#pragma unroll
      for (int r = 0; r < 4; ++r) {
        int row = row0 + mi * 16 + r;
        if (row < M) Ch[(size_t)row * Nout + col] = __float2half(acc[mi][nj][r]);
      }
    }
#pragma unroll
    for (int r = 0; r < 4; ++r) {
      int row = row0 + mi * 16 + r;
#pragma unroll
      for (int g = 0; g < NB / 4; ++g) {
        float ps = 0.f, pd = 0.f;
#pragma unroll
        for (int q = 0; q < 4; ++q) {
          float v = acc[mi][g * 4 + q][r];
          ps = fmaf(v, attsv[g * 4 + q], ps);
          pd = fmaf(v, attdv[g * 4 + q], pd);
        }
#pragma unroll
        for (int o = 1; o <= 8; o <<= 1) {
          ps += __shfl_xor(ps, o);
          pd += __shfl_xor(pd, o);
        }
        if ((lane & 15) == 0 && row < M) {
          int hh = (nblk0 + g * 4) >> 2;
          a_s[(size_t)row * H + hh] = ps;
          a_d[(size_t)row * H + hh] = pd;
        }
      }
    }
  }
}

// ---------------- H=4 edge softmax + aggregate; fp16 gather; writes fp16 tiled + ELU ----------------
// (round-4 exact inner-loop addressing: 40 VGPR / 79us / 55% occ measured)
__global__ __launch_bounds__(256) void gat_agg4_kernel(const __half* __restrict__ xlh,
                                                       const float* __restrict__ a_srcv,
                                                       const float* __restrict__ a_dstv,
                                                       const int* __restrict__ csrOff,
                                                       const int* __restrict__ csrSrc,
                                                       const float* __restrict__ bias,
                                                       unsigned short* __restrict__ outT) {
  __shared__ float4 plds[4][64];
  __shared__ int slds[4][64];
  const int w = threadIdx.x >> 6;
  const int lane = threadIdx.x & 63;
  const int d = blockIdx.x * 4 + w;
  if (d >= N_NODES) return;
  const int h = lane >> 4;
  int e0 = csrOff[d], e1 = csrOff[d + 1];
  float4 adv = reinterpret_cast<const float4*>(a_dstv)[d];
  float m[4], ssum[4];
#pragma unroll
  for (int j = 0; j < 4; ++j) { m[j] = -1e30f; ssum[j] = 0.f; }
  float4 acc = make_float4(0.f, 0.f, 0.f, 0.f);
  const float* pbase = reinterpret_cast<const float*>(&plds[w][0]);

  for (int cb = e0; cb < e1; cb += 64) {
    int ecount = min(64, e1 - cb);
    int sidx = (lane < ecount) ? csrSrc[cb + lane] : 0;
    slds[w][lane] = sidx;
    float4 asv = make_float4(0.f, 0.f, 0.f, 0.f);
    if (lane < ecount) asv = reinterpret_cast<const float4*>(a_srcv)[sidx];
    float p[4], scl[4];
#pragma unroll
    for (int j = 0; j < 4; ++j) {
      float av = (j == 0) ? asv.x : (j == 1) ? asv.y : (j == 2) ? asv.z : asv.w;
      float dv = (j == 0) ? adv.x : (j == 1) ? adv.y : (j == 2) ? adv.z : adv.w;
      float al = -1e30f;
      if (lane < ecount) {
        float v = av + dv;
        al = (v > 0.f) ? v : 0.2f * v;
      }
      float cm = al;
#pragma unroll
      for (int o = 32; o > 0; o >>= 1) cm = fmaxf(cm, __shfl_xor(cm, o));
      float nm = fmaxf(m[j], cm);
      float scale = __expf(m[j] - nm); // first chunk: exp(-inf)=0
      p[j] = (lane < ecount) ? __expf(al - nm) : 0.f;
      float ps = p[j];
#pragma unroll
      for (int o = 32; o > 0; o >>= 1) ps += __shfl_xor(ps, o);
      ssum[j] = ssum[j] * scale + ps;
      m[j] = nm;
      scl[j] = scale;
    }
    plds[w][lane] = make_float4(p[0], p[1], p[2], p[3]);
    float sc = (h == 0) ? scl[0] : (h == 1) ? scl[1] : (h == 2) ? scl[2] : scl[3];
    acc.x *= sc; acc.y *= sc; acc.z *= sc; acc.w *= sc;
    for (int i = 0; i < ecount; ++i) {
      int s = slds[w][i];          // broadcast ds_read
      float pv = pbase[i * 4 + h]; // broadcast-within-16 ds_read
      uint2 raw = *reinterpret_cast<const uint2*>(xlh + (size_t)s * 256 + lane * 4); // 512B/row
      float2 f0 = __half22float2(__builtin_bit_cast(__half2, raw.x));
      float2 f1 = __half22float2(__builtin_bit_cast(__half2, raw.y));
      acc.x = fmaf(pv, f0.x, acc.x);
      acc.y = fmaf(pv, f0.y, acc.y);
      acc.z = fmaf(pv, f1.x, acc.z);
      acc.w = fmaf(pv, f1.y, acc.w);
    }
  }
  float sm = (h == 0) ? ssum[0] : (h == 1) ? ssum[1] : (h == 2) ? ssum[2] : ssum[3];
  float inv = 1.f / (sm + 1e-16f);
  float4 bv = reinterpret_cast<const float4*>(bias)[lane];
  float4 r;
  r.x = acc.x * inv + bv.x;
  r.y = acc.y * inv + bv.y;
  r.z = acc.z * inv + bv.z;
  r.w = acc.w * inv + bv.w;
  r.x = (r.x > 0.f) ? r.x : (__expf(r.x) - 1.f);
  r.y = (r.y > 0.f) ? r.y : (__expf(r.y) - 1.f);
  r.z = (r.z > 0.f) ? r.z : (__expf(r.z) - 1.f);
  r.w = (r.w > 0.f) ? r.w : (__expf(r.w) - 1.f);
  // fp16 write in MFMA-tiled layout (col c=4L+i: kb=L>>3, kg=(L>>1)&3, j=(L&1)*4+i)
  ushort4 hh;
  hh.x = f2h_bits(r.x);
  hh.y = f2h_bits(r.y);
  hh.z = f2h_bits(r.z);
  hh.w = f2h_bits(r.w);
  const int mblk = d >> 4, rr = d & 15;
  const int kb = lane >> 3, kg = (lane >> 1) & 3, jj = (lane & 1) * 4;
  size_t base = ((size_t)mblk * 8 + kb) * 512 + (size_t)(kg * 16 + rr) * 8 + jj;
  *reinterpret_cast<ushort4*>(outT + base) = hh;
}

// layer 3 (H=1) + fused b3 + fc (64->2) + fc_b; fp16 gather; 4 edges per iteration
__global__ __launch_bounds__(256) void gat_final_kernel(const __half* __restrict__ xlh,
                                                        const float* __restrict__ a_srcv,
                                                        const float* __restrict__ a_dstv,
                                                        const int* __restrict__ csrOff,
                                                        const int* __restrict__ csrSrc,
                                                        const float* __restrict__ b3,
                                                        const float* __restrict__ fcw,
                                                        const float* __restrict__ fcb,
                                                        float* __restrict__ out) {
  __shared__ float plds[4][64];
  __shared__ int slds[4][64];
  const int w = threadIdx.x >> 6;
  const int lane = threadIdx.x & 63;
  const int d = blockIdx.x * 4 + w;
  if (d >= N_NODES) return;
  const int g = lane >> 4;   // edge subgroup
  const int c4 = lane & 15;  // 4-col group index
  int e0 = csrOff[d], e1 = csrOff[d + 1];
  float adv = a_dstv[d];
  float m = -1e30f, ssum = 0.f;
  float4 acc = make_float4(0.f, 0.f, 0.f, 0.f);

  for (int cb = e0; cb < e1; cb += 64) {
    int ecount = min(64, e1 - cb);
    int sidx = (lane < ecount) ? csrSrc[cb + lane] : 0;
    slds[w][lane] = sidx;
    float al = -1e30f;
    if (lane < ecount) {
      float v = a_srcv[sidx] + adv;
      al = (v > 0.f) ? v : 0.2f * v;
    }
    float cm = al;
#pragma unroll
    for (int o = 32; o > 0; o >>= 1) cm = fmaxf(cm, __shfl_xor(cm, o));
    float nm = fmaxf(m, cm);
    float scale = __expf(m - nm);
    float p = (lane < ecount) ? __expf(al - nm) : 0.f;
    float ps = p;
#pragma unroll
    for (int o = 32; o > 0; o >>= 1) ps += __shfl_xor(ps, o);
    ssum = ssum * scale + ps;
    m = nm;
    plds[w][lane] = p;
    acc.x *= scale; acc.y *= scale; acc.z *= scale; acc.w *= scale;
    for (int i = 0; i < ecount; i += 4) {
      int e = i + g; // <= 63 always; p==0 for e>=ecount
      int s = slds[w][e];
      float pv = plds[w][e];
      uint2 raw = *reinterpret_cast<const uint2*>(xlh + (size_t)s * 64 + c4 * 4); // 128B/row
      float2 f0 = __half22float2(__builtin_bit_cast(__half2, raw.x));
      float2 f1 = __half22float2(__builtin_bit_cast(__half2, raw.y));
      acc.x = fmaf(pv, f0.x, acc.x);
      acc.y = fmaf(pv, f0.y, acc.y);
      acc.z = fmaf(pv, f1.x, acc.z);
      acc.w = fmaf(pv, f1.y, acc.w);
    }
  }
#pragma unroll
  for (int o = 16; o <= 32; o <<= 1) {
    acc.x += __shfl_xor(acc.x, o);
    acc.y += __shfl_xor(acc.y, o);
    acc.z += __shfl_xor(acc.z, o);
    acc.w += __shfl_xor(acc.w, o);
  }
  float inv = 1.f / (ssum + 1e-16f);
  float4 bv = reinterpret_cast<const float4*>(b3)[c4];
  float4 v;
  v.x = acc.x * inv + bv.x;
  v.y = acc.y * inv + bv.y;
  v.z = acc.z * inv + bv.z;
  v.w = acc.w * inv + bv.w;
  const float2* fcw2 = reinterpret_cast<const float2*>(fcw);
  float2 w0 = fcw2[c4 * 4 + 0], w1 = fcw2[c4 * 4 + 1], w2 = fcw2[c4 * 4 + 2], w3 = fcw2[c4 * 4 + 3];
  float l0 = v.x * w0.x + v.y * w1.x + v.z * w2.x + v.w * w3.x;
  float l1 = v.x * w0.y + v.y * w1.y + v.z * w2.y + v.w * w3.y;
#pragma unroll
  for (int o = 1; o <= 8; o <<= 1) {
    l0 += __shfl_xor(l0, o);
    l1 += __shfl_xor(l1, o);
  }
  if (lane == 0) {
    out[2 * d + 0] = l0 + fcb[0];
    out[2 * d + 1] = l1 + fcb[1];
  }
}

extern "C" void kernel_launch(void* const* d_in, const int* in_sizes, int n_in,
                              void* d_out, int out_size, void* d_ws, size_t ws_size,
                              hipStream_t stream) {
  (void)in_sizes; (void)n_in; (void)out_size; (void)ws_size;
  const float* x      = (const float*)d_in[0];
  const void*  eidx   = d_in[1];
  const float* W1     = (const float*)d_in[2];
  const float* att_s1 = (const float*)d_in[3];
  const float* att_d1 = (const float*)d_in[4];
  const float* b1     = (const float*)d_in[5];
  const float* W2     = (const float*)d_in[6];
  const float* att_s2 = (const float*)d_in[7];
  const float* att_d2 = (const float*)d_in[8];
  const float* b2     = (const float*)d_in[9];
  const float* W3     = (const float*)d_in[10];
  const float* att_s3 = (const float*)d_in[11];
  const float* att_d3 = (const float*)d_in[12];
  const float* b3     = (const float*)d_in[13];
  const float* fcw    = (const float*)d_in[14];
  const float* fcb    = (const float*)d_in[15];
  float* out = (float*)d_out;

  char* ws = (char*)d_ws;
  size_t off = 0;
  auto alloc = [&](size_t bytes) -> void* {
    void* p = (void*)(ws + off);
    off += (bytes + 255) & ~(size_t)255;
    return p;
  };
  int*   srcI   = (int*)alloc((size_t)N_EDGES * 4);
  int*   dstI   = (int*)alloc((size_t)N_EDGES * 4);
  int*   cnt    = (int*)alloc((size_t)N_NODES * 4);
  int*   fillc  = (int*)alloc((size_t)N_NODES * 4);
  int*   csrOff = (int*)alloc((size_t)(N_NODES + 1) * 4);
  int*   csrSrc = (int*)alloc((size_t)ETOT * 4);
  int*   flag   = (int*)alloc(256);
  int*   escan  = (int*)alloc((size_t)N_NODES * 4);
  int*   bsum   = (int*)alloc((size_t)SCAN_BLOCKS * 4);
  int*   boff   = (int*)alloc((size_t)SCAN_BLOCKS * 4);
  float* a_s    = (float*)alloc((size_t)N_NODES * HEADS * 4);
  float* a_d    = (float*)alloc((size_t)N_NODES * HEADS * 4);
  unsigned short* At  = (unsigned short*)alloc((size_t)MP * F1 * 2); // tiled fp16 A
  unsigned short* Whi = (unsigned short*)alloc((size_t)(WOFF3 + 16384) * 2);
  unsigned short* Wlo = (unsigned short*)alloc((size_t)(WOFF3 + 16384) * 2);
  __half* xlh  = (__half*)alloc((size_t)MP * F1 * 2);   // fp16 xl (layers 1,2)
  __half* xlh3 = (__half*)alloc((size_t)MP * HIDC * 2); // fp16 xl (layer 3)

  // ---- graph build + all weight conversions up front ----
  detect_init_kernel<<<(N_NODES + 255) / 256, 256, 0, stream>>>((const unsigned int*)eidx, flag, cnt, fillc);
  decode_hist_kernel<<<(N_EDGES + 255) / 256, 256, 0, stream>>>(eidx, flag, srcI, dstI, cnt);
  scan1_kernel<<<SCAN_BLOCKS, 256, 0, stream>>>(cnt, escan, bsum);
  scan2_kernel<<<1, 256, 0, stream>>>(bsum, boff);
  scan3_kernel<<<SCAN_BLOCKS, 256, 0, stream>>>(escan, boff, csrOff);
  fill_kernel<<<(ETOT + 255) / 256, 256, 0, stream>>>(srcI, dstI, csrOff, fillc, csrSrc);
  convW_all_kernel<<<(WTOT_ITEMS + 255) / 256, 256, 0, stream>>>(W1, W2, W3, Whi, Wlo);

  const int gn = (N_NODES + 3) / 4;  // 12500
  const int gmb = MP / 16;           // 3128
  const int gx = MP / 128;           // 391

  // ---- Layer 1: x[N,128] @ W1[128,256] ----
  convA_kernel<IN_DIM><<<gmb, 256, 0, stream>>>(x, At, N_NODES);
  gemm_f16_kernel<4, 8, 4><<<dim3(gx, 2), 256, 0, stream>>>(At, Whi + WOFF1, Wlo + WOFF1,
                                                            att_s1, att_d1, xlh, a_s, a_d, N_NODES, F1);
  gat_agg4_kernel<<<gn, 256, 0, stream>>>(xlh, a_s, a_d, csrOff, csrSrc, b1, At);

  // ---- Layer 2: h1[N,256] @ W2[256,256] (A from agg epilogue, tiled fp16) ----
  gemm_f16_kernel<8, 8, 4><<<dim3(gx, 2), 256, 0, stream>>>(At, Whi + WOFF2, Wlo + WOFF2,
                                                            att_s2, att_d2, xlh, a_s, a_d, N_NODES, F1);
  gat_agg4_kernel<<<gn, 256, 0, stream>>>(xlh, a_s, a_d, csrOff, csrSrc, b2, At);

  // ---- Layer 3: h2[N,256] @ W3[256,64], H=1, fused fc ----
  gemm_f16_kernel<8, 4, 1><<<dim3(gx, 1), 256, 0, stream>>>(At, Whi + WOFF3, Wlo + WOFF3,
                                                            att_s3, att_d3, xlh3, a_s, a_d, N_NODES, HIDC);
  gat_final_kernel<<<gn, 256, 0, stream>>>(xlh3, a_s, a_d, csrOff, csrSrc, b3, fcw, fcb, out);
}

// Round 9
// 340.837 us; speedup vs baseline: 2.3619x; 1.0406x over previous
//
#include <hip/hip_runtime.h>
#include <hip/hip_fp16.h>
#include <math.h>

#define N_NODES 50000
#define N_EDGES 800000
#define ETOT (N_EDGES + N_NODES)
#define IN_DIM 128
#define HIDC 64
#define HEADS 4
#define F1 (HEADS * HIDC) /* 256 */
#define MP 50048 /* N_NODES padded to 128 */
#define SCAN_BLOCKS 196 /* ceil(N_NODES/256) */

// tiled W buffer element offsets (within Whi/Wlo)
#define WOFF1 0
#define WOFF2 32768  /* 128*256 */
#define WOFF3 98304  /* + 256*256 */
#define WTOT_ITEMS 14336 /* 4096 + 8192 + 2048 work items (8 elems each) */
#define CONVW_BLOCKS 56  /* ceil(WTOT_ITEMS/256) */

typedef _Float16 f16x8 __attribute__((ext_vector_type(8)));
typedef float f32x4 __attribute__((ext_vector_type(4)));
typedef unsigned short u16x8 __attribute__((ext_vector_type(8)));

__device__ inline unsigned short f2h_bits(float f) {
  _Float16 h = (_Float16)f;
  return __builtin_bit_cast(unsigned short, h);
}
__device__ inline float h_bits2f(unsigned short b) {
  return (float)__builtin_bit_cast(_Float16, b);
}

__device__ inline void gload_lds16(const void* g, void* l) {
  __builtin_amdgcn_global_load_lds(
      (const __attribute__((address_space(1))) unsigned int*)g,
      (__attribute__((address_space(3))) unsigned int*)l, 16, 0, 0);
}

// all three W matrices -> tiled fp16 hi/lo [Nw/16][K/32][kg=4][c=16][j=8]
__device__ inline void convW_item(const float* __restrict__ W, int K, int Nw, int t,
                                  unsigned short* __restrict__ hi, unsigned short* __restrict__ lo) {
  int KB = K >> 5;
  int c = t & 15;
  int kg = (t >> 4) & 3;
  int kb = (t >> 6) % KB;
  int nblk = (t >> 6) / KB;
  int n = nblk * 16 + c;
  int k0 = kb * 32 + kg * 8;
  u16x8 h8, l8;
#pragma unroll
  for (int j = 0; j < 8; ++j) {
    float v = W[(size_t)(k0 + j) * Nw + n];
    unsigned short h = f2h_bits(v);
    h8[j] = h;
    l8[j] = f2h_bits(v - h_bits2f(h));
  }
  *reinterpret_cast<u16x8*>(hi + (size_t)t * 8) = h8;
  *reinterpret_cast<u16x8*>(lo + (size_t)t * 8) = l8;
}

// ---------------- dtype detect + cnt/fillc init + convW (merged, independent roles) ----------------
__global__ void detect_init_convw_kernel(const unsigned int* __restrict__ buf, int* __restrict__ flag,
                                         int* __restrict__ cnt, int* __restrict__ fillc,
                                         const float* __restrict__ W1, const float* __restrict__ W2,
                                         const float* __restrict__ W3,
                                         unsigned short* __restrict__ hi, unsigned short* __restrict__ lo) {
  if (blockIdx.x < SCAN_BLOCKS) {
    int i = blockIdx.x * 256 + threadIdx.x;
    if (i < N_NODES) { cnt[i] = 1; fillc[i] = 0; } // self-loop pre-counted
    if (blockIdx.x == 0) {
      __shared__ int any;
      if (threadIdx.x == 0) any = 0;
      __syncthreads();
      for (int k = threadIdx.x; k < 2048; k += blockDim.x)
        if (buf[2 * k + 1] != 0u) any = 1;
      __syncthreads();
      if (threadIdx.x == 0) *flag = any; // 1 => int32, 0 => int64
    }
  } else {
    int t = (blockIdx.x - SCAN_BLOCKS) * 256 + threadIdx.x;
    if (t >= WTOT_ITEMS) return;
    if (t < 4096) {
      convW_item(W1, IN_DIM, F1, t, hi + WOFF1, lo + WOFF1);
    } else if (t < 4096 + 8192) {
      convW_item(W2, F1, F1, t - 4096, hi + WOFF2, lo + WOFF2);
    } else {
      convW_item(W3, F1, HIDC, t - (4096 + 8192), hi + WOFF3, lo + WOFF3);
    }
  }
}

// decode + histogram in one pass
__global__ void decode_hist_kernel(const void* __restrict__ eidx, const int* __restrict__ flag,
                                   int* __restrict__ srcO, int* __restrict__ dstO,
                                   int* __restrict__ cnt) {
  int i = blockIdx.x * blockDim.x + threadIdx.x;
  if (i >= N_EDGES) return;
  int s, d;
  if (*flag) {
    const int* b = (const int*)eidx;
    s = b[i]; d = b[N_EDGES + i];
  } else {
    const long long* b = (const long long*)eidx;
    s = (int)b[i]; d = (int)b[N_EDGES + i];
  }
  srcO[i] = s;
  dstO[i] = d;
  atomicAdd(&cnt[d], 1);
}

// ---------------- multi-block exclusive scan (2 kernels) ----------------
__global__ __launch_bounds__(256) void scan1_kernel(const int* __restrict__ cnt,
                                                    int* __restrict__ escan,
                                                    int* __restrict__ bsum) {
  __shared__ int tmp[256];
  const int t = threadIdx.x;
  const int i = blockIdx.x * 256 + t;
  int v = (i < N_NODES) ? cnt[i] : 0;
  tmp[t] = v;
  __syncthreads();
#pragma unroll
  for (int o = 1; o < 256; o <<= 1) {
    int u = (t >= o) ? tmp[t - o] : 0;
    __syncthreads();
    tmp[t] += u;
    __syncthreads();
  }
  if (i < N_NODES) escan[i] = tmp[t] - v; // exclusive within block
  if (t == 255) bsum[blockIdx.x] = tmp[255];
}

// every block redundantly scans the 196 block sums, applies its own offset
__global__ __launch_bounds__(256) void scan23_kernel(const int* __restrict__ escan,
                                                     const int* __restrict__ bsum,
                                                     int* __restrict__ off) {
  __shared__ int tmp[256];
  const int t = threadIdx.x;
  int v = (t < SCAN_BLOCKS) ? bsum[t] : 0;
  tmp[t] = v;
  __syncthreads();
#pragma unroll
  for (int o = 1; o < 256; o <<= 1) {
    int u = (t >= o) ? tmp[t - o] : 0;
    __syncthreads();
    tmp[t] += u;
    __syncthreads();
  }
  int boff = (blockIdx.x == 0) ? 0 : tmp[blockIdx.x - 1];
  const int i = blockIdx.x * 256 + t;
  if (i < N_NODES) off[i] = escan[i] + boff;
  if (i == 0) off[N_NODES] = ETOT; // total is a structural constant
}

__global__ void fill_kernel(const int* __restrict__ src, const int* __restrict__ dst,
                            const int* __restrict__ csrOff, int* __restrict__ fillc,
                            int* __restrict__ csrSrc) {
  int i = blockIdx.x * blockDim.x + threadIdx.x;
  if (i >= ETOT) return;
  int s, d;
  if (i < N_EDGES) { s = src[i]; d = dst[i]; } else { s = i - N_EDGES; d = s; }
  int pos = csrOff[d] + atomicAdd(&fillc[d], 1);
  csrSrc[pos] = s;
}

// ---------------- fp32 -> fp16, MFMA fragment-tiled layout ----------------
// tiled: [MP/16][K/32][kg=4][r=16][j=8]  (each 16x32 fragment = contiguous 512 u16)
template <int K>
__global__ __launch_bounds__(256) void convA_kernel(const float* __restrict__ A,
                                                    unsigned short* __restrict__ At, int M) {
  __shared__ float ld[16][264];
  const int mblk = blockIdx.x;
  const int tid = threadIdx.x;
  const int elems = 16 * K;
#pragma unroll
  for (int e = tid * 4; e < elems; e += 1024) {
    int r = e / K, c = e % K;
    int row = mblk * 16 + r;
    float4 v = make_float4(0.f, 0.f, 0.f, 0.f);
    if (row < M) v = *reinterpret_cast<const float4*>(&A[(size_t)row * K + c]);
    ld[r][c + 0] = v.x; ld[r][c + 1] = v.y; ld[r][c + 2] = v.z; ld[r][c + 3] = v.w;
  }
  __syncthreads();
#pragma unroll
  for (int o = tid * 8; o < elems; o += 2048) {
    int r = (o >> 3) & 15;
    int kg = (o >> 7) & 3;
    int kb = o >> 9;
    int k0 = kb * 32 + kg * 8;
    u16x8 h8;
#pragma unroll
    for (int j = 0; j < 8; ++j) h8[j] = f2h_bits(ld[r][k0 + j]);
    size_t base = ((size_t)mblk * (K >> 5) + kb) * 512 + (size_t)(kg * 16 + r) * 8;
    *reinterpret_cast<u16x8*>(At + base) = h8;
  }
}

// ---------------- fp16 MFMA GEMM (2-product: A*Whi + A*Wlo) + fused att-proj epilogue ----------------
template <int KB, int NB, int H>
__global__ __launch_bounds__(256) void gemm_f16_kernel(
    const unsigned short* __restrict__ At,
    const unsigned short* __restrict__ Bhi, const unsigned short* __restrict__ Blo,
    const float* __restrict__ atts, const float* __restrict__ attd,
    __half* __restrict__ Ch, float* __restrict__ a_s, float* __restrict__ a_d,
    int M, int Nout) {
  __shared__ unsigned short As[8 * 512];
  __shared__ unsigned short BsH[NB * 512], BsL[NB * 512];
  const int tid = threadIdx.x;
  const int w = tid >> 6, lane = tid & 63;
  const size_t machunk = ((size_t)blockIdx.x * 8 + w * 2) * KB;
  const int nblk0 = blockIdx.y * NB;
  const int laneo = lane * 8;

  f32x4 acc[2][NB];
#pragma unroll
  for (int mi = 0; mi < 2; ++mi)
#pragma unroll
    for (int nj = 0; nj < NB; ++nj) acc[mi][nj] = {0.f, 0.f, 0.f, 0.f};

  for (int kb = 0; kb < KB; ++kb) {
    gload_lds16(At + (machunk + kb) * 512 + laneo, As + (w * 2) * 512);
    gload_lds16(At + (machunk + (size_t)KB + kb) * 512 + laneo, As + (w * 2 + 1) * 512);
#pragma unroll
    for (int q = 0; q < NB / 4; ++q) {
      int nbl = w * (NB / 4) + q;
      size_t bo = ((size_t)(nblk0 + nbl) * KB + kb) * 512 + laneo;
      gload_lds16(Bhi + bo, BsH + nbl * 512);
      gload_lds16(Blo + bo, BsL + nbl * 512);
    }
    __syncthreads();
    f16x8 a0 = *reinterpret_cast<const f16x8*>(As + (w * 2) * 512 + laneo);
    f16x8 a1 = *reinterpret_cast<const f16x8*>(As + (w * 2 + 1) * 512 + laneo);
#pragma unroll
    for (int nj = 0; nj < NB; ++nj) {
      f16x8 bh = *reinterpret_cast<const f16x8*>(BsH + nj * 512 + laneo);
      f16x8 bl = *reinterpret_cast<const f16x8*>(BsL + nj * 512 + laneo);
      acc[0][nj] = __builtin_amdgcn_mfma_f32_16x16x32_f16(a0, bh, acc[0][nj], 0, 0, 0);
      acc[1][nj] = __builtin_amdgcn_mfma_f32_16x16x32_f16(a1, bh, acc[1][nj], 0, 0, 0);
      acc[0][nj] = __builtin_amdgcn_mfma_f32_16x16x32_f16(a0, bl, acc[0][nj], 0, 0, 0);
      acc[1][nj] = __builtin_amdgcn_mfma_f32_16x16x32_f16(a1, bl, acc[1][nj], 0, 0, 0);
    }
    __syncthreads();
  }
  // ---- epilogue: fp16 store + fused att dot products ----
  const int col0 = nblk0 * 16 + (lane & 15);
  const int row0 = blockIdx.x * 128 + w * 32 + (lane >> 4) * 4;
  float attsv[NB], attdv[NB];
#pragma unroll
  for (int nj = 0; nj < NB; ++nj) {
    int gcol = nblk0 + nj;
    int hh = gcol >> 2;
    int coff = (gcol & 3) * 16 + (lane & 15);
    attsv[nj] = atts[hh * 64 + coff];
    attdv[nj] = attd[hh * 64 + coff];
  }
#pragma unroll
  for (int mi = 0; mi < 2; ++mi) {
#pragma unroll
    for (int nj = 0; nj < NB; ++nj) {
      int col = col0 + nj * 16;
#pragma unroll
      for (int r = 0; r < 4; ++r) {
        int row = row0 + mi * 16 + r;
        if (row < M) Ch[(size_t)row * Nout + col] = __float2half(acc[mi][nj][r]);
      }
    }
#pragma unroll
    for (int r = 0; r < 4; ++r) {
      int row = row0 + mi * 16 + r;
#pragma unroll
      for (int g = 0; g < NB / 4; ++g) {
        float ps = 0.f, pd = 0.f;
#pragma unroll
        for (int q = 0; q < 4; ++q) {
          float v = acc[mi][g * 4 + q][r];
          ps = fmaf(v, attsv[g * 4 + q], ps);
          pd = fmaf(v, attdv[g * 4 + q], pd);
        }
#pragma unroll
        for (int o = 1; o <= 8; o <<= 1) {
          ps += __shfl_xor(ps, o);
          pd += __shfl_xor(pd, o);
        }
        if ((lane & 15) == 0 && row < M) {
          int hh = (nblk0 + g * 4) >> 2;
          a_s[(size_t)row * H + hh] = ps;
          a_d[(size_t)row * H + hh] = pd;
        }
      }
    }
  }
}

// ---------------- H=4 edge softmax + aggregate; dense edge-x-head softmax (chunk=16) ----------------
// softmax phase: lane = edge*4 + head (all 64 lanes active); gather phase: lane owns cols 4L..4L+3
__global__ __launch_bounds__(256) void gat_agg4_kernel(const __half* __restrict__ xlh,
                                                       const float* __restrict__ a_srcv,
                                                       const float* __restrict__ a_dstv,
                                                       const int* __restrict__ csrOff,
                                                       const int* __restrict__ csrSrc,
                                                       const float* __restrict__ bias,
                                                       unsigned short* __restrict__ outT) {
  __shared__ float plds[4][64];  // [wave][edge*4+head]
  __shared__ int slds[4][16];    // [wave][edge]
  __shared__ float hlds[4][4];   // [wave][head]: chunk scale, then final ssum
  const int w = threadIdx.x >> 6;
  const int lane = threadIdx.x & 63;
  const int d = blockIdx.x * 4 + w;
  if (d >= N_NODES) return;
  const int hG = lane >> 4;  // gather-phase head
  const int hS = lane & 3;   // softmax-phase head
  const int eS = lane >> 2;  // softmax-phase edge slot (0..15)
  int e0 = csrOff[d], e1 = csrOff[d + 1];
  float4 advv = reinterpret_cast<const float4*>(a_dstv)[d];
  float adv = (hS == 0) ? advv.x : (hS == 1) ? advv.y : (hS == 2) ? advv.z : advv.w;
  float m = -1e30f, ssum = 0.f; // running state for head hS (uniform within 16-lane head group)
  float4 acc = make_float4(0.f, 0.f, 0.f, 0.f);
  const float* pbase = &plds[w][0];

  for (int cb = e0; cb < e1; cb += 16) {
    int ecount = min(16, e1 - cb);
    int sidx = (eS < ecount) ? csrSrc[cb + eS] : 0;
    float al = -1e30f;
    if (eS < ecount) {
      float v = a_srcv[sidx * 4 + hS] + adv;
      al = (v > 0.f) ? v : 0.2f * v;
    }
    // reduce over the 16-lane stride-4 group (same head): xor 4,8,16,32
    float cm = al;
#pragma unroll
    for (int o = 4; o <= 32; o <<= 1) cm = fmaxf(cm, __shfl_xor(cm, o));
    float nm = fmaxf(m, cm);
    float scale = __expf(m - nm); // first chunk: exp(-inf)=0
    float p = (eS < ecount) ? __expf(al - nm) : 0.f;
    float ps = p;
#pragma unroll
    for (int o = 4; o <= 32; o <<= 1) ps += __shfl_xor(ps, o);
    ssum = ssum * scale + ps;
    m = nm;
    plds[w][eS * 4 + hS] = p;
    if (eS == 0) hlds[w][hS] = scale;
    if (hS == 0) slds[w][eS] = sidx;
    float sc = hlds[w][hG];
    acc.x *= sc; acc.y *= sc; acc.z *= sc; acc.w *= sc;
    for (int i = 0; i < ecount; ++i) {
      int s = slds[w][i];          // broadcast ds_read
      float pv = pbase[i * 4 + hG]; // broadcast-within-16 ds_read
      uint2 raw = *reinterpret_cast<const uint2*>(xlh + (size_t)s * 256 + lane * 4); // 512B/row
      float2 f0 = __half22float2(__builtin_bit_cast(__half2, raw.x));
      float2 f1 = __half22float2(__builtin_bit_cast(__half2, raw.y));
      acc.x = fmaf(pv, f0.x, acc.x);
      acc.y = fmaf(pv, f0.y, acc.y);
      acc.z = fmaf(pv, f1.x, acc.z);
      acc.w = fmaf(pv, f1.y, acc.w);
    }
  }
  if (eS == 0) hlds[w][hS] = ssum;
  float sm = hlds[w][hG];
  float inv = 1.f / (sm + 1e-16f);
  float4 bv = reinterpret_cast<const float4*>(bias)[lane];
  float4 r;
  r.x = acc.x * inv + bv.x;
  r.y = acc.y * inv + bv.y;
  r.z = acc.z * inv + bv.z;
  r.w = acc.w * inv + bv.w;
  r.x = (r.x > 0.f) ? r.x : (__expf(r.x) - 1.f);
  r.y = (r.y > 0.f) ? r.y : (__expf(r.y) - 1.f);
  r.z = (r.z > 0.f) ? r.z : (__expf(r.z) - 1.f);
  r.w = (r.w > 0.f) ? r.w : (__expf(r.w) - 1.f);
  // fp16 write in MFMA-tiled layout (col c=4L+i: kb=L>>3, kg=(L>>1)&3, j=(L&1)*4+i)
  ushort4 hh;
  hh.x = f2h_bits(r.x);
  hh.y = f2h_bits(r.y);
  hh.z = f2h_bits(r.z);
  hh.w = f2h_bits(r.w);
  const int mblk = d >> 4, rr = d & 15;
  const int kb = lane >> 3, kg = (lane >> 1) & 3, jj = (lane & 1) * 4;
  size_t base = ((size_t)mblk * 8 + kb) * 512 + (size_t)(kg * 16 + rr) * 8 + jj;
  *reinterpret_cast<ushort4*>(outT + base) = hh;
}

// layer 3 (H=1) + fused b3 + fc (64->2) + fc_b; fp16 gather; 4 edges per iteration (unchanged)
__global__ __launch_bounds__(256) void gat_final_kernel(const __half* __restrict__ xlh,
                                                        const float* __restrict__ a_srcv,
                                                        const float* __restrict__ a_dstv,
                                                        const int* __restrict__ csrOff,
                                                        const int* __restrict__ csrSrc,
                                                        const float* __restrict__ b3,
                                                        const float* __restrict__ fcw,
                                                        const float* __restrict__ fcb,
                                                        float* __restrict__ out) {
  __shared__ float plds[4][64];
  __shared__ int slds[4][64];
  const int w = threadIdx.x >> 6;
  const int lane = threadIdx.x & 63;
  const int d = blockIdx.x * 4 + w;
  if (d >= N_NODES) return;
  const int g = lane >> 4;   // edge subgroup
  const int c4 = lane & 15;  // 4-col group index
  int e0 = csrOff[d], e1 = csrOff[d + 1];
  float adv = a_dstv[d];
  float m = -1e30f, ssum = 0.f;
  float4 acc = make_float4(0.f, 0.f, 0.f, 0.f);

  for (int cb = e0; cb < e1; cb += 64) {
    int ecount = min(64, e1 - cb);
    int sidx = (lane < ecount) ? csrSrc[cb + lane] : 0;
    slds[w][lane] = sidx;
    float al = -1e30f;
    if (lane < ecount) {
      float v = a_srcv[sidx] + adv;
      al = (v > 0.f) ? v : 0.2f * v;
    }
    float cm = al;
#pragma unroll
    for (int o = 32; o > 0; o >>= 1) cm = fmaxf(cm, __shfl_xor(cm, o));
    float nm = fmaxf(m, cm);
    float scale = __expf(m - nm);
    float p = (lane < ecount) ? __expf(al - nm) : 0.f;
    float ps = p;
#pragma unroll
    for (int o = 32; o > 0; o >>= 1) ps += __shfl_xor(ps, o);
    ssum = ssum * scale + ps;
    m = nm;
    plds[w][lane] = p;
    acc.x *= scale; acc.y *= scale; acc.z *= scale; acc.w *= scale;
    for (int i = 0; i < ecount; i += 4) {
      int e = i + g; // <= 63 always; p==0 for e>=ecount
      int s = slds[w][e];
      float pv = plds[w][e];
      uint2 raw = *reinterpret_cast<const uint2*>(xlh + (size_t)s * 64 + c4 * 4); // 128B/row
      float2 f0 = __half22float2(__builtin_bit_cast(__half2, raw.x));
      float2 f1 = __half22float2(__builtin_bit_cast(__half2, raw.y));
      acc.x = fmaf(pv, f0.x, acc.x);
      acc.y = fmaf(pv, f0.y, acc.y);
      acc.z = fmaf(pv, f1.x, acc.z);
      acc.w = fmaf(pv, f1.y, acc.w);
    }
  }
#pragma unroll
  for (int o = 16; o <= 32; o <<= 1) {
    acc.x += __shfl_xor(acc.x, o);
    acc.y += __shfl_xor(acc.y, o);
    acc.z += __shfl_xor(acc.z, o);
    acc.w += __shfl_xor(acc.w, o);
  }
  float inv = 1.f / (ssum + 1e-16f);
  float4 bv = reinterpret_cast<const float4*>(b3)[c4];
  float4 v;
  v.x = acc.x * inv + bv.x;
  v.y = acc.y * inv + bv.y;
  v.z = acc.z * inv + bv.z;
  v.w = acc.w * inv + bv.w;
  const float2* fcw2 = reinterpret_cast<const float2*>(fcw);
  float2 w0 = fcw2[c4 * 4 + 0], w1 = fcw2[c4 * 4 + 1], w2 = fcw2[c4 * 4 + 2], w3 = fcw2[c4 * 4 + 3];
  float l0 = v.x * w0.x + v.y * w1.x + v.z * w2.x + v.w * w3.x;
  float l1 = v.x * w0.y + v.y * w1.y + v.z * w2.y + v.w * w3.y;
#pragma unroll
  for (int o = 1; o <= 8; o <<= 1) {
    l0 += __shfl_xor(l0, o);
    l1 += __shfl_xor(l1, o);
  }
  if (lane == 0) {
    out[2 * d + 0] = l0 + fcb[0];
    out[2 * d + 1] = l1 + fcb[1];
  }
}

extern "C" void kernel_launch(void* const* d_in, const int* in_sizes, int n_in,
                              void* d_out, int out_size, void* d_ws, size_t ws_size,
                              hipStream_t stream) {
  (void)in_sizes; (void)n_in; (void)out_size; (void)ws_size;
  const float* x      = (const float*)d_in[0];
  const void*  eidx   = d_in[1];
  const float* W1     = (const float*)d_in[2];
  const float* att_s1 = (const float*)d_in[3];
  const float* att_d1 = (const float*)d_in[4];
  const float* b1     = (const float*)d_in[5];
  const float* W2     = (const float*)d_in[6];
  const float* att_s2 = (const float*)d_in[7];
  const float* att_d2 = (const float*)d_in[8];
  const float* b2     = (const float*)d_in[9];
  const float* W3     = (const float*)d_in[10];
  const float* att_s3 = (const float*)d_in[11];
  const float* att_d3 = (const float*)d_in[12];
  const float* b3     = (const float*)d_in[13];
  const float* fcw    = (const float*)d_in[14];
  const float* fcb    = (const float*)d_in[15];
  float* out = (float*)d_out;

  char* ws = (char*)d_ws;
  size_t off = 0;
  auto alloc = [&](size_t bytes) -> void* {
    void* p = (void*)(ws + off);
    off += (bytes + 255) & ~(size_t)255;
    return p;
  };
  int*   srcI   = (int*)alloc((size_t)N_EDGES * 4);
  int*   dstI   = (int*)alloc((size_t)N_EDGES * 4);
  int*   cnt    = (int*)alloc((size_t)N_NODES * 4);
  int*   fillc  = (int*)alloc((size_t)N_NODES * 4);
  int*   csrOff = (int*)alloc((size_t)(N_NODES + 1) * 4);
  int*   csrSrc = (int*)alloc((size_t)ETOT * 4);
  int*   flag   = (int*)alloc(256);
  int*   escan  = (int*)alloc((size_t)N_NODES * 4);
  int*   bsum   = (int*)alloc((size_t)SCAN_BLOCKS * 4);
  float* a_s    = (float*)alloc((size_t)N_NODES * HEADS * 4);
  float* a_d    = (float*)alloc((size_t)N_NODES * HEADS * 4);
  unsigned short* At  = (unsigned short*)alloc((size_t)MP * F1 * 2); // tiled fp16 A
  unsigned short* Whi = (unsigned short*)alloc((size_t)(WOFF3 + 16384) * 2);
  unsigned short* Wlo = (unsigned short*)alloc((size_t)(WOFF3 + 16384) * 2);
  __half* xlh  = (__half*)alloc((size_t)MP * F1 * 2);   // fp16 xl (layers 1,2)
  __half* xlh3 = (__half*)alloc((size_t)MP * HIDC * 2); // fp16 xl (layer 3)

  // ---- graph build + all weight conversions up front ----
  detect_init_convw_kernel<<<SCAN_BLOCKS + CONVW_BLOCKS, 256, 0, stream>>>(
      (const unsigned int*)eidx, flag, cnt, fillc, W1, W2, W3, Whi, Wlo);
  decode_hist_kernel<<<(N_EDGES + 255) / 256, 256, 0, stream>>>(eidx, flag, srcI, dstI, cnt);
  scan1_kernel<<<SCAN_BLOCKS, 256, 0, stream>>>(cnt, escan, bsum);
  scan23_kernel<<<SCAN_BLOCKS, 256, 0, stream>>>(escan, bsum, csrOff);
  fill_kernel<<<(ETOT + 255) / 256, 256, 0, stream>>>(srcI, dstI, csrOff, fillc, csrSrc);

  const int gn = (N_NODES + 3) / 4;  // 12500
  const int gmb = MP / 16;           // 3128
  const int gx = MP / 128;           // 391

  // ---- Layer 1: x[N,128] @ W1[128,256] ----
  convA_kernel<IN_DIM><<<gmb, 256, 0, stream>>>(x, At, N_NODES);
  gemm_f16_kernel<4, 8, 4><<<dim3(gx, 2), 256, 0, stream>>>(At, Whi + WOFF1, Wlo + WOFF1,
                                                            att_s1, att_d1, xlh, a_s, a_d, N_NODES, F1);
  gat_agg4_kernel<<<gn, 256, 0, stream>>>(xlh, a_s, a_d, csrOff, csrSrc, b1, At);

  // ---- Layer 2: h1[N,256] @ W2[256,256] (A from agg epilogue, tiled fp16) ----
  gemm_f16_kernel<8, 8, 4><<<dim3(gx, 2), 256, 0, stream>>>(At, Whi + WOFF2, Wlo + WOFF2,
                                                            att_s2, att_d2, xlh, a_s, a_d, N_NODES, F1);
  gat_agg4_kernel<<<gn, 256, 0, stream>>>(xlh, a_s, a_d, csrOff, csrSrc, b2, At);

  // ---- Layer 3: h2[N,256] @ W3[256,64], H=1, fused fc ----
  gemm_f16_kernel<8, 4, 1><<<dim3(gx, 1), 256, 0, stream>>>(At, Whi + WOFF3, Wlo + WOFF3,
                                                            att_s3, att_d3, xlh3, a_s, a_d, N_NODES, HIDC);
  gat_final_kernel<<<gn, 256, 0, stream>>>(xlh3, a_s, a_d, csrOff, csrSrc, b3, fcw, fcb, out);
}

// Round 10
// 335.959 us; speedup vs baseline: 2.3962x; 1.0145x over previous
//
#include <hip/hip_runtime.h>
#include <hip/hip_fp16.h>
#include <math.h>

#define N_NODES 50000
#define N_EDGES 800000
#define ETOT (N_EDGES + N_NODES)
#define IN_DIM 128
#define HIDC 64
#define HEADS 4
#define F1 (HEADS * HIDC) /* 256 */
#define MP 50048 /* N_NODES padded to 128 */
#define SCAN_BLOCKS 196 /* ceil(N_NODES/256) */

// tiled W buffer element offsets (within Wt)
#define WOFF1 0
#define WOFF2 32768  /* 128*256 */
#define WOFF3 98304  /* + 256*256 */
#define WTOT_ITEMS 14336 /* 4096 + 8192 + 2048 work items (8 elems each) */
#define CONVW_BLOCKS 56  /* ceil(WTOT_ITEMS/256) */

typedef _Float16 f16x8 __attribute__((ext_vector_type(8)));
typedef float f32x4 __attribute__((ext_vector_type(4)));
typedef unsigned short u16x8 __attribute__((ext_vector_type(8)));

__device__ inline unsigned short f2h_bits(float f) {
  _Float16 h = (_Float16)f;
  return __builtin_bit_cast(unsigned short, h);
}

__device__ inline void gload_lds16(const void* g, void* l) {
  __builtin_amdgcn_global_load_lds(
      (const __attribute__((address_space(1))) unsigned int*)g,
      (__attribute__((address_space(3))) unsigned int*)l, 16, 0, 0);
}

// one W matrix tile item -> fp16 tiled [Nw/16][K/32][kg=4][c=16][j=8]
__device__ inline void convW_item(const float* __restrict__ W, int K, int Nw, int t,
                                  unsigned short* __restrict__ wt) {
  int KB = K >> 5;
  int c = t & 15;
  int kg = (t >> 4) & 3;
  int kb = (t >> 6) % KB;
  int nblk = (t >> 6) / KB;
  int n = nblk * 16 + c;
  int k0 = kb * 32 + kg * 8;
  u16x8 h8;
#pragma unroll
  for (int j = 0; j < 8; ++j) h8[j] = f2h_bits(W[(size_t)(k0 + j) * Nw + n]);
  *reinterpret_cast<u16x8*>(wt + (size_t)t * 8) = h8;
}

// ---------------- dtype detect + cnt/fillc init + convW (merged, independent roles) ----------------
__global__ void detect_init_convw_kernel(const unsigned int* __restrict__ buf, int* __restrict__ flag,
                                         int* __restrict__ cnt, int* __restrict__ fillc,
                                         const float* __restrict__ W1, const float* __restrict__ W2,
                                         const float* __restrict__ W3,
                                         unsigned short* __restrict__ wt) {
  if (blockIdx.x < SCAN_BLOCKS) {
    int i = blockIdx.x * 256 + threadIdx.x;
    if (i < N_NODES) { cnt[i] = 1; fillc[i] = 0; } // self-loop pre-counted
    if (blockIdx.x == 0) {
      __shared__ int any;
      if (threadIdx.x == 0) any = 0;
      __syncthreads();
      for (int k = threadIdx.x; k < 2048; k += blockDim.x)
        if (buf[2 * k + 1] != 0u) any = 1;
      __syncthreads();
      if (threadIdx.x == 0) *flag = any; // 1 => int32, 0 => int64
    }
  } else {
    int t = (blockIdx.x - SCAN_BLOCKS) * 256 + threadIdx.x;
    if (t >= WTOT_ITEMS) return;
    if (t < 4096) {
      convW_item(W1, IN_DIM, F1, t, wt + WOFF1);
    } else if (t < 4096 + 8192) {
      convW_item(W2, F1, F1, t - 4096, wt + WOFF2);
    } else {
      convW_item(W3, F1, HIDC, t - (4096 + 8192), wt + WOFF3);
    }
  }
}

// histogram only (reads dst half of edge_index directly)
__global__ void hist_kernel(const void* __restrict__ eidx, const int* __restrict__ flag,
                            int* __restrict__ cnt) {
  int i = blockIdx.x * blockDim.x + threadIdx.x;
  if (i >= N_EDGES) return;
  int d;
  if (*flag) {
    d = ((const int*)eidx)[N_EDGES + i];
  } else {
    d = (int)((const long long*)eidx)[N_EDGES + i];
  }
  atomicAdd(&cnt[d], 1);
}

// ---------------- multi-block exclusive scan (2 kernels) ----------------
__global__ __launch_bounds__(256) void scan1_kernel(const int* __restrict__ cnt,
                                                    int* __restrict__ escan,
                                                    int* __restrict__ bsum) {
  __shared__ int tmp[256];
  const int t = threadIdx.x;
  const int i = blockIdx.x * 256 + t;
  int v = (i < N_NODES) ? cnt[i] : 0;
  tmp[t] = v;
  __syncthreads();
#pragma unroll
  for (int o = 1; o < 256; o <<= 1) {
    int u = (t >= o) ? tmp[t - o] : 0;
    __syncthreads();
    tmp[t] += u;
    __syncthreads();
  }
  if (i < N_NODES) escan[i] = tmp[t] - v; // exclusive within block
  if (t == 255) bsum[blockIdx.x] = tmp[255];
}

// every block redundantly scans the 196 block sums, applies its own offset
__global__ __launch_bounds__(256) void scan23_kernel(const int* __restrict__ escan,
                                                     const int* __restrict__ bsum,
                                                     int* __restrict__ off) {
  __shared__ int tmp[256];
  const int t = threadIdx.x;
  int v = (t < SCAN_BLOCKS) ? bsum[t] : 0;
  tmp[t] = v;
  __syncthreads();
#pragma unroll
  for (int o = 1; o < 256; o <<= 1) {
    int u = (t >= o) ? tmp[t - o] : 0;
    __syncthreads();
    tmp[t] += u;
    __syncthreads();
  }
  int boff = (blockIdx.x == 0) ? 0 : tmp[blockIdx.x - 1];
  const int i = blockIdx.x * 256 + t;
  if (i < N_NODES) off[i] = escan[i] + boff;
  if (i == 0) off[N_NODES] = ETOT; // total is a structural constant
}

// fill: re-decode edge_index inline (no materialized src/dst arrays)
__global__ void fill_kernel(const void* __restrict__ eidx, const int* __restrict__ flag,
                            const int* __restrict__ csrOff, int* __restrict__ fillc,
                            int* __restrict__ csrSrc) {
  int i = blockIdx.x * blockDim.x + threadIdx.x;
  if (i >= ETOT) return;
  int s, d;
  if (i < N_EDGES) {
    if (*flag) {
      const int* b = (const int*)eidx;
      s = b[i]; d = b[N_EDGES + i];
    } else {
      const long long* b = (const long long*)eidx;
      s = (int)b[i]; d = (int)b[N_EDGES + i];
    }
  } else {
    s = i - N_EDGES; d = s;
  }
  int pos = csrOff[d] + atomicAdd(&fillc[d], 1);
  csrSrc[pos] = s;
}

// ---------------- fp32 -> fp16, MFMA fragment-tiled layout ----------------
// tiled: [MP/16][K/32][kg=4][r=16][j=8]  (each 16x32 fragment = contiguous 512 u16)
template <int K>
__global__ __launch_bounds__(256) void convA_kernel(const float* __restrict__ A,
                                                    unsigned short* __restrict__ At, int M) {
  __shared__ float ld[16][264];
  const int mblk = blockIdx.x;
  const int tid = threadIdx.x;
  const int elems = 16 * K;
#pragma unroll
  for (int e = tid * 4; e < elems; e += 1024) {
    int r = e / K, c = e % K;
    int row = mblk * 16 + r;
    float4 v = make_float4(0.f, 0.f, 0.f, 0.f);
    if (row < M) v = *reinterpret_cast<const float4*>(&A[(size_t)row * K + c]);
    ld[r][c + 0] = v.x; ld[r][c + 1] = v.y; ld[r][c + 2] = v.z; ld[r][c + 3] = v.w;
  }
  __syncthreads();
#pragma unroll
  for (int o = tid * 8; o < elems; o += 2048) {
    int r = (o >> 3) & 15;
    int kg = (o >> 7) & 3;
    int kb = o >> 9;
    int k0 = kb * 32 + kg * 8;
    u16x8 h8;
#pragma unroll
    for (int j = 0; j < 8; ++j) h8[j] = f2h_bits(ld[r][k0 + j]);
    size_t base = ((size_t)mblk * (K >> 5) + kb) * 512 + (size_t)(kg * 16 + r) * 8;
    *reinterpret_cast<u16x8*>(At + base) = h8;
  }
}

// ---------------- fp16 MFMA GEMM (single product: A*Wt) + fused att-proj epilogue ----------------
template <int KB, int NB, int H>
__global__ __launch_bounds__(256) void gemm_f16_kernel(
    const unsigned short* __restrict__ At, const unsigned short* __restrict__ Bt,
    const float* __restrict__ atts, const float* __restrict__ attd,
    __half* __restrict__ Ch, float* __restrict__ a_s, float* __restrict__ a_d,
    int M, int Nout) {
  __shared__ unsigned short As[8 * 512];
  __shared__ unsigned short Bs[NB * 512];
  const int tid = threadIdx.x;
  const int w = tid >> 6, lane = tid & 63;
  const size_t machunk = ((size_t)blockIdx.x * 8 + w * 2) * KB;
  const int nblk0 = blockIdx.y * NB;
  const int laneo = lane * 8;

  f32x4 acc[2][NB];
#pragma unroll
  for (int mi = 0; mi < 2; ++mi)
#pragma unroll
    for (int nj = 0; nj < NB; ++nj) acc[mi][nj] = {0.f, 0.f, 0.f, 0.f};

  for (int kb = 0; kb < KB; ++kb) {
    gload_lds16(At + (machunk + kb) * 512 + laneo, As + (w * 2) * 512);
    gload_lds16(At + (machunk + (size_t)KB + kb) * 512 + laneo, As + (w * 2 + 1) * 512);
#pragma unroll
    for (int q = 0; q < NB / 4; ++q) {
      int nbl = w * (NB / 4) + q;
      gload_lds16(Bt + ((size_t)(nblk0 + nbl) * KB + kb) * 512 + laneo, Bs + nbl * 512);
    }
    __syncthreads();
    f16x8 a0 = *reinterpret_cast<const f16x8*>(As + (w * 2) * 512 + laneo);
    f16x8 a1 = *reinterpret_cast<const f16x8*>(As + (w * 2 + 1) * 512 + laneo);
#pragma unroll
    for (int nj = 0; nj < NB; ++nj) {
      f16x8 b = *reinterpret_cast<const f16x8*>(Bs + nj * 512 + laneo);
      acc[0][nj] = __builtin_amdgcn_mfma_f32_16x16x32_f16(a0, b, acc[0][nj], 0, 0, 0);
      acc[1][nj] = __builtin_amdgcn_mfma_f32_16x16x32_f16(a1, b, acc[1][nj], 0, 0, 0);
    }
    __syncthreads();
  }
  // ---- epilogue: fp16 store + fused att dot products ----
  const int col0 = nblk0 * 16 + (lane & 15);
  const int row0 = blockIdx.x * 128 + w * 32 + (lane >> 4) * 4;
  float attsv[NB], attdv[NB];
#pragma unroll
  for (int nj = 0; nj < NB; ++nj) {
    int gcol = nblk0 + nj;
    int hh = gcol >> 2;
    int coff = (gcol & 3) * 16 + (lane & 15);
    attsv[nj] = atts[hh * 64 + coff];
    attdv[nj] = attd[hh * 64 + coff];
  }
#pragma unroll
  for (int mi = 0; mi < 2; ++mi) {
#pragma unroll
    for (int nj = 0; nj < NB; ++nj) {
      int col = col0 + nj * 16;
#pragma unroll
      for (int r = 0; r < 4; ++r) {
        int row = row0 + mi * 16 + r;
        if (row < M) Ch[(size_t)row * Nout + col] = __float2half(acc[mi][nj][r]);
      }
    }
#pragma unroll
    for (int r = 0; r < 4; ++r) {
      int row = row0 + mi * 16 + r;
#pragma unroll
      for (int g = 0; g < NB / 4; ++g) {
        float ps = 0.f, pd = 0.f;
#pragma unroll
        for (int q = 0; q < 4; ++q) {
          float v = acc[mi][g * 4 + q][r];
          ps = fmaf(v, attsv[g * 4 + q], ps);
          pd = fmaf(v, attdv[g * 4 + q], pd);
        }
#pragma unroll
        for (int o = 1; o <= 8; o <<= 1) {
          ps += __shfl_xor(ps, o);
          pd += __shfl_xor(pd, o);
        }
        if ((lane & 15) == 0 && row < M) {
          int hh = (nblk0 + g * 4) >> 2;
          a_s[(size_t)row * H + hh] = ps;
          a_d[(size_t)row * H + hh] = pd;
        }
      }
    }
  }
}

// ---------------- H=4 edge softmax + aggregate; dense edge-x-head softmax (chunk=16) ----------------
// softmax phase: lane = edge*4 + head (all 64 lanes active); gather phase: lane owns cols 4L..4L+3
__global__ __launch_bounds__(256) void gat_agg4_kernel(const __half* __restrict__ xlh,
                                                       const float* __restrict__ a_srcv,
                                                       const float* __restrict__ a_dstv,
                                                       const int* __restrict__ csrOff,
                                                       const int* __restrict__ csrSrc,
                                                       const float* __restrict__ bias,
                                                       unsigned short* __restrict__ outT) {
  __shared__ float plds[4][64];  // [wave][edge*4+head]
  __shared__ int slds[4][16];    // [wave][edge]
  __shared__ float hlds[4][4];   // [wave][head]: chunk scale, then final ssum
  const int w = threadIdx.x >> 6;
  const int lane = threadIdx.x & 63;
  const int d = blockIdx.x * 4 + w;
  if (d >= N_NODES) return;
  const int hG = lane >> 4;  // gather-phase head
  const int hS = lane & 3;   // softmax-phase head
  const int eS = lane >> 2;  // softmax-phase edge slot (0..15)
  int e0 = csrOff[d], e1 = csrOff[d + 1];
  float4 advv = reinterpret_cast<const float4*>(a_dstv)[d];
  float adv = (hS == 0) ? advv.x : (hS == 1) ? advv.y : (hS == 2) ? advv.z : advv.w;
  float m = -1e30f, ssum = 0.f; // running state for head hS (uniform within 16-lane head group)
  float4 acc = make_float4(0.f, 0.f, 0.f, 0.f);
  const float* pbase = &plds[w][0];

  for (int cb = e0; cb < e1; cb += 16) {
    int ecount = min(16, e1 - cb);
    int sidx = (eS < ecount) ? csrSrc[cb + eS] : 0;
    float al = -1e30f;
    if (eS < ecount) {
      float v = a_srcv[sidx * 4 + hS] + adv;
      al = (v > 0.f) ? v : 0.2f * v;
    }
    // reduce over the 16-lane stride-4 group (same head): xor 4,8,16,32
    float cm = al;
#pragma unroll
    for (int o = 4; o <= 32; o <<= 1) cm = fmaxf(cm, __shfl_xor(cm, o));
    float nm = fmaxf(m, cm);
    float scale = __expf(m - nm); // first chunk: exp(-inf)=0
    float p = (eS < ecount) ? __expf(al - nm) : 0.f;
    float ps = p;
#pragma unroll
    for (int o = 4; o <= 32; o <<= 1) ps += __shfl_xor(ps, o);
    ssum = ssum * scale + ps;
    m = nm;
    plds[w][eS * 4 + hS] = p;
    if (eS == 0) hlds[w][hS] = scale;
    if (hS == 0) slds[w][eS] = sidx;
    float sc = hlds[w][hG];
    acc.x *= sc; acc.y *= sc; acc.z *= sc; acc.w *= sc;
    for (int i = 0; i < ecount; ++i) {
      int s = slds[w][i];           // broadcast ds_read
      float pv = pbase[i * 4 + hG]; // broadcast-within-16 ds_read
      uint2 raw = *reinterpret_cast<const uint2*>(xlh + (size_t)s * 256 + lane * 4); // 512B/row
      float2 f0 = __half22float2(__builtin_bit_cast(__half2, raw.x));
      float2 f1 = __half22float2(__builtin_bit_cast(__half2, raw.y));
      acc.x = fmaf(pv, f0.x, acc.x);
      acc.y = fmaf(pv, f0.y, acc.y);
      acc.z = fmaf(pv, f1.x, acc.z);
      acc.w = fmaf(pv, f1.y, acc.w);
    }
  }
  if (eS == 0) hlds[w][hS] = ssum;
  float sm = hlds[w][hG];
  float inv = 1.f / (sm + 1e-16f);
  float4 bv = reinterpret_cast<const float4*>(bias)[lane];
  float4 r;
  r.x = acc.x * inv + bv.x;
  r.y = acc.y * inv + bv.y;
  r.z = acc.z * inv + bv.z;
  r.w = acc.w * inv + bv.w;
  r.x = (r.x > 0.f) ? r.x : (__expf(r.x) - 1.f);
  r.y = (r.y > 0.f) ? r.y : (__expf(r.y) - 1.f);
  r.z = (r.z > 0.f) ? r.z : (__expf(r.z) - 1.f);
  r.w = (r.w > 0.f) ? r.w : (__expf(r.w) - 1.f);
  // fp16 write in MFMA-tiled layout (col c=4L+i: kb=L>>3, kg=(L>>1)&3, j=(L&1)*4+i)
  ushort4 hh;
  hh.x = f2h_bits(r.x);
  hh.y = f2h_bits(r.y);
  hh.z = f2h_bits(r.z);
  hh.w = f2h_bits(r.w);
  const int mblk = d >> 4, rr = d & 15;
  const int kb = lane >> 3, kg = (lane >> 1) & 3, jj = (lane & 1) * 4;
  size_t base = ((size_t)mblk * 8 + kb) * 512 + (size_t)(kg * 16 + rr) * 8 + jj;
  *reinterpret_cast<ushort4*>(outT + base) = hh;
}

// layer 3 (H=1) + fused b3 + fc (64->2) + fc_b; fp16 gather; 4 edges per iteration (unchanged)
__global__ __launch_bounds__(256) void gat_final_kernel(const __half* __restrict__ xlh,
                                                        const float* __restrict__ a_srcv,
                                                        const float* __restrict__ a_dstv,
                                                        const int* __restrict__ csrOff,
                                                        const int* __restrict__ csrSrc,
                                                        const float* __restrict__ b3,
                                                        const float* __restrict__ fcw,
                                                        const float* __restrict__ fcb,
                                                        float* __restrict__ out) {
  __shared__ float plds[4][64];
  __shared__ int slds[4][64];
  const int w = threadIdx.x >> 6;
  const int lane = threadIdx.x & 63;
  const int d = blockIdx.x * 4 + w;
  if (d >= N_NODES) return;
  const int g = lane >> 4;   // edge subgroup
  const int c4 = lane & 15;  // 4-col group index
  int e0 = csrOff[d], e1 = csrOff[d + 1];
  float adv = a_dstv[d];
  float m = -1e30f, ssum = 0.f;
  float4 acc = make_float4(0.f, 0.f, 0.f, 0.f);

  for (int cb = e0; cb < e1; cb += 64) {
    int ecount = min(64, e1 - cb);
    int sidx = (lane < ecount) ? csrSrc[cb + lane] : 0;
    slds[w][lane] = sidx;
    float al = -1e30f;
    if (lane < ecount) {
      float v = a_srcv[sidx] + adv;
      al = (v > 0.f) ? v : 0.2f * v;
    }
    float cm = al;
#pragma unroll
    for (int o = 32; o > 0; o >>= 1) cm = fmaxf(cm, __shfl_xor(cm, o));
    float nm = fmaxf(m, cm);
    float scale = __expf(m - nm);
    float p = (lane < ecount) ? __expf(al - nm) : 0.f;
    float ps = p;
#pragma unroll
    for (int o = 32; o > 0; o >>= 1) ps += __shfl_xor(ps, o);
    ssum = ssum * scale + ps;
    m = nm;
    plds[w][lane] = p;
    acc.x *= scale; acc.y *= scale; acc.z *= scale; acc.w *= scale;
    for (int i = 0; i < ecount; i += 4) {
      int e = i + g; // <= 63 always; p==0 for e>=ecount
      int s = slds[w][e];
      float pv = plds[w][e];
      uint2 raw = *reinterpret_cast<const uint2*>(xlh + (size_t)s * 64 + c4 * 4); // 128B/row
      float2 f0 = __half22float2(__builtin_bit_cast(__half2, raw.x));
      float2 f1 = __half22float2(__builtin_bit_cast(__half2, raw.y));
      acc.x = fmaf(pv, f0.x, acc.x);
      acc.y = fmaf(pv, f0.y, acc.y);
      acc.z = fmaf(pv, f1.x, acc.z);
      acc.w = fmaf(pv, f1.y, acc.w);
    }
  }
#pragma unroll
  for (int o = 16; o <= 32; o <<= 1) {
    acc.x += __shfl_xor(acc.x, o);
    acc.y += __shfl_xor(acc.y, o);
    acc.z += __shfl_xor(acc.z, o);
    acc.w += __shfl_xor(acc.w, o);
  }
  float inv = 1.f / (ssum + 1e-16f);
  float4 bv = reinterpret_cast<const float4*>(b3)[c4];
  float4 v;
  v.x = acc.x * inv + bv.x;
  v.y = acc.y * inv + bv.y;
  v.z = acc.z * inv + bv.z;
  v.w = acc.w * inv + bv.w;
  const float2* fcw2 = reinterpret_cast<const float2*>(fcw);
  float2 w0 = fcw2[c4 * 4 + 0], w1 = fcw2[c4 * 4 + 1], w2 = fcw2[c4 * 4 + 2], w3 = fcw2[c4 * 4 + 3];
  float l0 = v.x * w0.x + v.y * w1.x + v.z * w2.x + v.w * w3.x;
  float l1 = v.x * w0.y + v.y * w1.y + v.z * w2.y + v.w * w3.y;
#pragma unroll
  for (int o = 1; o <= 8; o <<= 1) {
    l0 += __shfl_xor(l0, o);
    l1 += __shfl_xor(l1, o);
  }
  if (lane == 0) {
    out[2 * d + 0] = l0 + fcb[0];
    out[2 * d + 1] = l1 + fcb[1];
  }
}

extern "C" void kernel_launch(void* const* d_in, const int* in_sizes, int n_in,
                              void* d_out, int out_size, void* d_ws, size_t ws_size,
                              hipStream_t stream) {
  (void)in_sizes; (void)n_in; (void)out_size; (void)ws_size;
  const float* x      = (const float*)d_in[0];
  const void*  eidx   = d_in[1];
  const float* W1     = (const float*)d_in[2];
  const float* att_s1 = (const float*)d_in[3];
  const float* att_d1 = (const float*)d_in[4];
  const float* b1     = (const float*)d_in[5];
  const float* W2     = (const float*)d_in[6];
  const float* att_s2 = (const float*)d_in[7];
  const float* att_d2 = (const float*)d_in[8];
  const float* b2     = (const float*)d_in[9];
  const float* W3     = (const float*)d_in[10];
  const float* att_s3 = (const float*)d_in[11];
  const float* att_d3 = (const float*)d_in[12];
  const float* b3     = (const float*)d_in[13];
  const float* fcw    = (const float*)d_in[14];
  const float* fcb    = (const float*)d_in[15];
  float* out = (float*)d_out;

  char* ws = (char*)d_ws;
  size_t off = 0;
  auto alloc = [&](size_t bytes) -> void* {
    void* p = (void*)(ws + off);
    off += (bytes + 255) & ~(size_t)255;
    return p;
  };
  int*   cnt    = (int*)alloc((size_t)N_NODES * 4);
  int*   fillc  = (int*)alloc((size_t)N_NODES * 4);
  int*   csrOff = (int*)alloc((size_t)(N_NODES + 1) * 4);
  int*   csrSrc = (int*)alloc((size_t)ETOT * 4);
  int*   flag   = (int*)alloc(256);
  int*   escan  = (int*)alloc((size_t)N_NODES * 4);
  int*   bsum   = (int*)alloc((size_t)SCAN_BLOCKS * 4);
  float* a_s    = (float*)alloc((size_t)N_NODES * HEADS * 4);
  float* a_d    = (float*)alloc((size_t)N_NODES * HEADS * 4);
  unsigned short* At = (unsigned short*)alloc((size_t)MP * F1 * 2); // tiled fp16 A
  unsigned short* Wt = (unsigned short*)alloc((size_t)(WOFF3 + 16384) * 2);
  __half* xlh  = (__half*)alloc((size_t)MP * F1 * 2);   // fp16 xl (layers 1,2)
  __half* xlh3 = (__half*)alloc((size_t)MP * HIDC * 2); // fp16 xl (layer 3)

  // ---- graph build + all weight conversions up front ----
  detect_init_convw_kernel<<<SCAN_BLOCKS + CONVW_BLOCKS, 256, 0, stream>>>(
      (const unsigned int*)eidx, flag, cnt, fillc, W1, W2, W3, Wt);
  hist_kernel<<<(N_EDGES + 255) / 256, 256, 0, stream>>>(eidx, flag, cnt);
  scan1_kernel<<<SCAN_BLOCKS, 256, 0, stream>>>(cnt, escan, bsum);
  scan23_kernel<<<SCAN_BLOCKS, 256, 0, stream>>>(escan, bsum, csrOff);
  fill_kernel<<<(ETOT + 255) / 256, 256, 0, stream>>>(eidx, flag, csrOff, fillc, csrSrc);

  const int gn = (N_NODES + 3) / 4;  // 12500
  const int gmb = MP / 16;           // 3128
  const int gx = MP / 128;           // 391

  // ---- Layer 1: x[N,128] @ W1[128,256] ----
  convA_kernel<IN_DIM><<<gmb, 256, 0, stream>>>(x, At, N_NODES);
  gemm_f16_kernel<4, 8, 4><<<dim3(gx, 2), 256, 0, stream>>>(At, Wt + WOFF1,
                                                            att_s1, att_d1, xlh, a_s, a_d, N_NODES, F1);
  gat_agg4_kernel<<<gn, 256, 0, stream>>>(xlh, a_s, a_d, csrOff, csrSrc, b1, At);

  // ---- Layer 2: h1[N,256] @ W2[256,256] (A from agg epilogue, tiled fp16) ----
  gemm_f16_kernel<8, 8, 4><<<dim3(gx, 2), 256, 0, stream>>>(At, Wt + WOFF2,
                                                            att_s2, att_d2, xlh, a_s, a_d, N_NODES, F1);
  gat_agg4_kernel<<<gn, 256, 0, stream>>>(xlh, a_s, a_d, csrOff, csrSrc, b2, At);

  // ---- Layer 3: h2[N,256] @ W3[256,64], H=1, fused fc ----
  gemm_f16_kernel<8, 4, 1><<<dim3(gx, 1), 256, 0, stream>>>(At, Wt + WOFF3,
                                                            att_s3, att_d3, xlh3, a_s, a_d, N_NODES, HIDC);
  gat_final_kernel<<<gn, 256, 0, stream>>>(xlh3, a_s, a_d, csrOff, csrSrc, b3, fcw, fcb, out);
}

// Round 11
// 330.794 us; speedup vs baseline: 2.4336x; 1.0156x over previous
//
#include <hip/hip_runtime.h>
#include <hip/hip_fp16.h>
#include <math.h>

#define N_NODES 50000
#define N_EDGES 800000
#define ETOT (N_EDGES + N_NODES)
#define IN_DIM 128
#define HIDC 64
#define HEADS 4
#define F1 (HEADS * HIDC) /* 256 */
#define MP 50048 /* N_NODES padded to 128 */
#define SCAN_BLOCKS 196 /* ceil(N_NODES/256) */

// tiled W buffer element offsets (within Wt)
#define WOFF1 0
#define WOFF2 32768  /* 128*256 */
#define WOFF3 98304  /* + 256*256 */
#define WTOT_ITEMS 14336 /* 4096 + 8192 + 2048 work items (8 elems each) */
#define CONVW_BLOCKS 56  /* ceil(WTOT_ITEMS/256) */
#define CONVA_BLOCKS (MP / 16) /* 3128 */

typedef _Float16 f16x8 __attribute__((ext_vector_type(8)));
typedef float f32x4 __attribute__((ext_vector_type(4)));
typedef unsigned short u16x8 __attribute__((ext_vector_type(8)));

__device__ inline unsigned short f2h_bits(float f) {
  _Float16 h = (_Float16)f;
  return __builtin_bit_cast(unsigned short, h);
}

__device__ inline void gload_lds16(const void* g, void* l) {
  __builtin_amdgcn_global_load_lds(
      (const __attribute__((address_space(1))) unsigned int*)g,
      (__attribute__((address_space(3))) unsigned int*)l, 16, 0, 0);
}

// one W matrix tile item -> fp16 tiled [Nw/16][K/32][kg=4][c=16][j=8]
__device__ inline void convW_item(const float* __restrict__ W, int K, int Nw, int t,
                                  unsigned short* __restrict__ wt) {
  int KB = K >> 5;
  int c = t & 15;
  int kg = (t >> 4) & 3;
  int kb = (t >> 6) % KB;
  int nblk = (t >> 6) / KB;
  int n = nblk * 16 + c;
  int k0 = kb * 32 + kg * 8;
  u16x8 h8;
#pragma unroll
  for (int j = 0; j < 8; ++j) h8[j] = f2h_bits(W[(size_t)(k0 + j) * Nw + n]);
  *reinterpret_cast<u16x8*>(wt + (size_t)t * 8) = h8;
}

// ---------------- prep: dtype detect + cnt/fillc init + convW + convA(layer1), role-split grid ----------------
__global__ __launch_bounds__(256) void prep_kernel(const unsigned int* __restrict__ buf,
                                                   int* __restrict__ flag,
                                                   int* __restrict__ cnt, int* __restrict__ fillc,
                                                   const float* __restrict__ W1,
                                                   const float* __restrict__ W2,
                                                   const float* __restrict__ W3,
                                                   unsigned short* __restrict__ wt,
                                                   const float* __restrict__ x,
                                                   unsigned short* __restrict__ At) {
  __shared__ float ld[16][136]; // convA staging (K=128 here)
  const int tid = threadIdx.x;
  if (blockIdx.x < SCAN_BLOCKS) {
    int i = blockIdx.x * 256 + tid;
    if (i < N_NODES) { cnt[i] = 1; fillc[i] = 0; } // self-loop pre-counted
    if (blockIdx.x == 0) {
      __shared__ int any;
      if (tid == 0) any = 0;
      __syncthreads();
      for (int k = tid; k < 2048; k += blockDim.x)
        if (buf[2 * k + 1] != 0u) any = 1;
      __syncthreads();
      if (tid == 0) *flag = any; // 1 => int32, 0 => int64
    }
  } else if (blockIdx.x < SCAN_BLOCKS + CONVW_BLOCKS) {
    int t = (blockIdx.x - SCAN_BLOCKS) * 256 + tid;
    if (t >= WTOT_ITEMS) return;
    if (t < 4096) {
      convW_item(W1, IN_DIM, F1, t, wt + WOFF1);
    } else if (t < 4096 + 8192) {
      convW_item(W2, F1, F1, t - 4096, wt + WOFF2);
    } else {
      convW_item(W3, F1, HIDC, t - (4096 + 8192), wt + WOFF3);
    }
  } else {
    // convA for layer 1: x[N,128] -> At tiled [MP/16][4][kg=4][r=16][j=8]
    const int mblk = blockIdx.x - (SCAN_BLOCKS + CONVW_BLOCKS);
    const int elems = 16 * IN_DIM; // 2048
#pragma unroll
    for (int e = tid * 4; e < elems; e += 1024) {
      int r = e >> 7, c = e & 127;
      int row = mblk * 16 + r;
      float4 v = make_float4(0.f, 0.f, 0.f, 0.f);
      if (row < N_NODES) v = *reinterpret_cast<const float4*>(&x[(size_t)row * IN_DIM + c]);
      ld[r][c + 0] = v.x; ld[r][c + 1] = v.y; ld[r][c + 2] = v.z; ld[r][c + 3] = v.w;
    }
    __syncthreads();
    {
      int o = tid * 8; // elems == 2048 == 256*8: exactly one item per thread
      int r = (o >> 3) & 15;
      int kg = (o >> 7) & 3;
      int kb = o >> 9;
      int k0 = kb * 32 + kg * 8;
      u16x8 h8;
#pragma unroll
      for (int j = 0; j < 8; ++j) h8[j] = f2h_bits(ld[r][k0 + j]);
      size_t base = ((size_t)mblk * 4 + kb) * 512 + (size_t)(kg * 16 + r) * 8;
      *reinterpret_cast<u16x8*>(At + base) = h8;
    }
  }
}

// histogram, 4 edges/thread (N_EDGES % 4 == 0; bases 16B-aligned)
__global__ void hist_kernel(const void* __restrict__ eidx, const int* __restrict__ flag,
                            int* __restrict__ cnt) {
  int i = (blockIdx.x * blockDim.x + threadIdx.x) * 4;
  if (i >= N_EDGES) return;
  int d0, d1, d2, d3;
  if (*flag) {
    int4 v = *reinterpret_cast<const int4*>((const int*)eidx + N_EDGES + i);
    d0 = v.x; d1 = v.y; d2 = v.z; d3 = v.w;
  } else {
    const long long* b = (const long long*)eidx + N_EDGES + i;
    longlong2 v0 = *reinterpret_cast<const longlong2*>(b);
    longlong2 v1 = *reinterpret_cast<const longlong2*>(b + 2);
    d0 = (int)v0.x; d1 = (int)v0.y; d2 = (int)v1.x; d3 = (int)v1.y;
  }
  atomicAdd(&cnt[d0], 1);
  atomicAdd(&cnt[d1], 1);
  atomicAdd(&cnt[d2], 1);
  atomicAdd(&cnt[d3], 1);
}

// ---------------- multi-block exclusive scan (2 kernels) ----------------
__global__ __launch_bounds__(256) void scan1_kernel(const int* __restrict__ cnt,
                                                    int* __restrict__ escan,
                                                    int* __restrict__ bsum) {
  __shared__ int tmp[256];
  const int t = threadIdx.x;
  const int i = blockIdx.x * 256 + t;
  int v = (i < N_NODES) ? cnt[i] : 0;
  tmp[t] = v;
  __syncthreads();
#pragma unroll
  for (int o = 1; o < 256; o <<= 1) {
    int u = (t >= o) ? tmp[t - o] : 0;
    __syncthreads();
    tmp[t] += u;
    __syncthreads();
  }
  if (i < N_NODES) escan[i] = tmp[t] - v; // exclusive within block
  if (t == 255) bsum[blockIdx.x] = tmp[255];
}

// every block redundantly scans the 196 block sums, applies its own offset
__global__ __launch_bounds__(256) void scan23_kernel(const int* __restrict__ escan,
                                                     const int* __restrict__ bsum,
                                                     int* __restrict__ off) {
  __shared__ int tmp[256];
  const int t = threadIdx.x;
  int v = (t < SCAN_BLOCKS) ? bsum[t] : 0;
  tmp[t] = v;
  __syncthreads();
#pragma unroll
  for (int o = 1; o < 256; o <<= 1) {
    int u = (t >= o) ? tmp[t - o] : 0;
    __syncthreads();
    tmp[t] += u;
    __syncthreads();
  }
  int boff = (blockIdx.x == 0) ? 0 : tmp[blockIdx.x - 1];
  const int i = blockIdx.x * 256 + t;
  if (i < N_NODES) off[i] = escan[i] + boff;
  if (i == 0) off[N_NODES] = ETOT; // total is a structural constant
}

// fill: 4 edges/thread + self-loop tail range; inline decode
#define FILL_EDGE_THREADS (N_EDGES / 4) /* 200000 */
__global__ void fill_kernel(const void* __restrict__ eidx, const int* __restrict__ flag,
                            const int* __restrict__ csrOff, int* __restrict__ fillc,
                            int* __restrict__ csrSrc) {
  int t = blockIdx.x * blockDim.x + threadIdx.x;
  if (t < FILL_EDGE_THREADS) {
    int i = t * 4;
    int s0, s1, s2, s3, d0, d1, d2, d3;
    if (*flag) {
      const int* b = (const int*)eidx;
      int4 sv = *reinterpret_cast<const int4*>(b + i);
      int4 dv = *reinterpret_cast<const int4*>(b + N_EDGES + i);
      s0 = sv.x; s1 = sv.y; s2 = sv.z; s3 = sv.w;
      d0 = dv.x; d1 = dv.y; d2 = dv.z; d3 = dv.w;
    } else {
      const long long* b = (const long long*)eidx;
      longlong2 sv0 = *reinterpret_cast<const longlong2*>(b + i);
      longlong2 sv1 = *reinterpret_cast<const longlong2*>(b + i + 2);
      longlong2 dv0 = *reinterpret_cast<const longlong2*>(b + N_EDGES + i);
      longlong2 dv1 = *reinterpret_cast<const longlong2*>(b + N_EDGES + i + 2);
      s0 = (int)sv0.x; s1 = (int)sv0.y; s2 = (int)sv1.x; s3 = (int)sv1.y;
      d0 = (int)dv0.x; d1 = (int)dv0.y; d2 = (int)dv1.x; d3 = (int)dv1.y;
    }
    csrSrc[csrOff[d0] + atomicAdd(&fillc[d0], 1)] = s0;
    csrSrc[csrOff[d1] + atomicAdd(&fillc[d1], 1)] = s1;
    csrSrc[csrOff[d2] + atomicAdd(&fillc[d2], 1)] = s2;
    csrSrc[csrOff[d3] + atomicAdd(&fillc[d3], 1)] = s3;
  } else {
    int node = t - FILL_EDGE_THREADS;
    if (node < N_NODES) {
      csrSrc[csrOff[node] + atomicAdd(&fillc[node], 1)] = node;
    }
  }
}

// ---------------- fp16 MFMA GEMM (single product: A*Wt) + fused att-proj epilogue ----------------
template <int KB, int NB, int H>
__global__ __launch_bounds__(256) void gemm_f16_kernel(
    const unsigned short* __restrict__ At, const unsigned short* __restrict__ Bt,
    const float* __restrict__ atts, const float* __restrict__ attd,
    __half* __restrict__ Ch, float* __restrict__ a_s, float* __restrict__ a_d,
    int M, int Nout) {
  __shared__ unsigned short As[8 * 512];
  __shared__ unsigned short Bs[NB * 512];
  const int tid = threadIdx.x;
  const int w = tid >> 6, lane = tid & 63;
  const size_t machunk = ((size_t)blockIdx.x * 8 + w * 2) * KB;
  const int nblk0 = blockIdx.y * NB;
  const int laneo = lane * 8;

  f32x4 acc[2][NB];
#pragma unroll
  for (int mi = 0; mi < 2; ++mi)
#pragma unroll
    for (int nj = 0; nj < NB; ++nj) acc[mi][nj] = {0.f, 0.f, 0.f, 0.f};

  for (int kb = 0; kb < KB; ++kb) {
    gload_lds16(At + (machunk + kb) * 512 + laneo, As + (w * 2) * 512);
    gload_lds16(At + (machunk + (size_t)KB + kb) * 512 + laneo, As + (w * 2 + 1) * 512);
#pragma unroll
    for (int q = 0; q < NB / 4; ++q) {
      int nbl = w * (NB / 4) + q;
      gload_lds16(Bt + ((size_t)(nblk0 + nbl) * KB + kb) * 512 + laneo, Bs + nbl * 512);
    }
    __syncthreads();
    f16x8 a0 = *reinterpret_cast<const f16x8*>(As + (w * 2) * 512 + laneo);
    f16x8 a1 = *reinterpret_cast<const f16x8*>(As + (w * 2 + 1) * 512 + laneo);
#pragma unroll
    for (int nj = 0; nj < NB; ++nj) {
      f16x8 b = *reinterpret_cast<const f16x8*>(Bs + nj * 512 + laneo);
      acc[0][nj] = __builtin_amdgcn_mfma_f32_16x16x32_f16(a0, b, acc[0][nj], 0, 0, 0);
      acc[1][nj] = __builtin_amdgcn_mfma_f32_16x16x32_f16(a1, b, acc[1][nj], 0, 0, 0);
    }
    __syncthreads();
  }
  // ---- epilogue: fp16 store + fused att dot products ----
  const int col0 = nblk0 * 16 + (lane & 15);
  const int row0 = blockIdx.x * 128 + w * 32 + (lane >> 4) * 4;
  float attsv[NB], attdv[NB];
#pragma unroll
  for (int nj = 0; nj < NB; ++nj) {
    int gcol = nblk0 + nj;
    int hh = gcol >> 2;
    int coff = (gcol & 3) * 16 + (lane & 15);
    attsv[nj] = atts[hh * 64 + coff];
    attdv[nj] = attd[hh * 64 + coff];
  }
#pragma unroll
  for (int mi = 0; mi < 2; ++mi) {
#pragma unroll
    for (int nj = 0; nj < NB; ++nj) {
      int col = col0 + nj * 16;
#pragma unroll
      for (int r = 0; r < 4; ++r) {
        int row = row0 + mi * 16 + r;
        if (row < M) Ch[(size_t)row * Nout + col] = __float2half(acc[mi][nj][r]);
      }
    }
#pragma unroll
    for (int r = 0; r < 4; ++r) {
      int row = row0 + mi * 16 + r;
#pragma unroll
      for (int g = 0; g < NB / 4; ++g) {
        float ps = 0.f, pd = 0.f;
#pragma unroll
        for (int q = 0; q < 4; ++q) {
          float v = acc[mi][g * 4 + q][r];
          ps = fmaf(v, attsv[g * 4 + q], ps);
          pd = fmaf(v, attdv[g * 4 + q], pd);
        }
#pragma unroll
        for (int o = 1; o <= 8; o <<= 1) {
          ps += __shfl_xor(ps, o);
          pd += __shfl_xor(pd, o);
        }
        if ((lane & 15) == 0 && row < M) {
          int hh = (nblk0 + g * 4) >> 2;
          a_s[(size_t)row * H + hh] = ps;
          a_d[(size_t)row * H + hh] = pd;
        }
      }
    }
  }
}

// ---------------- H=4 edge softmax + aggregate; dense edge-x-head softmax (chunk=16) ----------------
// softmax phase: lane = edge*4 + head (all 64 lanes active); gather phase: lane owns cols 4L..4L+3
__global__ __launch_bounds__(256) void gat_agg4_kernel(const __half* __restrict__ xlh,
                                                       const float* __restrict__ a_srcv,
                                                       const float* __restrict__ a_dstv,
                                                       const int* __restrict__ csrOff,
                                                       const int* __restrict__ csrSrc,
                                                       const float* __restrict__ bias,
                                                       unsigned short* __restrict__ outT) {
  __shared__ float plds[4][64];  // [wave][edge*4+head]
  __shared__ int slds[4][16];    // [wave][edge]
  __shared__ float hlds[4][4];   // [wave][head]: chunk scale, then final ssum
  const int w = threadIdx.x >> 6;
  const int lane = threadIdx.x & 63;
  const int d = blockIdx.x * 4 + w;
  if (d >= N_NODES) return;
  const int hG = lane >> 4;  // gather-phase head
  const int hS = lane & 3;   // softmax-phase head
  const int eS = lane >> 2;  // softmax-phase edge slot (0..15)
  int e0 = csrOff[d], e1 = csrOff[d + 1];
  float4 advv = reinterpret_cast<const float4*>(a_dstv)[d];
  float adv = (hS == 0) ? advv.x : (hS == 1) ? advv.y : (hS == 2) ? advv.z : advv.w;
  float m = -1e30f, ssum = 0.f; // running state for head hS (uniform within 16-lane head group)
  float4 acc = make_float4(0.f, 0.f, 0.f, 0.f);
  const float* pbase = &plds[w][0];

  for (int cb = e0; cb < e1; cb += 16) {
    int ecount = min(16, e1 - cb);
    int sidx = (eS < ecount) ? csrSrc[cb + eS] : 0;
    float al = -1e30f;
    if (eS < ecount) {
      float v = a_srcv[sidx * 4 + hS] + adv;
      al = (v > 0.f) ? v : 0.2f * v;
    }
    // reduce over the 16-lane stride-4 group (same head): xor 4,8,16,32
    float cm = al;
#pragma unroll
    for (int o = 4; o <= 32; o <<= 1) cm = fmaxf(cm, __shfl_xor(cm, o));
    float nm = fmaxf(m, cm);
    float scale = __expf(m - nm); // first chunk: exp(-inf)=0
    float p = (eS < ecount) ? __expf(al - nm) : 0.f;
    float ps = p;
#pragma unroll
    for (int o = 4; o <= 32; o <<= 1) ps += __shfl_xor(ps, o);
    ssum = ssum * scale + ps;
    m = nm;
    plds[w][eS * 4 + hS] = p;
    if (eS == 0) hlds[w][hS] = scale;
    if (hS == 0) slds[w][eS] = sidx;
    float sc = hlds[w][hG];
    acc.x *= sc; acc.y *= sc; acc.z *= sc; acc.w *= sc;
    for (int i = 0; i < ecount; ++i) {
      int s = slds[w][i];           // broadcast ds_read
      float pv = pbase[i * 4 + hG]; // broadcast-within-16 ds_read
      uint2 raw = *reinterpret_cast<const uint2*>(xlh + (size_t)s * 256 + lane * 4); // 512B/row
      float2 f0 = __half22float2(__builtin_bit_cast(__half2, raw.x));
      float2 f1 = __half22float2(__builtin_bit_cast(__half2, raw.y));
      acc.x = fmaf(pv, f0.x, acc.x);
      acc.y = fmaf(pv, f0.y, acc.y);
      acc.z = fmaf(pv, f1.x, acc.z);
      acc.w = fmaf(pv, f1.y, acc.w);
    }
  }
  if (eS == 0) hlds[w][hS] = ssum;
  float sm = hlds[w][hG];
  float inv = 1.f / (sm + 1e-16f);
  float4 bv = reinterpret_cast<const float4*>(bias)[lane];
  float4 r;
  r.x = acc.x * inv + bv.x;
  r.y = acc.y * inv + bv.y;
  r.z = acc.z * inv + bv.z;
  r.w = acc.w * inv + bv.w;
  r.x = (r.x > 0.f) ? r.x : (__expf(r.x) - 1.f);
  r.y = (r.y > 0.f) ? r.y : (__expf(r.y) - 1.f);
  r.z = (r.z > 0.f) ? r.z : (__expf(r.z) - 1.f);
  r.w = (r.w > 0.f) ? r.w : (__expf(r.w) - 1.f);
  // fp16 write in MFMA-tiled layout (col c=4L+i: kb=L>>3, kg=(L>>1)&3, j=(L&1)*4+i)
  ushort4 hh;
  hh.x = f2h_bits(r.x);
  hh.y = f2h_bits(r.y);
  hh.z = f2h_bits(r.z);
  hh.w = f2h_bits(r.w);
  const int mblk = d >> 4, rr = d & 15;
  const int kb = lane >> 3, kg = (lane >> 1) & 3, jj = (lane & 1) * 4;
  size_t base = ((size_t)mblk * 8 + kb) * 512 + (size_t)(kg * 16 + rr) * 8 + jj;
  *reinterpret_cast<ushort4*>(outT + base) = hh;
}

// layer 3 (H=1) + fused b3 + fc (64->2) + fc_b; fp16 gather; 4 edges per iteration (unchanged)
__global__ __launch_bounds__(256) void gat_final_kernel(const __half* __restrict__ xlh,
                                                        const float* __restrict__ a_srcv,
                                                        const float* __restrict__ a_dstv,
                                                        const int* __restrict__ csrOff,
                                                        const int* __restrict__ csrSrc,
                                                        const float* __restrict__ b3,
                                                        const float* __restrict__ fcw,
                                                        const float* __restrict__ fcb,
                                                        float* __restrict__ out) {
  __shared__ float plds[4][64];
  __shared__ int slds[4][64];
  const int w = threadIdx.x >> 6;
  const int lane = threadIdx.x & 63;
  const int d = blockIdx.x * 4 + w;
  if (d >= N_NODES) return;
  const int g = lane >> 4;   // edge subgroup
  const int c4 = lane & 15;  // 4-col group index
  int e0 = csrOff[d], e1 = csrOff[d + 1];
  float adv = a_dstv[d];
  float m = -1e30f, ssum = 0.f;
  float4 acc = make_float4(0.f, 0.f, 0.f, 0.f);

  for (int cb = e0; cb < e1; cb += 64) {
    int ecount = min(64, e1 - cb);
    int sidx = (lane < ecount) ? csrSrc[cb + lane] : 0;
    slds[w][lane] = sidx;
    float al = -1e30f;
    if (lane < ecount) {
      float v = a_srcv[sidx] + adv;
      al = (v > 0.f) ? v : 0.2f * v;
    }
    float cm = al;
#pragma unroll
    for (int o = 32; o > 0; o >>= 1) cm = fmaxf(cm, __shfl_xor(cm, o));
    float nm = fmaxf(m, cm);
    float scale = __expf(m - nm);
    float p = (lane < ecount) ? __expf(al - nm) : 0.f;
    float ps = p;
#pragma unroll
    for (int o = 32; o > 0; o >>= 1) ps += __shfl_xor(ps, o);
    ssum = ssum * scale + ps;
    m = nm;
    plds[w][lane] = p;
    acc.x *= scale; acc.y *= scale; acc.z *= scale; acc.w *= scale;
    for (int i = 0; i < ecount; i += 4) {
      int e = i + g; // <= 63 always; p==0 for e>=ecount
      int s = slds[w][e];
      float pv = plds[w][e];
      uint2 raw = *reinterpret_cast<const uint2*>(xlh + (size_t)s * 64 + c4 * 4); // 128B/row
      float2 f0 = __half22float2(__builtin_bit_cast(__half2, raw.x));
      float2 f1 = __half22float2(__builtin_bit_cast(__half2, raw.y));
      acc.x = fmaf(pv, f0.x, acc.x);
      acc.y = fmaf(pv, f0.y, acc.y);
      acc.z = fmaf(pv, f1.x, acc.z);
      acc.w = fmaf(pv, f1.y, acc.w);
    }
  }
#pragma unroll
  for (int o = 16; o <= 32; o <<= 1) {
    acc.x += __shfl_xor(acc.x, o);
    acc.y += __shfl_xor(acc.y, o);
    acc.z += __shfl_xor(acc.z, o);
    acc.w += __shfl_xor(acc.w, o);
  }
  float inv = 1.f / (ssum + 1e-16f);
  float4 bv = reinterpret_cast<const float4*>(b3)[c4];
  float4 v;
  v.x = acc.x * inv + bv.x;
  v.y = acc.y * inv + bv.y;
  v.z = acc.z * inv + bv.z;
  v.w = acc.w * inv + bv.w;
  const float2* fcw2 = reinterpret_cast<const float2*>(fcw);
  float2 w0 = fcw2[c4 * 4 + 0], w1 = fcw2[c4 * 4 + 1], w2 = fcw2[c4 * 4 + 2], w3 = fcw2[c4 * 4 + 3];
  float l0 = v.x * w0.x + v.y * w1.x + v.z * w2.x + v.w * w3.x;
  float l1 = v.x * w0.y + v.y * w1.y + v.z * w2.y + v.w * w3.y;
#pragma unroll
  for (int o = 1; o <= 8; o <<= 1) {
    l0 += __shfl_xor(l0, o);
    l1 += __shfl_xor(l1, o);
  }
  if (lane == 0) {
    out[2 * d + 0] = l0 + fcb[0];
    out[2 * d + 1] = l1 + fcb[1];
  }
}

extern "C" void kernel_launch(void* const* d_in, const int* in_sizes, int n_in,
                              void* d_out, int out_size, void* d_ws, size_t ws_size,
                              hipStream_t stream) {
  (void)in_sizes; (void)n_in; (void)out_size; (void)ws_size;
  const float* x      = (const float*)d_in[0];
  const void*  eidx   = d_in[1];
  const float* W1     = (const float*)d_in[2];
  const float* att_s1 = (const float*)d_in[3];
  const float* att_d1 = (const float*)d_in[4];
  const float* b1     = (const float*)d_in[5];
  const float* W2     = (const float*)d_in[6];
  const float* att_s2 = (const float*)d_in[7];
  const float* att_d2 = (const float*)d_in[8];
  const float* b2     = (const float*)d_in[9];
  const float* W3     = (const float*)d_in[10];
  const float* att_s3 = (const float*)d_in[11];
  const float* att_d3 = (const float*)d_in[12];
  const float* b3     = (const float*)d_in[13];
  const float* fcw    = (const float*)d_in[14];
  const float* fcb    = (const float*)d_in[15];
  float* out = (float*)d_out;

  char* ws = (char*)d_ws;
  size_t off = 0;
  auto alloc = [&](size_t bytes) -> void* {
    void* p = (void*)(ws + off);
    off += (bytes + 255) & ~(size_t)255;
    return p;
  };
  int*   cnt    = (int*)alloc((size_t)N_NODES * 4);
  int*   fillc  = (int*)alloc((size_t)N_NODES * 4);
  int*   csrOff = (int*)alloc((size_t)(N_NODES + 1) * 4);
  int*   csrSrc = (int*)alloc((size_t)ETOT * 4);
  int*   flag   = (int*)alloc(256);
  int*   escan  = (int*)alloc((size_t)N_NODES * 4);
  int*   bsum   = (int*)alloc((size_t)SCAN_BLOCKS * 4);
  float* a_s    = (float*)alloc((size_t)N_NODES * HEADS * 4);
  float* a_d    = (float*)alloc((size_t)N_NODES * HEADS * 4);
  unsigned short* At = (unsigned short*)alloc((size_t)MP * F1 * 2); // tiled fp16 A
  unsigned short* Wt = (unsigned short*)alloc((size_t)(WOFF3 + 16384) * 2);
  __half* xlh  = (__half*)alloc((size_t)MP * F1 * 2);   // fp16 xl (layers 1,2)
  __half* xlh3 = (__half*)alloc((size_t)MP * HIDC * 2); // fp16 xl (layer 3)

  // ---- graph build + weight conversion + layer-1 A conversion, one prep launch ----
  prep_kernel<<<SCAN_BLOCKS + CONVW_BLOCKS + CONVA_BLOCKS, 256, 0, stream>>>(
      (const unsigned int*)eidx, flag, cnt, fillc, W1, W2, W3, Wt, x, At);
  hist_kernel<<<(N_EDGES / 4 + 255) / 256, 256, 0, stream>>>(eidx, flag, cnt);
  scan1_kernel<<<SCAN_BLOCKS, 256, 0, stream>>>(cnt, escan, bsum);
  scan23_kernel<<<SCAN_BLOCKS, 256, 0, stream>>>(escan, bsum, csrOff);
  fill_kernel<<<(FILL_EDGE_THREADS + N_NODES + 255) / 256, 256, 0, stream>>>(eidx, flag, csrOff, fillc, csrSrc);

  const int gn = (N_NODES + 3) / 4;  // 12500
  const int gx = MP / 128;           // 391

  // ---- Layer 1: x[N,128] @ W1[128,256] ----
  gemm_f16_kernel<4, 8, 4><<<dim3(gx, 2), 256, 0, stream>>>(At, Wt + WOFF1,
                                                            att_s1, att_d1, xlh, a_s, a_d, N_NODES, F1);
  gat_agg4_kernel<<<gn, 256, 0, stream>>>(xlh, a_s, a_d, csrOff, csrSrc, b1, At);

  // ---- Layer 2: h1[N,256] @ W2[256,256] (A from agg epilogue, tiled fp16) ----
  gemm_f16_kernel<8, 8, 4><<<dim3(gx, 2), 256, 0, stream>>>(At, Wt + WOFF2,
                                                            att_s2, att_d2, xlh, a_s, a_d, N_NODES, F1);
  gat_agg4_kernel<<<gn, 256, 0, stream>>>(xlh, a_s, a_d, csrOff, csrSrc, b2, At);

  // ---- Layer 3: h2[N,256] @ W3[256,64], H=1, fused fc ----
  gemm_f16_kernel<8, 4, 1><<<dim3(gx, 1), 256, 0, stream>>>(At, Wt + WOFF3,
                                                            att_s3, att_d3, xlh3, a_s, a_d, N_NODES, HIDC);
  gat_final_kernel<<<gn, 256, 0, stream>>>(xlh3, a_s, a_d, csrOff, csrSrc, b3, fcw, fcb, out);
}